// Round 3
// baseline (519.069 us; speedup 1.0000x reference)
//
#include <hip/hip_runtime.h>
#include <math.h>

#define NB 256      // events
#define KNN 8

typedef float v2f __attribute__((ext_vector_type(2)));

__device__ __forceinline__ float elu_f(float x) {
    return x > 0.f ? x : __expf(x) - 1.f;
}

// ---- sorting-network primitives on u32 keys -------------------------------
// key = (bits(dv) & ~511) | global_row_idx, dv >= 0 so raw-bit order == float
// order. Truncation to 512 ulp, tie-break lower-index-wins (validated r1/r2).
__device__ __forceinline__ void cex(unsigned& a, unsigned& b) {
    unsigned lo = min(a, b), hi = max(a, b);
    a = lo; b = hi;
}

__device__ __forceinline__ void sort4(unsigned* s) {
    cex(s[0], s[1]); cex(s[2], s[3]);
    cex(s[0], s[2]); cex(s[1], s[3]);
    cex(s[1], s[2]);
}

// v asc top-8; s asc 4 candidates -> v = 8 smallest of union, ascending.
__device__ __forceinline__ void merge8_4(unsigned* v, const unsigned* s) {
    v[4] = min(v[4], s[3]); v[5] = min(v[5], s[2]);
    v[6] = min(v[6], s[1]); v[7] = min(v[7], s[0]);
    cex(v[0], v[4]); cex(v[1], v[5]); cex(v[2], v[6]); cex(v[3], v[7]);
    cex(v[0], v[2]); cex(v[1], v[3]); cex(v[4], v[6]); cex(v[5], v[7]);
    cex(v[0], v[1]); cex(v[2], v[3]); cex(v[4], v[5]); cex(v[6], v[7]);
}

// v asc top-8, s asc 8 candidates -> v = 8 smallest of union, ascending.
__device__ __forceinline__ void merge8(unsigned* v, const unsigned* s) {
#pragma unroll
    for (int i = 0; i < 8; i++) v[i] = min(v[i], s[7 - i]);
    cex(v[0], v[4]); cex(v[1], v[5]); cex(v[2], v[6]); cex(v[3], v[7]);
    cex(v[0], v[2]); cex(v[1], v[3]); cex(v[4], v[6]); cex(v[5], v[7]);
    cex(v[0], v[1]); cex(v[2], v[3]); cex(v[4], v[5]); cex(v[6], v[7]);
}

// ================= fused encoder (+ conv-side linear precomputes) =========
template<int FIN, int EXTRA>
__device__ void encode64_body(const float* __restrict__ x,
    const float* __restrict__ W1, const float* __restrict__ b1,
    const float* __restrict__ W2, const float* __restrict__ b2,
    const float* __restrict__ conv_W, const float* __restrict__ conv_b,
    float* __restrict__ enc, float* __restrict__ e1, float* __restrict__ e2,
    int blk, float* smem)
{
    float* sx  = smem;              // up to 64*30
    float* sW1 = sx + 64 * 30;      // up to 30*32
    float* sW2 = sW1 + 30 * 32;     // 1024
    float* sWe = sW2 + 1024;        // 1024
    float* sb1 = sWe + 1024;
    float* sb2 = sb1 + 32;
    float* sbe = sb2 + 32;
    float* sh  = sbe + 32;          // 2048
    int tid = threadIdx.x;
    for (int i = tid; i < FIN * 32; i += 256) sW1[i] = W1[i];
    for (int i = tid; i < 1024; i += 256) sW2[i] = W2[i];
    if (EXTRA == 1) for (int i = tid; i < 1024; i += 256) sWe[i] = conv_W[1024 + i];
    if (EXTRA == 2) for (int i = tid; i < 1024; i += 256) sWe[i] = conv_W[i] - conv_W[1024 + i];
    if (tid < 32) {
        sb1[tid] = b1[tid]; sb2[tid] = b2[tid];
        sbe[tid] = (EXTRA == 2) ? conv_b[tid] : 0.f;
    }
    size_t node0 = (size_t)blk * 64;
    for (int i = tid; i < 64 * FIN; i += 256) sx[i] = x[node0 * FIN + i];
    __syncthreads();
    int g = tid >> 5, c = tid & 31;
    float o[8];
#pragma unroll
    for (int j = 0; j < 8; j++) {
        int n = g * 8 + j;
        float a = sb1[c];
#pragma unroll
        for (int f = 0; f < FIN; f++) a = fmaf(sx[n * FIN + f], sW1[f * 32 + c], a);
        sh[n * 32 + c] = elu_f(a);
    }
    __syncthreads();
#pragma unroll
    for (int j = 0; j < 8; j++) {
        int n = g * 8 + j;
        float a = sb2[c];
#pragma unroll
        for (int k = 0; k < 32; k++) a = fmaf(sh[n * 32 + k], sW2[k * 32 + c], a);
        o[j] = elu_f(a);
        enc[(node0 + n) * 32 + c] = o[j];
    }
    if (EXTRA == 0) return;
    __syncthreads();
#pragma unroll
    for (int j = 0; j < 8; j++) sh[(g * 8 + j) * 32 + c] = o[j];
    __syncthreads();
#pragma unroll
    for (int j = 0; j < 8; j++) {
        int n = g * 8 + j;
        float a = sbe[c];
#pragma unroll
        for (int d = 0; d < 32; d++) a = fmaf(sh[n * 32 + d], sWe[d * 32 + c], a);
        size_t off = (node0 + n) * 32 + c;
        e1[off] = a;
        if (EXTRA == 2) e2[off] = a;
    }
}

// 4352 blocks: sv(256) | trk(2048) | pfc(2048)
__global__ __launch_bounds__(256) void encode_all_kernel(
    const float* __restrict__ x_sv, const float* __restrict__ x_trk, const float* __restrict__ x_pfc,
    const float* __restrict__ sv_W1, const float* __restrict__ sv_b1,
    const float* __restrict__ sv_W2, const float* __restrict__ sv_b2,
    const float* __restrict__ trk_W1, const float* __restrict__ trk_b1,
    const float* __restrict__ trk_W2, const float* __restrict__ trk_b2,
    const float* __restrict__ pfc_W1, const float* __restrict__ pfc_b1,
    const float* __restrict__ pfc_W2, const float* __restrict__ pfc_b2,
    const float* __restrict__ conv_W, const float* __restrict__ conv_b,
    float* __restrict__ sv_enc, float* __restrict__ trk_enc, float* __restrict__ pfc_enc,
    float* __restrict__ Y1, float* __restrict__ Y2,
    float* __restrict__ f1, float* __restrict__ f2)
{
    __shared__ float smem[64*30 + 30*32 + 1024 + 1024 + 96 + 2048];
    int bid = blockIdx.x;
    if (bid < 256)
        encode64_body<14, 1>(x_sv, sv_W1, sv_b1, sv_W2, sv_b2, conv_W, conv_b,
                             sv_enc, Y1, nullptr, bid, smem);
    else if (bid < 2304)
        encode64_body<30, 2>(x_trk, trk_W1, trk_b1, trk_W2, trk_b2, conv_W, conv_b,
                             trk_enc, f1, f2, bid - 256, smem);
    else
        encode64_body<10, 1>(x_pfc, pfc_W1, pfc_b1, pfc_W2, pfc_b2, conv_W, conv_b,
                             pfc_enc, Y2, nullptr, bid - 2304, smem);
}

// ================= kNN =====================================================
// 256 threads = two 128-thread wave-pairs. Each thread owns 4 dst rows
// (every 16B src chunk broadcast from LDS feeds 4 accumulations). Wave-pair
// `half` scans half of the part's src rows; the two sorted top-8 lists per
// dst are merged through LDS at the end (pkey format unchanged, 4 parts).
// This keeps R2's DS-instruction count at R1's occupancy.
__device__ __forceinline__ void load_xd(const float4* xi, v2f* xd) {
#pragma unroll
    for (int q = 0; q < 8; q++) {
        float4 v = xi[q];
        xd[2*q]   = (v2f){v.x, v.y};
        xd[2*q+1] = (v2f){v.z, v.w};
    }
}

__device__ __forceinline__ float norm32(const v2f* xd) {
    v2f A = {0.f, 0.f}, B = {0.f, 0.f};
#pragma unroll
    for (int q = 0; q < 8; q++) {
        A = __builtin_elementwise_fma(xd[2*q],   xd[2*q],   A);
        B = __builtin_elementwise_fma(xd[2*q+1], xd[2*q+1], B);
    }
    v2f S = A + B;
    return S.x + S.y;
}

template<int NR, int NT>
__device__ void stage_rows(const float* __restrict__ src_rows,
                           float4* s_src, float* s_nrm, int tid)
{
    const float4* s4 = (const float4*)src_rows;
    for (int i = tid; i < NR * 8; i += NT) s_src[i] = s4[i];
    __syncthreads();
    for (int s = tid; s < NR; s += NT) {
        float a = 0.f;
#pragma unroll
        for (int q = 0; q < 8; q++) {
            float4 v = s_src[s * 8 + q];
            a = fmaf(v.x, v.x, a); a = fmaf(v.y, v.y, a);
            a = fmaf(v.z, v.z, a); a = fmaf(v.w, v.w, a);
        }
        s_nrm[s] = a;
    }
    __syncthreads();
}

// 4-dst scan: dst-norms folded into accumulator init (dv >= 0 so raw-bit
// unsigned order == distance order); batch-4 candidate sort + bitonic merge.
template<int NR>
__device__ void knn_scan_core4(const float4* __restrict__ s_src, const float* __restrict__ s_nrm,
                               v2f (&xd)[4][16], const float* nh,
                               unsigned (&key)[4][8], int base)
{
    for (int s0 = 0; s0 < NR; s0 += 4) {
        unsigned cand[4][4];
#pragma unroll
        for (int j = 0; j < 4; j++) {
            int s = s0 + j;
            v2f a0[4], a1[4];
#pragma unroll
            for (int d = 0; d < 4; d++) {
                a0[d] = (v2f){nh[d], 0.f};
                a1[d] = (v2f){0.f, 0.f};
            }
#pragma unroll
            for (int q = 0; q < 8; q++) {
                float4 v = s_src[s * 8 + q];
                v2f vxy = {v.x, v.y};
                v2f vzw = {v.z, v.w};
#pragma unroll
                for (int d = 0; d < 4; d++) {
                    a0[d] = __builtin_elementwise_fma(xd[d][2*q],   vxy, a0[d]);
                    a1[d] = __builtin_elementwise_fma(xd[d][2*q+1], vzw, a1[d]);
                }
            }
            float nrm = s_nrm[s];
#pragma unroll
            for (int d = 0; d < 4; d++) {
                v2f S = a0[d] + a1[d];
                float dv = fmaf(-2.f, S.x + S.y, nrm);   // = |s|^2 + |d|^2 - 2<d,s>
                cand[d][j] = (__float_as_uint(dv) & 0xFFFFFE00u) | (unsigned)(base + s);
            }
        }
#pragma unroll
        for (int d = 0; d < 4; d++) { sort4(cand[d]); merge8_4(key[d], cand[d]); }
    }
}

// split part (128 rows): per-dst partial sorted top-8 keys (global idx in key)
// thread (tid&127) owns dsts {lt, lt+128, lt+256, lt+384}; wave-pair (tid>>7)
// scans src rows [half*64, half*64+64); halves merged via LDS.
__device__ void knn_split_body4(const float* __restrict__ src, const float* __restrict__ dst,
                                unsigned* __restrict__ pkey,
                                int b, int part, float4* s_src, float* s_nrm)
{
    int tid = threadIdx.x, half = tid >> 7, lt = tid & 127;
    stage_rows<128, 256>(src + ((size_t)b * 512 + part * 128) * 32, s_src, s_nrm, tid);

    v2f xd[4][16];
    float nh[4];
#pragma unroll
    for (int d = 0; d < 4; d++) {
        load_xd((const float4*)(dst + ((size_t)b * 512 + d * 128 + lt) * 32), xd[d]);
        nh[d] = -0.5f * norm32(xd[d]);
    }

    unsigned key[4][8];
#pragma unroll
    for (int d = 0; d < 4; d++)
#pragma unroll
        for (int k = 0; k < 8; k++) key[d][k] = 0xFFFFFFFFu;

    knn_scan_core4<64>(s_src + half * 64 * 8, s_nrm + half * 64, xd, nh, key,
                       part * 128 + half * 64);

    __syncthreads();                       // all scans done before s_src reuse
    unsigned* skey = (unsigned*)s_src;     // 512 dsts x 8 u32 = 16 KB
    if (half) {
#pragma unroll
        for (int d = 0; d < 4; d++) {
            unsigned* p = skey + ((size_t)(d * 128 + lt)) * 8;
#pragma unroll
            for (int k = 0; k < 8; k++) p[k] = key[d][k];
        }
    }
    __syncthreads();
    if (!half) {
#pragma unroll
        for (int d = 0; d < 4; d++) {
            unsigned s8[8];
            const unsigned* p = skey + ((size_t)(d * 128 + lt)) * 8;
#pragma unroll
            for (int k = 0; k < 8; k++) s8[k] = p[k];
            merge8(key[d], s8);
            unsigned* o = pkey + ((size_t)b * 512 + d * 128 + lt) * 32 + part * 8;
#pragma unroll
            for (int k = 0; k < 8; k++) o[k] = key[d][k];
        }
    }
}

// conv1 small (64 src rows): final top-8 idx (u16) directly; halves of 32.
__device__ void knn_small_body4(const float* __restrict__ src, const float* __restrict__ dst,
                                unsigned short* __restrict__ idx1_out,
                                int b, float4* s_src, float* s_nrm)
{
    int tid = threadIdx.x, half = tid >> 7, lt = tid & 127;
    stage_rows<64, 256>(src + (size_t)b * 64 * 32, s_src, s_nrm, tid);

    v2f xd[4][16];
    float nh[4];
#pragma unroll
    for (int d = 0; d < 4; d++) {
        load_xd((const float4*)(dst + ((size_t)b * 512 + d * 128 + lt) * 32), xd[d]);
        nh[d] = -0.5f * norm32(xd[d]);
    }

    unsigned key[4][8];
#pragma unroll
    for (int d = 0; d < 4; d++)
#pragma unroll
        for (int k = 0; k < 8; k++) key[d][k] = 0xFFFFFFFFu;

    knn_scan_core4<32>(s_src + half * 32 * 8, s_nrm + half * 32, xd, nh, key,
                       half * 32);

    __syncthreads();
    unsigned* skey = (unsigned*)s_src;
    if (half) {
#pragma unroll
        for (int d = 0; d < 4; d++) {
            unsigned* p = skey + ((size_t)(d * 128 + lt)) * 8;
#pragma unroll
            for (int k = 0; k < 8; k++) p[k] = key[d][k];
        }
    }
    __syncthreads();
    if (!half) {
#pragma unroll
        for (int d = 0; d < 4; d++) {
            unsigned s8[8];
            const unsigned* p = skey + ((size_t)(d * 128 + lt)) * 8;
#pragma unroll
            for (int k = 0; k < 8; k++) s8[k] = p[k];
            merge8(key[d], s8);
            int t = d * 128 + lt;
            unsigned int* o32 = (unsigned int*)(idx1_out + ((size_t)b * 512 + t) * 8);
#pragma unroll
            for (int k = 0; k < 4; k++)
                o32[k] = (key[d][2*k] & 511u) | ((key[d][2*k+1] & 511u) << 16);
        }
    }
}

// knn12: 1280 blocks x 256 thr. conv2 split: bid<1024 (part=bid>>8, e=bid&255).
// conv1 small: tail blocks.
__global__ __launch_bounds__(256, 2) void knn12_kernel(
    const float* __restrict__ sv_enc, const float* __restrict__ trk_enc,
    const float* __restrict__ pfc_enc,
    unsigned short* __restrict__ idx1_out,
    unsigned* __restrict__ pkey)
{
    __shared__ float4 s_src[128 * 8];
    __shared__ float  s_nrm[128];
    int bid = blockIdx.x;
    if (bid < 1024) knn_split_body4(pfc_enc, trk_enc, pkey, bid & 255, bid >> 8, s_src, s_nrm);
    else            knn_small_body4(sv_enc, trk_enc, idx1_out, bid - 1024, s_src, s_nrm);
}

__global__ __launch_bounds__(256, 2) void knn3_kernel(
    const float* __restrict__ f1, const float* __restrict__ f2,
    unsigned* __restrict__ pkey)
{
    __shared__ float4 s_src[128 * 8];
    __shared__ float  s_nrm[128];
    int bid = blockIdx.x;
    knn_split_body4(f1, f2, pkey, bid & 255, bid >> 8, s_src, s_nrm);
}

// ================= gather helpers ==========================================
// merge 4 sorted partial key-lists (ascending part order) -> final 8 rows
__device__ __forceinline__ void merge_parts(const unsigned* __restrict__ pk_, int* rows)
{
    const uint4* pk = (const uint4*)pk_;
    uint4 a0 = pk[0], a1 = pk[1];
    unsigned v[8] = { a0.x, a0.y, a0.z, a0.w, a1.x, a1.y, a1.z, a1.w };
#pragma unroll
    for (int p = 1; p < 4; p++) {
        uint4 b0 = pk[2*p], b1 = pk[2*p+1];
        unsigned s[8] = { b0.x, b0.y, b0.z, b0.w, b1.x, b1.y, b1.z, b1.w };
        merge8(v, s);
    }
#pragma unroll
    for (int k = 0; k < 8; k++) rows[k] = (int)(v[k] & 511u);
}

__device__ __forceinline__ void maxgather(const float* __restrict__ Ybase,
                                          const int* rows, float4* m)
{
    const float4* Yb = (const float4*)Ybase;
    const float4* r0 = Yb + (size_t)rows[0] * 8;
#pragma unroll
    for (int q = 0; q < 8; q++) m[q] = r0[q];
#pragma unroll
    for (int k = 1; k < 8; k++) {
        const float4* rr = Yb + (size_t)rows[k] * 8;
#pragma unroll
        for (int q = 0; q < 8; q++) {
            float4 v = rr[q];
            m[q].x = fmaxf(m[q].x, v.x); m[q].y = fmaxf(m[q].y, v.y);
            m[q].z = fmaxf(m[q].z, v.z); m[q].w = fmaxf(m[q].w, v.w);
        }
    }
}

// g12: 1024 blocks. f holds Base (written by encode); in-place f=elu(f+maxY).
__global__ __launch_bounds__(256) void g12_kernel(
    const float* __restrict__ Y1, const unsigned short* __restrict__ idx1, float* __restrict__ f1,
    const float* __restrict__ Y2, const unsigned* __restrict__ pkey, float* __restrict__ f2)
{
    int bid = blockIdx.x;
    int tid = threadIdx.x;
    int rows[8];
    float* fp;
    const float* Yb;
    int t;
    if (bid < 512) {
        t = bid * 256 + tid;
        uint4 u = *(const uint4*)(idx1 + (size_t)t * 8);
        rows[0] = (int)(u.x & 0xffff); rows[1] = (int)(u.x >> 16);
        rows[2] = (int)(u.y & 0xffff); rows[3] = (int)(u.y >> 16);
        rows[4] = (int)(u.z & 0xffff); rows[5] = (int)(u.z >> 16);
        rows[6] = (int)(u.w & 0xffff); rows[7] = (int)(u.w >> 16);
        Yb = Y1 + (size_t)(t >> 9) * 64 * 32;
        fp = f1 + (size_t)t * 32;
    } else {
        t = (bid - 512) * 256 + tid;
        merge_parts(pkey + (size_t)t * 32, rows);
        Yb = Y2 + (size_t)(t >> 9) * 512 * 32;
        fp = f2 + (size_t)t * 32;
    }
    float4 m[8];
    maxgather(Yb, rows, m);
    float4* op = (float4*)fp;
#pragma unroll
    for (int q = 0; q < 8; q++) {
        float4 bv = op[q];
        float4 o;
        o.x = elu_f(bv.x + m[q].x); o.y = elu_f(bv.y + m[q].y);
        o.z = elu_f(bv.z + m[q].z); o.w = elu_f(bv.w + m[q].w);
        op[q] = o;
    }
}

// yb3: 4096 blocks: Y3 = f1@w2h (bid<2048) | B3 = f2@wd+bb
__global__ __launch_bounds__(256) void yb3_kernel(
    const float* __restrict__ f1, const float* __restrict__ f2,
    const float* __restrict__ conv_W, const float* __restrict__ conv_b,
    float* __restrict__ Y3, float* __restrict__ B3)
{
    __shared__ float sW[1024];
    __shared__ float sb[32];
    __shared__ float sx[8][32];
    int bid = blockIdx.x;
    int tid = threadIdx.x;
    int mode = (bid >= 2048);
    const float* X = mode ? f2 : f1;
    float* O = mode ? B3 : Y3;
    int rb = (mode ? bid - 2048 : bid) * 64;
    for (int i = tid; i < 1024; i += 256)
        sW[i] = mode ? (conv_W[i] - conv_W[1024 + i]) : conv_W[1024 + i];
    if (tid < 32) sb[tid] = mode ? conv_b[tid] : 0.f;
    int ln = tid >> 5, c = tid & 31;
    for (int p = 0; p < 8; p++) {
        __syncthreads();
        sx[ln][c] = X[(size_t)(rb + p * 8 + ln) * 32 + c];
        __syncthreads();
        float acc = sb[c];
#pragma unroll
        for (int d = 0; d < 32; d++) acc = fmaf(sx[ln][d], sW[d * 32 + c], acc);
        O[(size_t)(rb + p * 8 + ln) * 32 + c] = acc;
    }
}

// g3: 512 blocks. f3 rows in registers, reduced straight to pooled partials.
__global__ __launch_bounds__(256) void g3_kernel(
    const float* __restrict__ Y3, const float* __restrict__ B3,
    const unsigned* __restrict__ pkey,
    float* __restrict__ pool)
{
    __shared__ float sp[4][32];
    int bid = blockIdx.x;
    int tid = threadIdx.x, lane = tid & 63, wave = tid >> 6;
    int t = bid * 256 + tid;
    int e = t >> 9;
    int rows[8];
    merge_parts(pkey + (size_t)t * 32, rows);
    float4 m[8];
    maxgather(Y3 + (size_t)e * 512 * 32, rows, m);
    const float4* bp = (const float4*)(B3 + (size_t)t * 32);
    float4 r[8];
#pragma unroll
    for (int q = 0; q < 8; q++) {
        float4 bv = bp[q];
        r[q].x = elu_f(bv.x + m[q].x); r[q].y = elu_f(bv.y + m[q].y);
        r[q].z = elu_f(bv.z + m[q].z); r[q].w = elu_f(bv.w + m[q].w);
    }
    for (int off = 1; off < 64; off <<= 1) {
#pragma unroll
        for (int q = 0; q < 8; q++) {
            r[q].x += __shfl_xor(r[q].x, off);
            r[q].y += __shfl_xor(r[q].y, off);
            r[q].z += __shfl_xor(r[q].z, off);
            r[q].w += __shfl_xor(r[q].w, off);
        }
    }
    if (lane == 0) {
#pragma unroll
        for (int q = 0; q < 8; q++) {
            sp[wave][q*4+0] = r[q].x; sp[wave][q*4+1] = r[q].y;
            sp[wave][q*4+2] = r[q].z; sp[wave][q*4+3] = r[q].w;
        }
    }
    __syncthreads();
    if (tid < 32)
        pool[(size_t)bid * 32 + tid] = sp[0][tid] + sp[1][tid] + sp[2][tid] + sp[3][tid];
}

// final: 2 pooled partials per event + MLP + sigmoid + arange
__global__ __launch_bounds__(64) void final_kernel(
    const float* __restrict__ pool,
    const float* __restrict__ W1, const float* __restrict__ b1,
    const float* __restrict__ W2, const float* __restrict__ b2,
    float* __restrict__ outp)
{
    int b = blockIdx.x;
    int lane = threadIdx.x, c = lane & 31;
    __shared__ float sp[32];
    __shared__ float sh1[32];
    if (lane < 32)
        sp[c] = (pool[(size_t)(2*b) * 32 + c] + pool[(size_t)(2*b+1) * 32 + c]) * (1.0f / 512.0f);
    __syncthreads();
    if (lane < 32) {
        float h = b1[c];
#pragma unroll
        for (int d = 0; d < 32; d++) h = fmaf(sp[d], W1[d * 32 + c], h);
        sh1[c] = elu_f(h);
    }
    __syncthreads();
    if (lane == 0) {
        float o = b2[0];
#pragma unroll
        for (int d = 0; d < 32; d++) o = fmaf(sh1[d], W2[d], o);
        o = 1.f / (1.f + __expf(-o));
        outp[b] = o;
        outp[NB + b] = (float)b;
    }
}

extern "C" void kernel_launch(void* const* d_in, const int* in_sizes, int n_in,
                              void* d_out, int out_size, void* d_ws, size_t ws_size,
                              hipStream_t stream) {
    const float* x_sv  = (const float*)d_in[0];
    const float* x_trk = (const float*)d_in[1];
    const float* x_pfc = (const float*)d_in[2];
    const float* sv_W1  = (const float*)d_in[6];
    const float* sv_b1  = (const float*)d_in[7];
    const float* sv_W2  = (const float*)d_in[8];
    const float* sv_b2  = (const float*)d_in[9];
    const float* trk_W1 = (const float*)d_in[10];
    const float* trk_b1 = (const float*)d_in[11];
    const float* trk_W2 = (const float*)d_in[12];
    const float* trk_b2 = (const float*)d_in[13];
    const float* pfc_W1 = (const float*)d_in[14];
    const float* pfc_b1 = (const float*)d_in[15];
    const float* pfc_W2 = (const float*)d_in[16];
    const float* pfc_b2 = (const float*)d_in[17];
    const float* conv_W = (const float*)d_in[18];
    const float* conv_b = (const float*)d_in[19];
    const float* out_W1 = (const float*)d_in[20];
    const float* out_b1 = (const float*)d_in[21];
    const float* out_W2 = (const float*)d_in[22];
    const float* out_b2 = (const float*)d_in[23];

    float* ws = (float*)d_ws;
    const size_t SV_E  = (size_t)NB * 64 * 32;     //   524288
    const size_t TRK_E = (size_t)NB * 512 * 32;    //  4194304
    float* sv_enc  = ws;                           // pool aliases after knn12
    float* trk_enc = sv_enc + SV_E;                // B3 aliases after knn12
    float* pfc_enc = trk_enc + TRK_E;              // Y3 aliases after knn12
    float* f1      = pfc_enc + TRK_E;
    float* f2      = f1 + TRK_E;
    float* Y1      = f2 + TRK_E;                   // SV_E
    float* Y2      = Y1 + SV_E;                    // TRK_E
    unsigned* pkey = (unsigned*)(Y2 + TRK_E);      // NB*512*32 u32 (4 parts x 8)
    unsigned short* idx1 = (unsigned short*)(pkey + TRK_E);    // NB*512*8 u16
    float* Y3   = pfc_enc;   // pfc_enc dead after knn12
    float* B3   = trk_enc;   // trk_enc dead after knn12
    float* pool = sv_enc;    // sv_enc dead after knn12

    encode_all_kernel<<<4352, 256, 0, stream>>>(
        x_sv, x_trk, x_pfc,
        sv_W1, sv_b1, sv_W2, sv_b2,
        trk_W1, trk_b1, trk_W2, trk_b2,
        pfc_W1, pfc_b1, pfc_W2, pfc_b2,
        conv_W, conv_b,
        sv_enc, trk_enc, pfc_enc, Y1, Y2, f1, f2);

    knn12_kernel<<<1280, 256, 0, stream>>>(sv_enc, trk_enc, pfc_enc, idx1, pkey);
    g12_kernel<<<1024, 256, 0, stream>>>(Y1, idx1, f1, Y2, pkey, f2);

    yb3_kernel<<<4096, 256, 0, stream>>>(f1, f2, conv_W, conv_b, Y3, B3);
    knn3_kernel<<<1024, 256, 0, stream>>>(f1, f2, pkey);
    g3_kernel<<<512, 256, 0, stream>>>(Y3, B3, pkey, pool);

    final_kernel<<<NB, 64, 0, stream>>>(pool, out_W1, out_b1, out_W2, out_b2, (float*)d_out);
}

// Round 4
// 460.366 us; speedup vs baseline: 1.1275x; 1.1275x over previous
//
#include <hip/hip_runtime.h>
#include <math.h>

#define NB 256      // events
#define KNN 8

typedef __attribute__((ext_vector_type(8))) short short8;
typedef __attribute__((ext_vector_type(4))) float f32x4;

__device__ __forceinline__ float elu_f(float x) {
    return x > 0.f ? x : __expf(x) - 1.f;
}

// round-to-nearest-even fp32 -> bf16 (returns low 16 bits)
__device__ __forceinline__ unsigned bf16rn(float x) {
    unsigned u = __float_as_uint(x);
    return (u + 0x7FFFu + ((u >> 16) & 1u)) >> 16;
}

// ---- sorting-network primitives on u32 keys -------------------------------
// key = (bits(dv) & ~511) | src_idx, dv >= 0 so raw-bit order == float order.
// Truncation to 512 ulp, tie-break lower-index-wins (validated r1-r3).
__device__ __forceinline__ void cex(unsigned& a, unsigned& b) {
    unsigned lo = min(a, b), hi = max(a, b);
    a = lo; b = hi;
}

__device__ __forceinline__ void sort4(unsigned* s) {
    cex(s[0], s[1]); cex(s[2], s[3]);
    cex(s[0], s[2]); cex(s[1], s[3]);
    cex(s[1], s[2]);
}

// v asc top-8; s asc 4 candidates -> v = 8 smallest of union, ascending.
__device__ __forceinline__ void merge8_4(unsigned* v, const unsigned* s) {
    v[4] = min(v[4], s[3]); v[5] = min(v[5], s[2]);
    v[6] = min(v[6], s[1]); v[7] = min(v[7], s[0]);
    cex(v[0], v[4]); cex(v[1], v[5]); cex(v[2], v[6]); cex(v[3], v[7]);
    cex(v[0], v[2]); cex(v[1], v[3]); cex(v[4], v[6]); cex(v[5], v[7]);
    cex(v[0], v[1]); cex(v[2], v[3]); cex(v[4], v[5]); cex(v[6], v[7]);
}

// v asc top-8, s asc 8 candidates -> v = 8 smallest of union, ascending.
__device__ __forceinline__ void merge8(unsigned* v, const unsigned* s) {
#pragma unroll
    for (int i = 0; i < 8; i++) v[i] = min(v[i], s[7 - i]);
    cex(v[0], v[4]); cex(v[1], v[5]); cex(v[2], v[6]); cex(v[3], v[7]);
    cex(v[0], v[2]); cex(v[1], v[3]); cex(v[4], v[6]); cex(v[5], v[7]);
    cex(v[0], v[1]); cex(v[2], v[3]); cex(v[4], v[5]); cex(v[6], v[7]);
}

// ================= fused encoder (+ conv-side linear precomputes) =========
// MODE 0: sv/pfc (src-side of a conv): write bf16 hi/lo planes + norms + Y.
// MODE 1: trk (dst-side): write f32 enc + f1/f2 conv bases (unchanged path).
template<int FIN, int MODE>
__device__ void encode64_body(const float* __restrict__ x,
    const float* __restrict__ W1, const float* __restrict__ b1,
    const float* __restrict__ W2, const float* __restrict__ b2,
    const float* __restrict__ conv_W, const float* __restrict__ conv_b,
    float* __restrict__ enc, float* __restrict__ e1, float* __restrict__ e2,
    unsigned short* __restrict__ hiP, unsigned short* __restrict__ loP,
    float* __restrict__ nrmP,
    int blk, float* smem)
{
    float* sx  = smem;              // up to 64*30
    float* sW1 = sx + 64 * 30;      // up to 30*32
    float* sW2 = sW1 + 30 * 32;     // 1024
    float* sWe = sW2 + 1024;        // 1024
    float* sb1 = sWe + 1024;
    float* sb2 = sb1 + 32;
    float* sbe = sb2 + 32;
    float* sh  = sbe + 32;          // 2048
    int tid = threadIdx.x;
    for (int i = tid; i < FIN * 32; i += 256) sW1[i] = W1[i];
    for (int i = tid; i < 1024; i += 256) sW2[i] = W2[i];
    if (MODE == 0) for (int i = tid; i < 1024; i += 256) sWe[i] = conv_W[1024 + i];
    if (MODE == 1) for (int i = tid; i < 1024; i += 256) sWe[i] = conv_W[i] - conv_W[1024 + i];
    if (tid < 32) {
        sb1[tid] = b1[tid]; sb2[tid] = b2[tid];
        sbe[tid] = (MODE == 1) ? conv_b[tid] : 0.f;
    }
    size_t node0 = (size_t)blk * 64;
    for (int i = tid; i < 64 * FIN; i += 256) sx[i] = x[node0 * FIN + i];
    __syncthreads();
    int g = tid >> 5, c = tid & 31;
    float o[8];
#pragma unroll
    for (int j = 0; j < 8; j++) {
        int n = g * 8 + j;
        float a = sb1[c];
#pragma unroll
        for (int f = 0; f < FIN; f++) a = fmaf(sx[n * FIN + f], sW1[f * 32 + c], a);
        sh[n * 32 + c] = elu_f(a);
    }
    __syncthreads();
#pragma unroll
    for (int j = 0; j < 8; j++) {
        int n = g * 8 + j;
        float a = sb2[c];
#pragma unroll
        for (int k = 0; k < 32; k++) a = fmaf(sh[n * 32 + k], sW2[k * 32 + c], a);
        o[j] = elu_f(a);
        if (MODE == 1) enc[(node0 + n) * 32 + c] = o[j];
    }
    if (MODE == 0) {
        // bf16 hi/lo planes + per-node norms (norm = cross-lane sum over c)
#pragma unroll
        for (int j = 0; j < 8; j++) {
            int n = g * 8 + j;
            float v = o[j];
            float a = v * v;
            a += __shfl_xor(a, 1);  a += __shfl_xor(a, 2);
            a += __shfl_xor(a, 4);  a += __shfl_xor(a, 8);
            a += __shfl_xor(a, 16);
            if (c == 0) nrmP[node0 + n] = a;
            unsigned h = bf16rn(v);
            float r = v - __uint_as_float(h << 16);
            unsigned l = bf16rn(r);
            hiP[(node0 + n) * 32 + c] = (unsigned short)h;
            loP[(node0 + n) * 32 + c] = (unsigned short)l;
        }
    }
    __syncthreads();
#pragma unroll
    for (int j = 0; j < 8; j++) sh[(g * 8 + j) * 32 + c] = o[j];
    __syncthreads();
#pragma unroll
    for (int j = 0; j < 8; j++) {
        int n = g * 8 + j;
        float a = sbe[c];
#pragma unroll
        for (int d = 0; d < 32; d++) a = fmaf(sh[n * 32 + d], sWe[d * 32 + c], a);
        size_t off = (node0 + n) * 32 + c;
        e1[off] = a;
        if (MODE == 1) e2[off] = a;
    }
}

// 4352 blocks: sv(256) | trk(2048) | pfc(2048)
__global__ __launch_bounds__(256) void encode_all_kernel(
    const float* __restrict__ x_sv, const float* __restrict__ x_trk, const float* __restrict__ x_pfc,
    const float* __restrict__ sv_W1, const float* __restrict__ sv_b1,
    const float* __restrict__ sv_W2, const float* __restrict__ sv_b2,
    const float* __restrict__ trk_W1, const float* __restrict__ trk_b1,
    const float* __restrict__ trk_W2, const float* __restrict__ trk_b2,
    const float* __restrict__ pfc_W1, const float* __restrict__ pfc_b1,
    const float* __restrict__ pfc_W2, const float* __restrict__ pfc_b2,
    const float* __restrict__ conv_W, const float* __restrict__ conv_b,
    float* __restrict__ trk_enc,
    float* __restrict__ Y1, float* __restrict__ Y2,
    float* __restrict__ f1, float* __restrict__ f2,
    unsigned short* __restrict__ svHi, unsigned short* __restrict__ svLo, float* __restrict__ nrm_sv,
    unsigned short* __restrict__ pfcHi, unsigned short* __restrict__ pfcLo, float* __restrict__ nrm_pfc)
{
    __shared__ float smem[64*30 + 30*32 + 1024 + 1024 + 96 + 2048];
    int bid = blockIdx.x;
    if (bid < 256)
        encode64_body<14, 0>(x_sv, sv_W1, sv_b1, sv_W2, sv_b2, conv_W, conv_b,
                             nullptr, Y1, nullptr, svHi, svLo, nrm_sv, bid, smem);
    else if (bid < 2304)
        encode64_body<30, 1>(x_trk, trk_W1, trk_b1, trk_W2, trk_b2, conv_W, conv_b,
                             trk_enc, f1, f2, nullptr, nullptr, nullptr, bid - 256, smem);
    else
        encode64_body<10, 0>(x_pfc, pfc_W1, pfc_b1, pfc_W2, pfc_b2, conv_W, conv_b,
                             nullptr, Y2, nullptr, pfcHi, pfcLo, nrm_pfc, bid - 2304, smem);
}

// ================= kNN via MFMA Gram tiles =================================
// Wave owns 16 dsts x all NT*16 srcs of one event. A = srcs (hi/lo planes,
// 16B fragment loads), B = 16 dst rows split to bf16 hi/lo in-register once.
// dot via 4 MFMAs (ll, lh, hl, hh). D layout (m89): col=lane&15 (dst),
// row=(lane>>4)*4+reg (src). Each lane top-8's its 128-src subset, then
// 2x shfl_xor(16,32) merges -> final top-8 per dst, written directly as u16.
template<int NT>
__device__ void knn_mfma_wave(
    const unsigned short* __restrict__ srcHi, const unsigned short* __restrict__ srcLo,
    const float* __restrict__ snrm,
    const float* __restrict__ dstF,
    int dstbase,
    unsigned short* __restrict__ idx_out)
{
    int lane = threadIdx.x & 63;
    int c = lane & 15, kg = lane >> 4;

    // ---- B fragment (16 dsts), f32 -> bf16 hi/lo, plus dst norm ----------
    const float* brow = dstF + (size_t)(dstbase + c) * 32 + kg * 8;
    float4 b0 = *(const float4*)(brow);
    float4 b1 = *(const float4*)(brow + 4);
    float bx[8] = {b0.x, b0.y, b0.z, b0.w, b1.x, b1.y, b1.z, b1.w};
    short8 Bh, Bl;
    float nd = 0.f;
#pragma unroll
    for (int i = 0; i < 8; i++) {
        float xv = bx[i];
        nd = fmaf(xv, xv, nd);
        unsigned h = bf16rn(xv);
        Bh[i] = (short)h;
        float r = xv - __uint_as_float(h << 16);
        Bl[i] = (short)bf16rn(r);
    }
    // full |d|^2: k-chunks live on lanes c, c+16, c+32, c+48
    nd += __shfl_xor(nd, 16);
    nd += __shfl_xor(nd, 32);

    unsigned key[8];
#pragma unroll
    for (int k = 0; k < 8; k++) key[k] = 0xFFFFFFFFu;

    for (int t = 0; t < NT; t++) {
        size_t arow = ((size_t)(t * 16 + c)) * 32 + (size_t)kg * 8;
        short8 Ah = *(const short8*)(srcHi + arow);
        short8 Al = *(const short8*)(srcLo + arow);
        f32x4 acc = {0.f, 0.f, 0.f, 0.f};
        acc = __builtin_amdgcn_mfma_f32_16x16x32_bf16(Al, Bl, acc, 0, 0, 0);
        acc = __builtin_amdgcn_mfma_f32_16x16x32_bf16(Al, Bh, acc, 0, 0, 0);
        acc = __builtin_amdgcn_mfma_f32_16x16x32_bf16(Ah, Bl, acc, 0, 0, 0);
        acc = __builtin_amdgcn_mfma_f32_16x16x32_bf16(Ah, Bh, acc, 0, 0, 0);
        float4 sn = *(const float4*)(snrm + t * 16 + kg * 4);
        int sb = t * 16 + kg * 4;
        unsigned cand[4];
        cand[0] = (__float_as_uint(fmaf(-2.f, acc[0], sn.x + nd)) & 0xFFFFFE00u) | (unsigned)(sb + 0);
        cand[1] = (__float_as_uint(fmaf(-2.f, acc[1], sn.y + nd)) & 0xFFFFFE00u) | (unsigned)(sb + 1);
        cand[2] = (__float_as_uint(fmaf(-2.f, acc[2], sn.z + nd)) & 0xFFFFFE00u) | (unsigned)(sb + 2);
        cand[3] = (__float_as_uint(fmaf(-2.f, acc[3], sn.w + nd)) & 0xFFFFFE00u) | (unsigned)(sb + 3);
        sort4(cand); merge8_4(key, cand);
    }

    // merge the 4 src-subsets (lanes c, c+16, c+32, c+48)
    unsigned oth[8];
#pragma unroll
    for (int k = 0; k < 8; k++) oth[k] = __shfl_xor(key[k], 16);
    merge8(key, oth);
#pragma unroll
    for (int k = 0; k < 8; k++) oth[k] = __shfl_xor(key[k], 32);
    merge8(key, oth);

    if (lane < 16) {
        uint4 o;
        o.x = (key[0] & 511u) | ((key[1] & 511u) << 16);
        o.y = (key[2] & 511u) | ((key[3] & 511u) << 16);
        o.z = (key[4] & 511u) | ((key[5] & 511u) << 16);
        o.w = (key[6] & 511u) | ((key[7] & 511u) << 16);
        *(uint4*)(idx_out + (size_t)(dstbase + c) * 8) = o;
    }
}

// knn12: 4096 blocks. bid<2048: conv2 (pfc->trk), else conv1 (sv->trk).
// e = bid&255 keeps an event's 8 dst-blocks on one XCD (bid%8 == e%8).
__global__ __launch_bounds__(256) void knn12_kernel(
    const unsigned short* __restrict__ svHi, const unsigned short* __restrict__ svLo,
    const float* __restrict__ nrm_sv,
    const unsigned short* __restrict__ pfcHi, const unsigned short* __restrict__ pfcLo,
    const float* __restrict__ nrm_pfc,
    const float* __restrict__ trk_enc,
    unsigned short* __restrict__ idx1, unsigned short* __restrict__ idx2)
{
    int bid = blockIdx.x;
    int wave = threadIdx.x >> 6;
    if (bid < 2048) {
        int e = bid & 255, j = bid >> 8;
        knn_mfma_wave<32>(pfcHi + (size_t)e * 512 * 32, pfcLo + (size_t)e * 512 * 32,
                          nrm_pfc + e * 512, trk_enc + (size_t)e * 512 * 32,
                          j * 64 + wave * 16, idx2 + (size_t)e * 512 * 8);
    } else {
        int b2 = bid - 2048;
        int e = b2 & 255, j = b2 >> 8;
        knn_mfma_wave<4>(svHi + (size_t)e * 64 * 32, svLo + (size_t)e * 64 * 32,
                         nrm_sv + e * 64, trk_enc + (size_t)e * 512 * 32,
                         j * 64 + wave * 16, idx1 + (size_t)e * 512 * 8);
    }
}

// knn3: 2048 blocks. src=f1 (hi/lo from g12), dst=f2 (f32).
__global__ __launch_bounds__(256) void knn3_kernel(
    const unsigned short* __restrict__ f1Hi, const unsigned short* __restrict__ f1Lo,
    const float* __restrict__ nrm_f1,
    const float* __restrict__ f2,
    unsigned short* __restrict__ idx3)
{
    int bid = blockIdx.x;
    int wave = threadIdx.x >> 6;
    int e = bid & 255, j = bid >> 8;
    knn_mfma_wave<32>(f1Hi + (size_t)e * 512 * 32, f1Lo + (size_t)e * 512 * 32,
                      nrm_f1 + e * 512, f2 + (size_t)e * 512 * 32,
                      j * 64 + wave * 16, idx3 + (size_t)e * 512 * 8);
}

// ================= gather helpers ==========================================
__device__ __forceinline__ void maxgather(const float* __restrict__ Ybase,
                                          const int* rows, float4* m)
{
    const float4* Yb = (const float4*)Ybase;
    const float4* r0 = Yb + (size_t)rows[0] * 8;
#pragma unroll
    for (int q = 0; q < 8; q++) m[q] = r0[q];
#pragma unroll
    for (int k = 1; k < 8; k++) {
        const float4* rr = Yb + (size_t)rows[k] * 8;
#pragma unroll
        for (int q = 0; q < 8; q++) {
            float4 v = rr[q];
            m[q].x = fmaxf(m[q].x, v.x); m[q].y = fmaxf(m[q].y, v.y);
            m[q].z = fmaxf(m[q].z, v.z); m[q].w = fmaxf(m[q].w, v.w);
        }
    }
}

__device__ __forceinline__ void decode_rows(const unsigned short* __restrict__ ip,
                                            size_t t, int* rows)
{
    uint4 u = *(const uint4*)(ip + t * 8);
    rows[0] = (int)(u.x & 0xffff); rows[1] = (int)(u.x >> 16);
    rows[2] = (int)(u.y & 0xffff); rows[3] = (int)(u.y >> 16);
    rows[4] = (int)(u.z & 0xffff); rows[5] = (int)(u.z >> 16);
    rows[6] = (int)(u.w & 0xffff); rows[7] = (int)(u.w >> 16);
}

// g12: 1024 blocks. f holds Base (from encoder); in-place f=elu(f+maxY).
// f1 branch also emits f1 hi/lo planes + norms for knn3.
__global__ __launch_bounds__(256) void g12_kernel(
    const float* __restrict__ Y1, const unsigned short* __restrict__ idx1, float* __restrict__ f1,
    const float* __restrict__ Y2, const unsigned short* __restrict__ idx2, float* __restrict__ f2,
    unsigned short* __restrict__ f1Hi, unsigned short* __restrict__ f1Lo,
    float* __restrict__ nrm_f1)
{
    int bid = blockIdx.x;
    int tid = threadIdx.x;
    int rows[8];
    float* fp;
    const float* Yb;
    int t;
    int isf1 = (bid < 512);
    if (isf1) {
        t = bid * 256 + tid;
        decode_rows(idx1, (size_t)t, rows);
        Yb = Y1 + (size_t)(t >> 9) * 64 * 32;
        fp = f1 + (size_t)t * 32;
    } else {
        t = (bid - 512) * 256 + tid;
        decode_rows(idx2, (size_t)t, rows);
        Yb = Y2 + (size_t)(t >> 9) * 512 * 32;
        fp = f2 + (size_t)t * 32;
    }
    float4 m[8];
    maxgather(Yb, rows, m);
    float4* op = (float4*)fp;
    float4 r[8];
#pragma unroll
    for (int q = 0; q < 8; q++) {
        float4 bv = op[q];
        r[q].x = elu_f(bv.x + m[q].x); r[q].y = elu_f(bv.y + m[q].y);
        r[q].z = elu_f(bv.z + m[q].z); r[q].w = elu_f(bv.w + m[q].w);
        op[q] = r[q];
    }
    if (isf1) {
        unsigned hw[16], lw[16];
        float nr = 0.f;
#pragma unroll
        for (int q = 0; q < 8; q++) {
            float4 v = r[q];
            nr = fmaf(v.x, v.x, nr); nr = fmaf(v.y, v.y, nr);
            nr = fmaf(v.z, v.z, nr); nr = fmaf(v.w, v.w, nr);
            unsigned h0 = bf16rn(v.x), h1 = bf16rn(v.y), h2 = bf16rn(v.z), h3 = bf16rn(v.w);
            unsigned l0 = bf16rn(v.x - __uint_as_float(h0 << 16));
            unsigned l1 = bf16rn(v.y - __uint_as_float(h1 << 16));
            unsigned l2 = bf16rn(v.z - __uint_as_float(h2 << 16));
            unsigned l3 = bf16rn(v.w - __uint_as_float(h3 << 16));
            hw[2*q]   = h0 | (h1 << 16); hw[2*q+1] = h2 | (h3 << 16);
            lw[2*q]   = l0 | (l1 << 16); lw[2*q+1] = l2 | (l3 << 16);
        }
        nrm_f1[t] = nr;
        uint4* hp = (uint4*)(f1Hi + (size_t)t * 32);
        uint4* lp = (uint4*)(f1Lo + (size_t)t * 32);
#pragma unroll
        for (int q = 0; q < 4; q++) {
            hp[q] = make_uint4(hw[4*q], hw[4*q+1], hw[4*q+2], hw[4*q+3]);
            lp[q] = make_uint4(lw[4*q], lw[4*q+1], lw[4*q+2], lw[4*q+3]);
        }
    }
}

// yb3: 4096 blocks: Y3 = f1@w2h (bid<2048) | B3 = f2@wd+bb
__global__ __launch_bounds__(256) void yb3_kernel(
    const float* __restrict__ f1, const float* __restrict__ f2,
    const float* __restrict__ conv_W, const float* __restrict__ conv_b,
    float* __restrict__ Y3, float* __restrict__ B3)
{
    __shared__ float sW[1024];
    __shared__ float sb[32];
    __shared__ float sx[8][32];
    int bid = blockIdx.x;
    int tid = threadIdx.x;
    int mode = (bid >= 2048);
    const float* X = mode ? f2 : f1;
    float* O = mode ? B3 : Y3;
    int rb = (mode ? bid - 2048 : bid) * 64;
    for (int i = tid; i < 1024; i += 256)
        sW[i] = mode ? (conv_W[i] - conv_W[1024 + i]) : conv_W[1024 + i];
    if (tid < 32) sb[tid] = mode ? conv_b[tid] : 0.f;
    int ln = tid >> 5, c = tid & 31;
    for (int p = 0; p < 8; p++) {
        __syncthreads();
        sx[ln][c] = X[(size_t)(rb + p * 8 + ln) * 32 + c];
        __syncthreads();
        float acc = sb[c];
#pragma unroll
        for (int d = 0; d < 32; d++) acc = fmaf(sx[ln][d], sW[d * 32 + c], acc);
        O[(size_t)(rb + p * 8 + ln) * 32 + c] = acc;
    }
}

// g3: 512 blocks. f3 rows in registers, reduced straight to pooled partials.
__global__ __launch_bounds__(256) void g3_kernel(
    const float* __restrict__ Y3, const float* __restrict__ B3,
    const unsigned short* __restrict__ idx3,
    float* __restrict__ pool)
{
    __shared__ float sp[4][32];
    int bid = blockIdx.x;
    int tid = threadIdx.x, lane = tid & 63, wave = tid >> 6;
    int t = bid * 256 + tid;
    int e = t >> 9;
    int rows[8];
    decode_rows(idx3, (size_t)t, rows);
    float4 m[8];
    maxgather(Y3 + (size_t)e * 512 * 32, rows, m);
    const float4* bp = (const float4*)(B3 + (size_t)t * 32);
    float4 r[8];
#pragma unroll
    for (int q = 0; q < 8; q++) {
        float4 bv = bp[q];
        r[q].x = elu_f(bv.x + m[q].x); r[q].y = elu_f(bv.y + m[q].y);
        r[q].z = elu_f(bv.z + m[q].z); r[q].w = elu_f(bv.w + m[q].w);
    }
    for (int off = 1; off < 64; off <<= 1) {
#pragma unroll
        for (int q = 0; q < 8; q++) {
            r[q].x += __shfl_xor(r[q].x, off);
            r[q].y += __shfl_xor(r[q].y, off);
            r[q].z += __shfl_xor(r[q].z, off);
            r[q].w += __shfl_xor(r[q].w, off);
        }
    }
    if (lane == 0) {
#pragma unroll
        for (int q = 0; q < 8; q++) {
            sp[wave][q*4+0] = r[q].x; sp[wave][q*4+1] = r[q].y;
            sp[wave][q*4+2] = r[q].z; sp[wave][q*4+3] = r[q].w;
        }
    }
    __syncthreads();
    if (tid < 32)
        pool[(size_t)bid * 32 + tid] = sp[0][tid] + sp[1][tid] + sp[2][tid] + sp[3][tid];
}

// final: 2 pooled partials per event + MLP + sigmoid + arange
__global__ __launch_bounds__(64) void final_kernel(
    const float* __restrict__ pool,
    const float* __restrict__ W1, const float* __restrict__ b1,
    const float* __restrict__ W2, const float* __restrict__ b2,
    float* __restrict__ outp)
{
    int b = blockIdx.x;
    int lane = threadIdx.x, c = lane & 31;
    __shared__ float sp[32];
    __shared__ float sh1[32];
    if (lane < 32)
        sp[c] = (pool[(size_t)(2*b) * 32 + c] + pool[(size_t)(2*b+1) * 32 + c]) * (1.0f / 512.0f);
    __syncthreads();
    if (lane < 32) {
        float h = b1[c];
#pragma unroll
        for (int d = 0; d < 32; d++) h = fmaf(sp[d], W1[d * 32 + c], h);
        sh1[c] = elu_f(h);
    }
    __syncthreads();
    if (lane == 0) {
        float o = b2[0];
#pragma unroll
        for (int d = 0; d < 32; d++) o = fmaf(sh1[d], W2[d], o);
        o = 1.f / (1.f + __expf(-o));
        outp[b] = o;
        outp[NB + b] = (float)b;
    }
}

extern "C" void kernel_launch(void* const* d_in, const int* in_sizes, int n_in,
                              void* d_out, int out_size, void* d_ws, size_t ws_size,
                              hipStream_t stream) {
    const float* x_sv  = (const float*)d_in[0];
    const float* x_trk = (const float*)d_in[1];
    const float* x_pfc = (const float*)d_in[2];
    const float* sv_W1  = (const float*)d_in[6];
    const float* sv_b1  = (const float*)d_in[7];
    const float* sv_W2  = (const float*)d_in[8];
    const float* sv_b2  = (const float*)d_in[9];
    const float* trk_W1 = (const float*)d_in[10];
    const float* trk_b1 = (const float*)d_in[11];
    const float* trk_W2 = (const float*)d_in[12];
    const float* trk_b2 = (const float*)d_in[13];
    const float* pfc_W1 = (const float*)d_in[14];
    const float* pfc_b1 = (const float*)d_in[15];
    const float* pfc_W2 = (const float*)d_in[16];
    const float* pfc_b2 = (const float*)d_in[17];
    const float* conv_W = (const float*)d_in[18];
    const float* conv_b = (const float*)d_in[19];
    const float* out_W1 = (const float*)d_in[20];
    const float* out_b1 = (const float*)d_in[21];
    const float* out_W2 = (const float*)d_in[22];
    const float* out_b2 = (const float*)d_in[23];

    float* ws = (float*)d_ws;
    const size_t SV_E  = (size_t)NB * 64 * 32;     //   524288
    const size_t TRK_E = (size_t)NB * 512 * 32;    //  4194304
    float* f1      = ws;
    float* f2      = f1 + TRK_E;
    float* trk_enc = f2 + TRK_E;                   // Y3 aliases after knn12
    float* Y1      = trk_enc + TRK_E;
    float* Y2      = Y1 + SV_E;
    unsigned short* svHi  = (unsigned short*)(Y2 + TRK_E);   // SV_E u16
    unsigned short* svLo  = svHi + SV_E;                     // pool aliases
    unsigned short* pfcHi = svLo + SV_E;                     // TRK_E u16
    unsigned short* pfcLo = pfcHi + TRK_E;                   // B3 aliases
    unsigned short* f1Hi  = pfcLo + TRK_E;
    unsigned short* f1Lo  = f1Hi + TRK_E;
    float* nrm_sv  = (float*)(f1Lo + TRK_E);                 // NB*64
    float* nrm_pfc = nrm_sv + (size_t)NB * 64;               // NB*512
    float* nrm_f1  = nrm_pfc + (size_t)NB * 512;             // NB*512
    unsigned short* idx1 = (unsigned short*)(nrm_f1 + (size_t)NB * 512); // NB*512*8
    unsigned short* idx2 = idx1 + (size_t)NB * 512 * 8;
    unsigned short* idx3 = idx2 + (size_t)NB * 512 * 8;
    float* Y3   = trk_enc;          // trk_enc dead after knn12
    float* B3   = (float*)pfcHi;    // pfc hi/lo planes dead after knn12
    float* pool = (float*)svHi;     // sv planes dead after knn12

    encode_all_kernel<<<4352, 256, 0, stream>>>(
        x_sv, x_trk, x_pfc,
        sv_W1, sv_b1, sv_W2, sv_b2,
        trk_W1, trk_b1, trk_W2, trk_b2,
        pfc_W1, pfc_b1, pfc_W2, pfc_b2,
        conv_W, conv_b,
        trk_enc, Y1, Y2, f1, f2,
        svHi, svLo, nrm_sv, pfcHi, pfcLo, nrm_pfc);

    knn12_kernel<<<4096, 256, 0, stream>>>(svHi, svLo, nrm_sv,
                                           pfcHi, pfcLo, nrm_pfc,
                                           trk_enc, idx1, idx2);
    g12_kernel<<<1024, 256, 0, stream>>>(Y1, idx1, f1, Y2, idx2, f2,
                                         f1Hi, f1Lo, nrm_f1);

    yb3_kernel<<<4096, 256, 0, stream>>>(f1, f2, conv_W, conv_b, Y3, B3);
    knn3_kernel<<<2048, 256, 0, stream>>>(f1Hi, f1Lo, nrm_f1, f2, idx3);
    g3_kernel<<<512, 256, 0, stream>>>(Y3, B3, idx3, pool);

    final_kernel<<<NB, 64, 0, stream>>>(pool, out_W1, out_b1, out_W2, out_b2, (float*)d_out);
}

// Round 5
// 432.395 us; speedup vs baseline: 1.2004x; 1.0647x over previous
//
#include <hip/hip_runtime.h>
#include <math.h>

#define NB 256      // events
#define KNN 8

typedef __attribute__((ext_vector_type(8))) short short8;
typedef __attribute__((ext_vector_type(4))) float f32x4;

__device__ __forceinline__ float elu_f(float x) {
    return x > 0.f ? x : __expf(x) - 1.f;
}

// round-to-nearest-even fp32 -> bf16 (returns low 16 bits)
__device__ __forceinline__ unsigned bf16rn(float x) {
    unsigned u = __float_as_uint(x);
    return (u + 0x7FFFu + ((u >> 16) & 1u)) >> 16;
}

// ---- sorting-network primitives on u32 keys -------------------------------
// key = (bits(dv) & ~511) | src_idx, dv >= 0 so raw-bit order == float order.
// Truncation to 512 ulp, tie-break lower-index-wins (validated r1-r4).
__device__ __forceinline__ void cex(unsigned& a, unsigned& b) {
    unsigned lo = min(a, b), hi = max(a, b);
    a = lo; b = hi;
}

__device__ __forceinline__ void sort4(unsigned* s) {
    cex(s[0], s[1]); cex(s[2], s[3]);
    cex(s[0], s[2]); cex(s[1], s[3]);
    cex(s[1], s[2]);
}

// v asc top-8; s asc 4 candidates -> v = 8 smallest of union, ascending.
__device__ __forceinline__ void merge8_4(unsigned* v, const unsigned* s) {
    v[4] = min(v[4], s[3]); v[5] = min(v[5], s[2]);
    v[6] = min(v[6], s[1]); v[7] = min(v[7], s[0]);
    cex(v[0], v[4]); cex(v[1], v[5]); cex(v[2], v[6]); cex(v[3], v[7]);
    cex(v[0], v[2]); cex(v[1], v[3]); cex(v[4], v[6]); cex(v[5], v[7]);
    cex(v[0], v[1]); cex(v[2], v[3]); cex(v[4], v[5]); cex(v[6], v[7]);
}

// v asc top-8, s asc 8 candidates -> v = 8 smallest of union, ascending.
__device__ __forceinline__ void merge8(unsigned* v, const unsigned* s) {
#pragma unroll
    for (int i = 0; i < 8; i++) v[i] = min(v[i], s[7 - i]);
    cex(v[0], v[4]); cex(v[1], v[5]); cex(v[2], v[6]); cex(v[3], v[7]);
    cex(v[0], v[2]); cex(v[1], v[3]); cex(v[4], v[6]); cex(v[5], v[7]);
    cex(v[0], v[1]); cex(v[2], v[3]); cex(v[4], v[5]); cex(v[6], v[7]);
}

// ================= fused encoder (+ conv-side linear precomputes) =========
// Register-weight version: lane c holds the weight COLUMN in wcol[32]
// (reused across the 3 phases); activations are read from LDS as b128
// broadcasts. FMA order identical to the validated scalar version ->
// bit-exact. MODE 0: sv/pfc (src-side): also emit bf16 hi/lo planes+norms.
// MODE 1: trk (dst-side): write f32 enc + f1/f2 conv bases.
template<int FIN, int MODE>
__device__ void encode64_body(const float* __restrict__ x,
    const float* __restrict__ W1, const float* __restrict__ b1,
    const float* __restrict__ W2, const float* __restrict__ b2,
    const float* __restrict__ conv_W, const float* __restrict__ conv_b,
    float* __restrict__ enc, float* __restrict__ e1, float* __restrict__ e2,
    unsigned short* __restrict__ hiP, unsigned short* __restrict__ loP,
    float* __restrict__ nrmP,
    int blk, float* smem)
{
    float* sx = smem;          // [64][32] zero-padded
    float* sh = smem + 2048;   // [64][32]
    int tid = threadIdx.x;
    int g = tid >> 5, c = tid & 31;
    size_t node0 = (size_t)blk * 64;

    // stage x zero-padded: consecutive tids cover f=0..31 of one node
    {
        const float* xb = x + node0 * FIN;
        for (int i = tid; i < 2048; i += 256) {
            int n = i >> 5, f = i & 31;
            sx[i] = (f < FIN) ? xb[n * FIN + f] : 0.f;
        }
    }

    float wcol[32];
#pragma unroll
    for (int f = 0; f < FIN; f++) wcol[f] = W1[f * 32 + c];
    float bias = b1[c];
    __syncthreads();

    float o[8];
    // ---- phase 1: h = elu(x @ W1 + b1) -----------------------------------
#pragma unroll
    for (int j = 0; j < 8; j++) {
        int n = g * 8 + j;
        const float4* xr = (const float4*)(sx + n * 32);
        float a = bias;
#pragma unroll
        for (int q = 0; q < 8; q++) {
            if (q * 4 < FIN) {
                float4 xx = xr[q];
                if (q * 4 + 0 < FIN) a = fmaf(xx.x, wcol[q * 4 + 0], a);
                if (q * 4 + 1 < FIN) a = fmaf(xx.y, wcol[q * 4 + 1], a);
                if (q * 4 + 2 < FIN) a = fmaf(xx.z, wcol[q * 4 + 2], a);
                if (q * 4 + 3 < FIN) a = fmaf(xx.w, wcol[q * 4 + 3], a);
            }
        }
        sh[n * 32 + c] = elu_f(a);
    }

#pragma unroll
    for (int k = 0; k < 32; k++) wcol[k] = W2[k * 32 + c];
    bias = b2[c];
    __syncthreads();

    // ---- phase 2: o = elu(h @ W2 + b2) -----------------------------------
#pragma unroll
    for (int j = 0; j < 8; j++) {
        int n = g * 8 + j;
        const float4* hr = (const float4*)(sh + n * 32);
        float a = bias;
#pragma unroll
        for (int q = 0; q < 8; q++) {
            float4 hh = hr[q];
            a = fmaf(hh.x, wcol[q * 4 + 0], a);
            a = fmaf(hh.y, wcol[q * 4 + 1], a);
            a = fmaf(hh.z, wcol[q * 4 + 2], a);
            a = fmaf(hh.w, wcol[q * 4 + 3], a);
        }
        o[j] = elu_f(a);
        if (MODE == 1) enc[(node0 + n) * 32 + c] = o[j];
    }

    if (MODE == 0) {
        // bf16 hi/lo planes + per-node norms (norm = cross-lane sum over c)
#pragma unroll
        for (int j = 0; j < 8; j++) {
            int n = g * 8 + j;
            float v = o[j];
            float a = v * v;
            a += __shfl_xor(a, 1);  a += __shfl_xor(a, 2);
            a += __shfl_xor(a, 4);  a += __shfl_xor(a, 8);
            a += __shfl_xor(a, 16);
            if (c == 0) nrmP[node0 + n] = a;
            unsigned h = bf16rn(v);
            float r = v - __uint_as_float(h << 16);
            unsigned l = bf16rn(r);
            hiP[(node0 + n) * 32 + c] = (unsigned short)h;
            loP[(node0 + n) * 32 + c] = (unsigned short)l;
        }
    }

    __syncthreads();   // all phase-2 reads of sh done
#pragma unroll
    for (int j = 0; j < 8; j++) sh[(g * 8 + j) * 32 + c] = o[j];
#pragma unroll
    for (int d = 0; d < 32; d++)
        wcol[d] = (MODE == 1) ? (conv_W[d * 32 + c] - conv_W[1024 + d * 32 + c])
                              : conv_W[1024 + d * 32 + c];
    bias = (MODE == 1) ? conv_b[c] : 0.f;
    __syncthreads();

    // ---- phase 3: conv-side linear precompute ----------------------------
#pragma unroll
    for (int j = 0; j < 8; j++) {
        int n = g * 8 + j;
        const float4* hr = (const float4*)(sh + n * 32);
        float a = bias;
#pragma unroll
        for (int q = 0; q < 8; q++) {
            float4 hh = hr[q];
            a = fmaf(hh.x, wcol[q * 4 + 0], a);
            a = fmaf(hh.y, wcol[q * 4 + 1], a);
            a = fmaf(hh.z, wcol[q * 4 + 2], a);
            a = fmaf(hh.w, wcol[q * 4 + 3], a);
        }
        size_t off = (node0 + n) * 32 + c;
        e1[off] = a;
        if (MODE == 1) e2[off] = a;
    }
}

// 4352 blocks: sv(256) | trk(2048) | pfc(2048)
__global__ __launch_bounds__(256) void encode_all_kernel(
    const float* __restrict__ x_sv, const float* __restrict__ x_trk, const float* __restrict__ x_pfc,
    const float* __restrict__ sv_W1, const float* __restrict__ sv_b1,
    const float* __restrict__ sv_W2, const float* __restrict__ sv_b2,
    const float* __restrict__ trk_W1, const float* __restrict__ trk_b1,
    const float* __restrict__ trk_W2, const float* __restrict__ trk_b2,
    const float* __restrict__ pfc_W1, const float* __restrict__ pfc_b1,
    const float* __restrict__ pfc_W2, const float* __restrict__ pfc_b2,
    const float* __restrict__ conv_W, const float* __restrict__ conv_b,
    float* __restrict__ trk_enc,
    float* __restrict__ Y1, float* __restrict__ Y2,
    float* __restrict__ f1, float* __restrict__ f2,
    unsigned short* __restrict__ svHi, unsigned short* __restrict__ svLo, float* __restrict__ nrm_sv,
    unsigned short* __restrict__ pfcHi, unsigned short* __restrict__ pfcLo, float* __restrict__ nrm_pfc)
{
    __shared__ float smem[4096];
    int bid = blockIdx.x;
    if (bid < 256)
        encode64_body<14, 0>(x_sv, sv_W1, sv_b1, sv_W2, sv_b2, conv_W, conv_b,
                             nullptr, Y1, nullptr, svHi, svLo, nrm_sv, bid, smem);
    else if (bid < 2304)
        encode64_body<30, 1>(x_trk, trk_W1, trk_b1, trk_W2, trk_b2, conv_W, conv_b,
                             trk_enc, f1, f2, nullptr, nullptr, nullptr, bid - 256, smem);
    else
        encode64_body<10, 0>(x_pfc, pfc_W1, pfc_b1, pfc_W2, pfc_b2, conv_W, conv_b,
                             nullptr, Y2, nullptr, pfcHi, pfcLo, nrm_pfc, bid - 2304, smem);
}

// ================= kNN via MFMA Gram tiles =================================
// Wave owns 16 dsts x all NT*16 srcs of one event. A = srcs (hi/lo planes,
// 16B fragment loads), B = 16 dst rows split to bf16 hi/lo in-register once.
// dot via 4 MFMAs (ll, lh, hl, hh). D layout (m89): col=lane&15 (dst),
// row=(lane>>4)*4+reg (src). Each lane top-8's its 128-src subset, then
// 2x shfl_xor(16,32) merges -> final top-8 per dst, written directly as u16.
template<int NT>
__device__ void knn_mfma_wave(
    const unsigned short* __restrict__ srcHi, const unsigned short* __restrict__ srcLo,
    const float* __restrict__ snrm,
    const float* __restrict__ dstF,
    int dstbase,
    unsigned short* __restrict__ idx_out)
{
    int lane = threadIdx.x & 63;
    int c = lane & 15, kg = lane >> 4;

    // ---- B fragment (16 dsts), f32 -> bf16 hi/lo, plus dst norm ----------
    const float* brow = dstF + (size_t)(dstbase + c) * 32 + kg * 8;
    float4 b0 = *(const float4*)(brow);
    float4 b1 = *(const float4*)(brow + 4);
    float bx[8] = {b0.x, b0.y, b0.z, b0.w, b1.x, b1.y, b1.z, b1.w};
    short8 Bh, Bl;
    float nd = 0.f;
#pragma unroll
    for (int i = 0; i < 8; i++) {
        float xv = bx[i];
        nd = fmaf(xv, xv, nd);
        unsigned h = bf16rn(xv);
        Bh[i] = (short)h;
        float r = xv - __uint_as_float(h << 16);
        Bl[i] = (short)bf16rn(r);
    }
    // full |d|^2: k-chunks live on lanes c, c+16, c+32, c+48
    nd += __shfl_xor(nd, 16);
    nd += __shfl_xor(nd, 32);

    unsigned key[8];
#pragma unroll
    for (int k = 0; k < 8; k++) key[k] = 0xFFFFFFFFu;

    for (int t = 0; t < NT; t++) {
        size_t arow = ((size_t)(t * 16 + c)) * 32 + (size_t)kg * 8;
        short8 Ah = *(const short8*)(srcHi + arow);
        short8 Al = *(const short8*)(srcLo + arow);
        f32x4 acc = {0.f, 0.f, 0.f, 0.f};
        acc = __builtin_amdgcn_mfma_f32_16x16x32_bf16(Al, Bl, acc, 0, 0, 0);
        acc = __builtin_amdgcn_mfma_f32_16x16x32_bf16(Al, Bh, acc, 0, 0, 0);
        acc = __builtin_amdgcn_mfma_f32_16x16x32_bf16(Ah, Bl, acc, 0, 0, 0);
        acc = __builtin_amdgcn_mfma_f32_16x16x32_bf16(Ah, Bh, acc, 0, 0, 0);
        float4 sn = *(const float4*)(snrm + t * 16 + kg * 4);
        int sb = t * 16 + kg * 4;
        unsigned cand[4];
        cand[0] = (__float_as_uint(fmaf(-2.f, acc[0], sn.x + nd)) & 0xFFFFFE00u) | (unsigned)(sb + 0);
        cand[1] = (__float_as_uint(fmaf(-2.f, acc[1], sn.y + nd)) & 0xFFFFFE00u) | (unsigned)(sb + 1);
        cand[2] = (__float_as_uint(fmaf(-2.f, acc[2], sn.z + nd)) & 0xFFFFFE00u) | (unsigned)(sb + 2);
        cand[3] = (__float_as_uint(fmaf(-2.f, acc[3], sn.w + nd)) & 0xFFFFFE00u) | (unsigned)(sb + 3);
        sort4(cand); merge8_4(key, cand);
    }

    // merge the 4 src-subsets (lanes c, c+16, c+32, c+48)
    unsigned oth[8];
#pragma unroll
    for (int k = 0; k < 8; k++) oth[k] = __shfl_xor(key[k], 16);
    merge8(key, oth);
#pragma unroll
    for (int k = 0; k < 8; k++) oth[k] = __shfl_xor(key[k], 32);
    merge8(key, oth);

    if (lane < 16) {
        uint4 o;
        o.x = (key[0] & 511u) | ((key[1] & 511u) << 16);
        o.y = (key[2] & 511u) | ((key[3] & 511u) << 16);
        o.z = (key[4] & 511u) | ((key[5] & 511u) << 16);
        o.w = (key[6] & 511u) | ((key[7] & 511u) << 16);
        *(uint4*)(idx_out + (size_t)(dstbase + c) * 8) = o;
    }
}

// knn12: 4096 blocks. bid<2048: conv2 (pfc->trk), else conv1 (sv->trk).
// e = bid&255 keeps an event's 8 dst-blocks on one XCD (bid%8 == e%8).
__global__ __launch_bounds__(256) void knn12_kernel(
    const unsigned short* __restrict__ svHi, const unsigned short* __restrict__ svLo,
    const float* __restrict__ nrm_sv,
    const unsigned short* __restrict__ pfcHi, const unsigned short* __restrict__ pfcLo,
    const float* __restrict__ nrm_pfc,
    const float* __restrict__ trk_enc,
    unsigned short* __restrict__ idx1, unsigned short* __restrict__ idx2)
{
    int bid = blockIdx.x;
    int wave = threadIdx.x >> 6;
    if (bid < 2048) {
        int e = bid & 255, j = bid >> 8;
        knn_mfma_wave<32>(pfcHi + (size_t)e * 512 * 32, pfcLo + (size_t)e * 512 * 32,
                          nrm_pfc + e * 512, trk_enc + (size_t)e * 512 * 32,
                          j * 64 + wave * 16, idx2 + (size_t)e * 512 * 8);
    } else {
        int b2 = bid - 2048;
        int e = b2 & 255, j = b2 >> 8;
        knn_mfma_wave<4>(svHi + (size_t)e * 64 * 32, svLo + (size_t)e * 64 * 32,
                         nrm_sv + e * 64, trk_enc + (size_t)e * 512 * 32,
                         j * 64 + wave * 16, idx1 + (size_t)e * 512 * 8);
    }
}

// knn3: 2048 blocks. src=f1 (hi/lo from g12), dst=f2 (f32).
__global__ __launch_bounds__(256) void knn3_kernel(
    const unsigned short* __restrict__ f1Hi, const unsigned short* __restrict__ f1Lo,
    const float* __restrict__ nrm_f1,
    const float* __restrict__ f2,
    unsigned short* __restrict__ idx3)
{
    int bid = blockIdx.x;
    int wave = threadIdx.x >> 6;
    int e = bid & 255, j = bid >> 8;
    knn_mfma_wave<32>(f1Hi + (size_t)e * 512 * 32, f1Lo + (size_t)e * 512 * 32,
                      nrm_f1 + e * 512, f2 + (size_t)e * 512 * 32,
                      j * 64 + wave * 16, idx3 + (size_t)e * 512 * 8);
}

// ================= gather helpers ==========================================
__device__ __forceinline__ void maxgather(const float* __restrict__ Ybase,
                                          const int* rows, float4* m)
{
    const float4* Yb = (const float4*)Ybase;
    const float4* r0 = Yb + (size_t)rows[0] * 8;
#pragma unroll
    for (int q = 0; q < 8; q++) m[q] = r0[q];
#pragma unroll
    for (int k = 1; k < 8; k++) {
        const float4* rr = Yb + (size_t)rows[k] * 8;
#pragma unroll
        for (int q = 0; q < 8; q++) {
            float4 v = rr[q];
            m[q].x = fmaxf(m[q].x, v.x); m[q].y = fmaxf(m[q].y, v.y);
            m[q].z = fmaxf(m[q].z, v.z); m[q].w = fmaxf(m[q].w, v.w);
        }
    }
}

__device__ __forceinline__ void decode_rows(const unsigned short* __restrict__ ip,
                                            size_t t, int* rows)
{
    uint4 u = *(const uint4*)(ip + t * 8);
    rows[0] = (int)(u.x & 0xffff); rows[1] = (int)(u.x >> 16);
    rows[2] = (int)(u.y & 0xffff); rows[3] = (int)(u.y >> 16);
    rows[4] = (int)(u.z & 0xffff); rows[5] = (int)(u.z >> 16);
    rows[6] = (int)(u.w & 0xffff); rows[7] = (int)(u.w >> 16);
}

// g12: 1024 blocks. f holds Base (from encoder); in-place f=elu(f+maxY).
// f1 branch also emits f1 hi/lo planes + norms for knn3.
__global__ __launch_bounds__(256) void g12_kernel(
    const float* __restrict__ Y1, const unsigned short* __restrict__ idx1, float* __restrict__ f1,
    const float* __restrict__ Y2, const unsigned short* __restrict__ idx2, float* __restrict__ f2,
    unsigned short* __restrict__ f1Hi, unsigned short* __restrict__ f1Lo,
    float* __restrict__ nrm_f1)
{
    int bid = blockIdx.x;
    int tid = threadIdx.x;
    int rows[8];
    float* fp;
    const float* Yb;
    int t;
    int isf1 = (bid < 512);
    if (isf1) {
        t = bid * 256 + tid;
        decode_rows(idx1, (size_t)t, rows);
        Yb = Y1 + (size_t)(t >> 9) * 64 * 32;
        fp = f1 + (size_t)t * 32;
    } else {
        t = (bid - 512) * 256 + tid;
        decode_rows(idx2, (size_t)t, rows);
        Yb = Y2 + (size_t)(t >> 9) * 512 * 32;
        fp = f2 + (size_t)t * 32;
    }
    float4 m[8];
    maxgather(Yb, rows, m);
    float4* op = (float4*)fp;
    float4 r[8];
#pragma unroll
    for (int q = 0; q < 8; q++) {
        float4 bv = op[q];
        r[q].x = elu_f(bv.x + m[q].x); r[q].y = elu_f(bv.y + m[q].y);
        r[q].z = elu_f(bv.z + m[q].z); r[q].w = elu_f(bv.w + m[q].w);
        op[q] = r[q];
    }
    if (isf1) {
        unsigned hw[16], lw[16];
        float nr = 0.f;
#pragma unroll
        for (int q = 0; q < 8; q++) {
            float4 v = r[q];
            nr = fmaf(v.x, v.x, nr); nr = fmaf(v.y, v.y, nr);
            nr = fmaf(v.z, v.z, nr); nr = fmaf(v.w, v.w, nr);
            unsigned h0 = bf16rn(v.x), h1 = bf16rn(v.y), h2 = bf16rn(v.z), h3 = bf16rn(v.w);
            unsigned l0 = bf16rn(v.x - __uint_as_float(h0 << 16));
            unsigned l1 = bf16rn(v.y - __uint_as_float(h1 << 16));
            unsigned l2 = bf16rn(v.z - __uint_as_float(h2 << 16));
            unsigned l3 = bf16rn(v.w - __uint_as_float(h3 << 16));
            hw[2*q]   = h0 | (h1 << 16); hw[2*q+1] = h2 | (h3 << 16);
            lw[2*q]   = l0 | (l1 << 16); lw[2*q+1] = l2 | (l3 << 16);
        }
        nrm_f1[t] = nr;
        uint4* hp = (uint4*)(f1Hi + (size_t)t * 32);
        uint4* lp = (uint4*)(f1Lo + (size_t)t * 32);
#pragma unroll
        for (int q = 0; q < 4; q++) {
            hp[q] = make_uint4(hw[4*q], hw[4*q+1], hw[4*q+2], hw[4*q+3]);
            lp[q] = make_uint4(lw[4*q], lw[4*q+1], lw[4*q+2], lw[4*q+3]);
        }
    }
}

// yb3: 4096 blocks: Y3 = f1@w2h (bid<2048) | B3 = f2@wd+bb.
// Register-weight version (bit-exact, d ascending).
__global__ __launch_bounds__(256) void yb3_kernel(
    const float* __restrict__ f1, const float* __restrict__ f2,
    const float* __restrict__ conv_W, const float* __restrict__ conv_b,
    float* __restrict__ Y3, float* __restrict__ B3)
{
    __shared__ float sx[8][32];
    int bid = blockIdx.x;
    int tid = threadIdx.x;
    int mode = (bid >= 2048);
    const float* X = mode ? f2 : f1;
    float* O = mode ? B3 : Y3;
    int rb = (mode ? bid - 2048 : bid) * 64;
    int ln = tid >> 5, c = tid & 31;
    float wcol[32];
#pragma unroll
    for (int d = 0; d < 32; d++)
        wcol[d] = mode ? (conv_W[d * 32 + c] - conv_W[1024 + d * 32 + c])
                       : conv_W[1024 + d * 32 + c];
    float bias = mode ? conv_b[c] : 0.f;
    for (int p = 0; p < 8; p++) {
        __syncthreads();
        sx[ln][c] = X[(size_t)(rb + p * 8 + ln) * 32 + c];
        __syncthreads();
        const float4* hr = (const float4*)(&sx[ln][0]);
        float acc = bias;
#pragma unroll
        for (int q = 0; q < 8; q++) {
            float4 hh = hr[q];
            acc = fmaf(hh.x, wcol[q * 4 + 0], acc);
            acc = fmaf(hh.y, wcol[q * 4 + 1], acc);
            acc = fmaf(hh.z, wcol[q * 4 + 2], acc);
            acc = fmaf(hh.w, wcol[q * 4 + 3], acc);
        }
        O[(size_t)(rb + p * 8 + ln) * 32 + c] = acc;
    }
}

// g3: 512 blocks. f3 rows in registers, reduced straight to pooled partials.
__global__ __launch_bounds__(256) void g3_kernel(
    const float* __restrict__ Y3, const float* __restrict__ B3,
    const unsigned short* __restrict__ idx3,
    float* __restrict__ pool)
{
    __shared__ float sp[4][32];
    int bid = blockIdx.x;
    int tid = threadIdx.x, lane = tid & 63, wave = tid >> 6;
    int t = bid * 256 + tid;
    int e = t >> 9;
    int rows[8];
    decode_rows(idx3, (size_t)t, rows);
    float4 m[8];
    maxgather(Y3 + (size_t)e * 512 * 32, rows, m);
    const float4* bp = (const float4*)(B3 + (size_t)t * 32);
    float4 r[8];
#pragma unroll
    for (int q = 0; q < 8; q++) {
        float4 bv = bp[q];
        r[q].x = elu_f(bv.x + m[q].x); r[q].y = elu_f(bv.y + m[q].y);
        r[q].z = elu_f(bv.z + m[q].z); r[q].w = elu_f(bv.w + m[q].w);
    }
    for (int off = 1; off < 64; off <<= 1) {
#pragma unroll
        for (int q = 0; q < 8; q++) {
            r[q].x += __shfl_xor(r[q].x, off);
            r[q].y += __shfl_xor(r[q].y, off);
            r[q].z += __shfl_xor(r[q].z, off);
            r[q].w += __shfl_xor(r[q].w, off);
        }
    }
    if (lane == 0) {
#pragma unroll
        for (int q = 0; q < 8; q++) {
            sp[wave][q*4+0] = r[q].x; sp[wave][q*4+1] = r[q].y;
            sp[wave][q*4+2] = r[q].z; sp[wave][q*4+3] = r[q].w;
        }
    }
    __syncthreads();
    if (tid < 32)
        pool[(size_t)bid * 32 + tid] = sp[0][tid] + sp[1][tid] + sp[2][tid] + sp[3][tid];
}

// final: 2 pooled partials per event + MLP + sigmoid + arange
__global__ __launch_bounds__(64) void final_kernel(
    const float* __restrict__ pool,
    const float* __restrict__ W1, const float* __restrict__ b1,
    const float* __restrict__ W2, const float* __restrict__ b2,
    float* __restrict__ outp)
{
    int b = blockIdx.x;
    int lane = threadIdx.x, c = lane & 31;
    __shared__ float sp[32];
    __shared__ float sh1[32];
    if (lane < 32)
        sp[c] = (pool[(size_t)(2*b) * 32 + c] + pool[(size_t)(2*b+1) * 32 + c]) * (1.0f / 512.0f);
    __syncthreads();
    if (lane < 32) {
        float h = b1[c];
#pragma unroll
        for (int d = 0; d < 32; d++) h = fmaf(sp[d], W1[d * 32 + c], h);
        sh1[c] = elu_f(h);
    }
    __syncthreads();
    if (lane == 0) {
        float o = b2[0];
#pragma unroll
        for (int d = 0; d < 32; d++) o = fmaf(sh1[d], W2[d], o);
        o = 1.f / (1.f + __expf(-o));
        outp[b] = o;
        outp[NB + b] = (float)b;
    }
}

extern "C" void kernel_launch(void* const* d_in, const int* in_sizes, int n_in,
                              void* d_out, int out_size, void* d_ws, size_t ws_size,
                              hipStream_t stream) {
    const float* x_sv  = (const float*)d_in[0];
    const float* x_trk = (const float*)d_in[1];
    const float* x_pfc = (const float*)d_in[2];
    const float* sv_W1  = (const float*)d_in[6];
    const float* sv_b1  = (const float*)d_in[7];
    const float* sv_W2  = (const float*)d_in[8];
    const float* sv_b2  = (const float*)d_in[9];
    const float* trk_W1 = (const float*)d_in[10];
    const float* trk_b1 = (const float*)d_in[11];
    const float* trk_W2 = (const float*)d_in[12];
    const float* trk_b2 = (const float*)d_in[13];
    const float* pfc_W1 = (const float*)d_in[14];
    const float* pfc_b1 = (const float*)d_in[15];
    const float* pfc_W2 = (const float*)d_in[16];
    const float* pfc_b2 = (const float*)d_in[17];
    const float* conv_W = (const float*)d_in[18];
    const float* conv_b = (const float*)d_in[19];
    const float* out_W1 = (const float*)d_in[20];
    const float* out_b1 = (const float*)d_in[21];
    const float* out_W2 = (const float*)d_in[22];
    const float* out_b2 = (const float*)d_in[23];

    float* ws = (float*)d_ws;
    const size_t SV_E  = (size_t)NB * 64 * 32;     //   524288
    const size_t TRK_E = (size_t)NB * 512 * 32;    //  4194304
    float* f1      = ws;
    float* f2      = f1 + TRK_E;
    float* trk_enc = f2 + TRK_E;                   // Y3 aliases after knn12
    float* Y1      = trk_enc + TRK_E;
    float* Y2      = Y1 + SV_E;
    unsigned short* svHi  = (unsigned short*)(Y2 + TRK_E);   // SV_E u16
    unsigned short* svLo  = svHi + SV_E;                     // pool aliases
    unsigned short* pfcHi = svLo + SV_E;                     // TRK_E u16
    unsigned short* pfcLo = pfcHi + TRK_E;                   // B3 aliases
    unsigned short* f1Hi  = pfcLo + TRK_E;
    unsigned short* f1Lo  = f1Hi + TRK_E;
    float* nrm_sv  = (float*)(f1Lo + TRK_E);                 // NB*64
    float* nrm_pfc = nrm_sv + (size_t)NB * 64;               // NB*512
    float* nrm_f1  = nrm_pfc + (size_t)NB * 512;             // NB*512
    unsigned short* idx1 = (unsigned short*)(nrm_f1 + (size_t)NB * 512); // NB*512*8
    unsigned short* idx2 = idx1 + (size_t)NB * 512 * 8;
    unsigned short* idx3 = idx2 + (size_t)NB * 512 * 8;
    float* Y3   = trk_enc;          // trk_enc dead after knn12
    float* B3   = (float*)pfcHi;    // pfc hi/lo planes dead after knn12
    float* pool = (float*)svHi;     // sv planes dead after knn12

    encode_all_kernel<<<4352, 256, 0, stream>>>(
        x_sv, x_trk, x_pfc,
        sv_W1, sv_b1, sv_W2, sv_b2,
        trk_W1, trk_b1, trk_W2, trk_b2,
        pfc_W1, pfc_b1, pfc_W2, pfc_b2,
        conv_W, conv_b,
        trk_enc, Y1, Y2, f1, f2,
        svHi, svLo, nrm_sv, pfcHi, pfcLo, nrm_pfc);

    knn12_kernel<<<4096, 256, 0, stream>>>(svHi, svLo, nrm_sv,
                                           pfcHi, pfcLo, nrm_pfc,
                                           trk_enc, idx1, idx2);
    g12_kernel<<<1024, 256, 0, stream>>>(Y1, idx1, f1, Y2, idx2, f2,
                                         f1Hi, f1Lo, nrm_f1);

    yb3_kernel<<<4096, 256, 0, stream>>>(f1, f2, conv_W, conv_b, Y3, B3);
    knn3_kernel<<<2048, 256, 0, stream>>>(f1Hi, f1Lo, nrm_f1, f2, idx3);
    g3_kernel<<<512, 256, 0, stream>>>(Y3, B3, idx3, pool);

    final_kernel<<<NB, 64, 0, stream>>>(pool, out_W1, out_b1, out_W2, out_b2, (float*)d_out);
}

// Round 6
// 337.264 us; speedup vs baseline: 1.5391x; 1.2821x over previous
//
#include <hip/hip_runtime.h>
#include <math.h>

#define NB 256      // events
#define KNN 8

typedef __attribute__((ext_vector_type(8))) short short8;
typedef __attribute__((ext_vector_type(4))) float f32x4;

__device__ __forceinline__ float elu_f(float x) {
    return x > 0.f ? x : __expf(x) - 1.f;
}

// round-to-nearest-even fp32 -> bf16 (returns low 16 bits)
__device__ __forceinline__ unsigned bf16rn(float x) {
    unsigned u = __float_as_uint(x);
    return (u + 0x7FFFu + ((u >> 16) & 1u)) >> 16;
}

// split fp32 -> (hi, lo) bf16 pair
__device__ __forceinline__ void bfsplit(float x, short& h, short& l) {
    unsigned hu = bf16rn(x);
    h = (short)hu;
    l = (short)bf16rn(x - __uint_as_float(hu << 16));
}

// ---- sorting-network primitives on u32 keys -------------------------------
// key = (bits(dv) & ~511) | src_idx, dv >= 0 so raw-bit order == float order.
// Truncation to 512 ulp, tie-break lower-index-wins (validated r1-r5).
__device__ __forceinline__ void cex(unsigned& a, unsigned& b) {
    unsigned lo = min(a, b), hi = max(a, b);
    a = lo; b = hi;
}

__device__ __forceinline__ void sort4(unsigned* s) {
    cex(s[0], s[1]); cex(s[2], s[3]);
    cex(s[0], s[2]); cex(s[1], s[3]);
    cex(s[1], s[2]);
}

// v asc top-8; s asc 4 candidates -> v = 8 smallest of union, ascending.
__device__ __forceinline__ void merge8_4(unsigned* v, const unsigned* s) {
    v[4] = min(v[4], s[3]); v[5] = min(v[5], s[2]);
    v[6] = min(v[6], s[1]); v[7] = min(v[7], s[0]);
    cex(v[0], v[4]); cex(v[1], v[5]); cex(v[2], v[6]); cex(v[3], v[7]);
    cex(v[0], v[2]); cex(v[1], v[3]); cex(v[4], v[6]); cex(v[5], v[7]);
    cex(v[0], v[1]); cex(v[2], v[3]); cex(v[4], v[5]); cex(v[6], v[7]);
}

// v asc top-8, s asc 8 candidates -> v = 8 smallest of union, ascending.
__device__ __forceinline__ void merge8(unsigned* v, const unsigned* s) {
#pragma unroll
    for (int i = 0; i < 8; i++) v[i] = min(v[i], s[7 - i]);
    cex(v[0], v[4]); cex(v[1], v[5]); cex(v[2], v[6]); cex(v[3], v[7]);
    cex(v[0], v[2]); cex(v[1], v[3]); cex(v[4], v[6]); cex(v[5], v[7]);
    cex(v[0], v[1]); cex(v[2], v[3]); cex(v[4], v[5]); cex(v[6], v[7]);
}

// ================= MFMA encoder (+ conv-side linear precomputes) ==========
// 256 nodes/block, 4 waves; wave owns 64 rows (4 row-tiles of 16).
// 3 chained GEMMs (K=32 each = one mfma_f32_16x16x32_bf16 K-tile), fp32
// operands hi/lo-bf16 split, 3 MFMAs per product (ll dropped, ~2^-17 rel).
// Phases hand off through wave-private LDS rows: only ONE barrier (stage).
// A-frag: lane(c=lane&15,kg=lane>>4) reads row tb+c, feats kg*8..+7.
// D: row = tb+kg*4+reg, col = lane&15 (+16 for 2nd col-tile)  [r4-validated].
// MODE 0 (sv/pfc): phase-3 A-read doubles as hi/lo plane emission + norms.
// MODE 1 (trk): phase 2 stores enc; phase 3 stores e1 AND e2.
template<int FIN, int MODE>
__device__ void encode_mfma_body(const float* __restrict__ x,
    const float* __restrict__ W1, const float* __restrict__ b1,
    const float* __restrict__ W2, const float* __restrict__ b2,
    const float* __restrict__ conv_W, const float* __restrict__ conv_b,
    float* __restrict__ enc, float* __restrict__ e1, float* __restrict__ e2,
    unsigned short* __restrict__ hiP, unsigned short* __restrict__ loP,
    float* __restrict__ nrmP,
    int blk, float* __restrict__ sx)
{
    int tid = threadIdx.x;
    int lane = tid & 63, wv = tid >> 6;
    int c = lane & 15, kg = lane >> 4;
    size_t node0 = (size_t)blk * 256;

    // cooperative stage, zero-padded to [256][32]
    {
        const float* xb = x + node0 * FIN;
        for (int i = tid; i < 8192; i += 256) {
            int n = i >> 5, f = i & 31;
            sx[i] = (f < FIN) ? xb[n * FIN + f] : 0.f;
        }
    }
    __syncthreads();

    int rb = wv * 64;   // wave-private rows [rb, rb+64)

#pragma unroll
    for (int ph = 0; ph < 3; ph++) {
        // ---- weight fragments (2 col-tiles, hi/lo) + bias ----------------
        short8 Bh0, Bl0, Bh1, Bl1;
#pragma unroll
        for (int e = 0; e < 8; e++) {
            int kk = kg * 8 + e;
            float w0, w1;
            if (ph == 0) {
                w0 = (kk < FIN) ? W1[kk * 32 + c] : 0.f;
                w1 = (kk < FIN) ? W1[kk * 32 + 16 + c] : 0.f;
            } else if (ph == 1) {
                w0 = W2[kk * 32 + c];
                w1 = W2[kk * 32 + 16 + c];
            } else {
                w0 = conv_W[1024 + kk * 32 + c];
                w1 = conv_W[1024 + kk * 32 + 16 + c];
                if (MODE == 1) {
                    w0 = conv_W[kk * 32 + c] - w0;
                    w1 = conv_W[kk * 32 + 16 + c] - w1;
                }
            }
            short h, l;
            bfsplit(w0, h, l); Bh0[e] = h; Bl0[e] = l;
            bfsplit(w1, h, l); Bh1[e] = h; Bl1[e] = l;
        }
        float bias0, bias1;
        if (ph == 0)      { bias0 = b1[c]; bias1 = b1[16 + c]; }
        else if (ph == 1) { bias0 = b2[c]; bias1 = b2[16 + c]; }
        else              { bias0 = (MODE == 1) ? conv_b[c] : 0.f;
                            bias1 = (MODE == 1) ? conv_b[16 + c] : 0.f; }

        // ---- 4 row-tiles -------------------------------------------------
#pragma unroll
        for (int t = 0; t < 4; t++) {
            int tb = rb + t * 16;
            int arow = tb + c;
            const float* ap = sx + arow * 32 + kg * 8;
            float4 a0 = *(const float4*)(ap);
            float4 a1 = *(const float4*)(ap + 4);
            float av[8] = {a0.x, a0.y, a0.z, a0.w, a1.x, a1.y, a1.z, a1.w};
            short8 Ah, Al;
#pragma unroll
            for (int e = 0; e < 8; e++) {
                short h, l;
                bfsplit(av[e], h, l);
                Ah[e] = h; Al[e] = l;
            }

            if (MODE == 0 && ph == 2) {
                // fuse: hi/lo plane emission + per-node norm (o == av here)
                float nr = 0.f;
#pragma unroll
                for (int e = 0; e < 8; e++) nr = fmaf(av[e], av[e], nr);
                nr += __shfl_xor(nr, 16);
                nr += __shfl_xor(nr, 32);
                if (kg == 0) nrmP[node0 + arow] = nr;
                *(short8*)(hiP + (node0 + arow) * 32 + kg * 8) = Ah;
                *(short8*)(loP + (node0 + arow) * 32 + kg * 8) = Al;
            }

            f32x4 acc0 = {bias0, bias0, bias0, bias0};
            f32x4 acc1 = {bias1, bias1, bias1, bias1};
            acc0 = __builtin_amdgcn_mfma_f32_16x16x32_bf16(Al, Bh0, acc0, 0, 0, 0);
            acc0 = __builtin_amdgcn_mfma_f32_16x16x32_bf16(Ah, Bl0, acc0, 0, 0, 0);
            acc0 = __builtin_amdgcn_mfma_f32_16x16x32_bf16(Ah, Bh0, acc0, 0, 0, 0);
            acc1 = __builtin_amdgcn_mfma_f32_16x16x32_bf16(Al, Bh1, acc1, 0, 0, 0);
            acc1 = __builtin_amdgcn_mfma_f32_16x16x32_bf16(Ah, Bl1, acc1, 0, 0, 0);
            acc1 = __builtin_amdgcn_mfma_f32_16x16x32_bf16(Ah, Bh1, acc1, 0, 0, 0);

            int drow = tb + kg * 4;
            if (ph < 2) {
#pragma unroll
                for (int r = 0; r < 4; r++) {
                    float v0 = elu_f(acc0[r]);
                    float v1 = elu_f(acc1[r]);
                    sx[(drow + r) * 32 + c] = v0;
                    sx[(drow + r) * 32 + 16 + c] = v1;
                    if (MODE == 1 && ph == 1) {
                        size_t off = (node0 + drow + r) * 32 + c;
                        enc[off] = v0;
                        enc[off + 16] = v1;
                    }
                }
            } else {
#pragma unroll
                for (int r = 0; r < 4; r++) {
                    size_t off = (node0 + drow + r) * 32 + c;
                    e1[off] = acc0[r];
                    e1[off + 16] = acc1[r];
                    if (MODE == 1) {
                        e2[off] = acc0[r];
                        e2[off + 16] = acc1[r];
                    }
                }
            }
        }
    }
}

// 1088 blocks: sv(64) | trk(512) | pfc(512); 256 nodes/block
__global__ __launch_bounds__(256) void encode_all_kernel(
    const float* __restrict__ x_sv, const float* __restrict__ x_trk, const float* __restrict__ x_pfc,
    const float* __restrict__ sv_W1, const float* __restrict__ sv_b1,
    const float* __restrict__ sv_W2, const float* __restrict__ sv_b2,
    const float* __restrict__ trk_W1, const float* __restrict__ trk_b1,
    const float* __restrict__ trk_W2, const float* __restrict__ trk_b2,
    const float* __restrict__ pfc_W1, const float* __restrict__ pfc_b1,
    const float* __restrict__ pfc_W2, const float* __restrict__ pfc_b2,
    const float* __restrict__ conv_W, const float* __restrict__ conv_b,
    float* __restrict__ trk_enc,
    float* __restrict__ Y1, float* __restrict__ Y2,
    float* __restrict__ f1, float* __restrict__ f2,
    unsigned short* __restrict__ svHi, unsigned short* __restrict__ svLo, float* __restrict__ nrm_sv,
    unsigned short* __restrict__ pfcHi, unsigned short* __restrict__ pfcLo, float* __restrict__ nrm_pfc)
{
    __shared__ float sx[8192];
    int bid = blockIdx.x;
    if (bid < 64)
        encode_mfma_body<14, 0>(x_sv, sv_W1, sv_b1, sv_W2, sv_b2, conv_W, conv_b,
                                nullptr, Y1, nullptr, svHi, svLo, nrm_sv, bid, sx);
    else if (bid < 576)
        encode_mfma_body<30, 1>(x_trk, trk_W1, trk_b1, trk_W2, trk_b2, conv_W, conv_b,
                                trk_enc, f1, f2, nullptr, nullptr, nullptr, bid - 64, sx);
    else
        encode_mfma_body<10, 0>(x_pfc, pfc_W1, pfc_b1, pfc_W2, pfc_b2, conv_W, conv_b,
                                nullptr, Y2, nullptr, pfcHi, pfcLo, nrm_pfc, bid - 576, sx);
}

// ================= kNN via MFMA Gram tiles (r4-validated) ==================
template<int NT>
__device__ void knn_mfma_wave(
    const unsigned short* __restrict__ srcHi, const unsigned short* __restrict__ srcLo,
    const float* __restrict__ snrm,
    const float* __restrict__ dstF,
    int dstbase,
    unsigned short* __restrict__ idx_out)
{
    int lane = threadIdx.x & 63;
    int c = lane & 15, kg = lane >> 4;

    // ---- B fragment (16 dsts), f32 -> bf16 hi/lo, plus dst norm ----------
    const float* brow = dstF + (size_t)(dstbase + c) * 32 + kg * 8;
    float4 b0 = *(const float4*)(brow);
    float4 b1 = *(const float4*)(brow + 4);
    float bx[8] = {b0.x, b0.y, b0.z, b0.w, b1.x, b1.y, b1.z, b1.w};
    short8 Bh, Bl;
    float nd = 0.f;
#pragma unroll
    for (int i = 0; i < 8; i++) {
        float xv = bx[i];
        nd = fmaf(xv, xv, nd);
        short h, l;
        bfsplit(xv, h, l);
        Bh[i] = h; Bl[i] = l;
    }
    nd += __shfl_xor(nd, 16);
    nd += __shfl_xor(nd, 32);

    unsigned key[8];
#pragma unroll
    for (int k = 0; k < 8; k++) key[k] = 0xFFFFFFFFu;

    for (int t = 0; t < NT; t++) {
        size_t arow = ((size_t)(t * 16 + c)) * 32 + (size_t)kg * 8;
        short8 Ah = *(const short8*)(srcHi + arow);
        short8 Al = *(const short8*)(srcLo + arow);
        f32x4 acc = {0.f, 0.f, 0.f, 0.f};
        acc = __builtin_amdgcn_mfma_f32_16x16x32_bf16(Al, Bl, acc, 0, 0, 0);
        acc = __builtin_amdgcn_mfma_f32_16x16x32_bf16(Al, Bh, acc, 0, 0, 0);
        acc = __builtin_amdgcn_mfma_f32_16x16x32_bf16(Ah, Bl, acc, 0, 0, 0);
        acc = __builtin_amdgcn_mfma_f32_16x16x32_bf16(Ah, Bh, acc, 0, 0, 0);
        float4 sn = *(const float4*)(snrm + t * 16 + kg * 4);
        int sb = t * 16 + kg * 4;
        unsigned cand[4];
        cand[0] = (__float_as_uint(fmaf(-2.f, acc[0], sn.x + nd)) & 0xFFFFFE00u) | (unsigned)(sb + 0);
        cand[1] = (__float_as_uint(fmaf(-2.f, acc[1], sn.y + nd)) & 0xFFFFFE00u) | (unsigned)(sb + 1);
        cand[2] = (__float_as_uint(fmaf(-2.f, acc[2], sn.z + nd)) & 0xFFFFFE00u) | (unsigned)(sb + 2);
        cand[3] = (__float_as_uint(fmaf(-2.f, acc[3], sn.w + nd)) & 0xFFFFFE00u) | (unsigned)(sb + 3);
        sort4(cand); merge8_4(key, cand);
    }

    unsigned oth[8];
#pragma unroll
    for (int k = 0; k < 8; k++) oth[k] = __shfl_xor(key[k], 16);
    merge8(key, oth);
#pragma unroll
    for (int k = 0; k < 8; k++) oth[k] = __shfl_xor(key[k], 32);
    merge8(key, oth);

    if (lane < 16) {
        uint4 o;
        o.x = (key[0] & 511u) | ((key[1] & 511u) << 16);
        o.y = (key[2] & 511u) | ((key[3] & 511u) << 16);
        o.z = (key[4] & 511u) | ((key[5] & 511u) << 16);
        o.w = (key[6] & 511u) | ((key[7] & 511u) << 16);
        *(uint4*)(idx_out + (size_t)(dstbase + c) * 8) = o;
    }
}

// knn12: 4096 blocks. bid<2048: conv2 (pfc->trk), else conv1 (sv->trk).
__global__ __launch_bounds__(256) void knn12_kernel(
    const unsigned short* __restrict__ svHi, const unsigned short* __restrict__ svLo,
    const float* __restrict__ nrm_sv,
    const unsigned short* __restrict__ pfcHi, const unsigned short* __restrict__ pfcLo,
    const float* __restrict__ nrm_pfc,
    const float* __restrict__ trk_enc,
    unsigned short* __restrict__ idx1, unsigned short* __restrict__ idx2)
{
    int bid = blockIdx.x;
    int wave = threadIdx.x >> 6;
    if (bid < 2048) {
        int e = bid & 255, j = bid >> 8;
        knn_mfma_wave<32>(pfcHi + (size_t)e * 512 * 32, pfcLo + (size_t)e * 512 * 32,
                          nrm_pfc + e * 512, trk_enc + (size_t)e * 512 * 32,
                          j * 64 + wave * 16, idx2 + (size_t)e * 512 * 8);
    } else {
        int b2 = bid - 2048;
        int e = b2 & 255, j = b2 >> 8;
        knn_mfma_wave<4>(svHi + (size_t)e * 64 * 32, svLo + (size_t)e * 64 * 32,
                         nrm_sv + e * 64, trk_enc + (size_t)e * 512 * 32,
                         j * 64 + wave * 16, idx1 + (size_t)e * 512 * 8);
    }
}

// knn3: 2048 blocks. src=f1 (hi/lo from g12), dst=f2 (f32).
__global__ __launch_bounds__(256) void knn3_kernel(
    const unsigned short* __restrict__ f1Hi, const unsigned short* __restrict__ f1Lo,
    const float* __restrict__ nrm_f1,
    const float* __restrict__ f2,
    unsigned short* __restrict__ idx3)
{
    int bid = blockIdx.x;
    int wave = threadIdx.x >> 6;
    int e = bid & 255, j = bid >> 8;
    knn_mfma_wave<32>(f1Hi + (size_t)e * 512 * 32, f1Lo + (size_t)e * 512 * 32,
                      nrm_f1 + e * 512, f2 + (size_t)e * 512 * 32,
                      j * 64 + wave * 16, idx3 + (size_t)e * 512 * 8);
}

// ================= gather helpers ==========================================
__device__ __forceinline__ void maxgather(const float* __restrict__ Ybase,
                                          const int* rows, float4* m)
{
    const float4* Yb = (const float4*)Ybase;
    const float4* r0 = Yb + (size_t)rows[0] * 8;
#pragma unroll
    for (int q = 0; q < 8; q++) m[q] = r0[q];
#pragma unroll
    for (int k = 1; k < 8; k++) {
        const float4* rr = Yb + (size_t)rows[k] * 8;
#pragma unroll
        for (int q = 0; q < 8; q++) {
            float4 v = rr[q];
            m[q].x = fmaxf(m[q].x, v.x); m[q].y = fmaxf(m[q].y, v.y);
            m[q].z = fmaxf(m[q].z, v.z); m[q].w = fmaxf(m[q].w, v.w);
        }
    }
}

__device__ __forceinline__ void decode_rows(const unsigned short* __restrict__ ip,
                                            size_t t, int* rows)
{
    uint4 u = *(const uint4*)(ip + t * 8);
    rows[0] = (int)(u.x & 0xffff); rows[1] = (int)(u.x >> 16);
    rows[2] = (int)(u.y & 0xffff); rows[3] = (int)(u.y >> 16);
    rows[4] = (int)(u.z & 0xffff); rows[5] = (int)(u.z >> 16);
    rows[6] = (int)(u.w & 0xffff); rows[7] = (int)(u.w >> 16);
}

// g12: 1024 blocks. f holds Base (from encoder); in-place f=elu(f+maxY).
// f1 branch also emits f1 hi/lo planes + norms for knn3.
__global__ __launch_bounds__(256) void g12_kernel(
    const float* __restrict__ Y1, const unsigned short* __restrict__ idx1, float* __restrict__ f1,
    const float* __restrict__ Y2, const unsigned short* __restrict__ idx2, float* __restrict__ f2,
    unsigned short* __restrict__ f1Hi, unsigned short* __restrict__ f1Lo,
    float* __restrict__ nrm_f1)
{
    int bid = blockIdx.x;
    int tid = threadIdx.x;
    int rows[8];
    float* fp;
    const float* Yb;
    int t;
    int isf1 = (bid < 512);
    if (isf1) {
        t = bid * 256 + tid;
        decode_rows(idx1, (size_t)t, rows);
        Yb = Y1 + (size_t)(t >> 9) * 64 * 32;
        fp = f1 + (size_t)t * 32;
    } else {
        t = (bid - 512) * 256 + tid;
        decode_rows(idx2, (size_t)t, rows);
        Yb = Y2 + (size_t)(t >> 9) * 512 * 32;
        fp = f2 + (size_t)t * 32;
    }
    float4 m[8];
    maxgather(Yb, rows, m);
    float4* op = (float4*)fp;
    float4 r[8];
#pragma unroll
    for (int q = 0; q < 8; q++) {
        float4 bv = op[q];
        r[q].x = elu_f(bv.x + m[q].x); r[q].y = elu_f(bv.y + m[q].y);
        r[q].z = elu_f(bv.z + m[q].z); r[q].w = elu_f(bv.w + m[q].w);
        op[q] = r[q];
    }
    if (isf1) {
        unsigned hw[16], lw[16];
        float nr = 0.f;
#pragma unroll
        for (int q = 0; q < 8; q++) {
            float4 v = r[q];
            nr = fmaf(v.x, v.x, nr); nr = fmaf(v.y, v.y, nr);
            nr = fmaf(v.z, v.z, nr); nr = fmaf(v.w, v.w, nr);
            unsigned h0 = bf16rn(v.x), h1 = bf16rn(v.y), h2 = bf16rn(v.z), h3 = bf16rn(v.w);
            unsigned l0 = bf16rn(v.x - __uint_as_float(h0 << 16));
            unsigned l1 = bf16rn(v.y - __uint_as_float(h1 << 16));
            unsigned l2 = bf16rn(v.z - __uint_as_float(h2 << 16));
            unsigned l3 = bf16rn(v.w - __uint_as_float(h3 << 16));
            hw[2*q]   = h0 | (h1 << 16); hw[2*q+1] = h2 | (h3 << 16);
            lw[2*q]   = l0 | (l1 << 16); lw[2*q+1] = l2 | (l3 << 16);
        }
        nrm_f1[t] = nr;
        uint4* hp = (uint4*)(f1Hi + (size_t)t * 32);
        uint4* lp = (uint4*)(f1Lo + (size_t)t * 32);
#pragma unroll
        for (int q = 0; q < 4; q++) {
            hp[q] = make_uint4(hw[4*q], hw[4*q+1], hw[4*q+2], hw[4*q+3]);
            lp[q] = make_uint4(lw[4*q], lw[4*q+1], lw[4*q+2], lw[4*q+3]);
        }
    }
}

// yb3: 4096 blocks: Y3 = f1@w2h (bid<2048) | B3 = f2@wd+bb.
__global__ __launch_bounds__(256) void yb3_kernel(
    const float* __restrict__ f1, const float* __restrict__ f2,
    const float* __restrict__ conv_W, const float* __restrict__ conv_b,
    float* __restrict__ Y3, float* __restrict__ B3)
{
    __shared__ float sx[8][32];
    int bid = blockIdx.x;
    int tid = threadIdx.x;
    int mode = (bid >= 2048);
    const float* X = mode ? f2 : f1;
    float* O = mode ? B3 : Y3;
    int rb = (mode ? bid - 2048 : bid) * 64;
    int ln = tid >> 5, c = tid & 31;
    float wcol[32];
#pragma unroll
    for (int d = 0; d < 32; d++)
        wcol[d] = mode ? (conv_W[d * 32 + c] - conv_W[1024 + d * 32 + c])
                       : conv_W[1024 + d * 32 + c];
    float bias = mode ? conv_b[c] : 0.f;
    for (int p = 0; p < 8; p++) {
        __syncthreads();
        sx[ln][c] = X[(size_t)(rb + p * 8 + ln) * 32 + c];
        __syncthreads();
        const float4* hr = (const float4*)(&sx[ln][0]);
        float acc = bias;
#pragma unroll
        for (int q = 0; q < 8; q++) {
            float4 hh = hr[q];
            acc = fmaf(hh.x, wcol[q * 4 + 0], acc);
            acc = fmaf(hh.y, wcol[q * 4 + 1], acc);
            acc = fmaf(hh.z, wcol[q * 4 + 2], acc);
            acc = fmaf(hh.w, wcol[q * 4 + 3], acc);
        }
        O[(size_t)(rb + p * 8 + ln) * 32 + c] = acc;
    }
}

// g3: 512 blocks. f3 rows in registers, reduced straight to pooled partials.
__global__ __launch_bounds__(256) void g3_kernel(
    const float* __restrict__ Y3, const float* __restrict__ B3,
    const unsigned short* __restrict__ idx3,
    float* __restrict__ pool)
{
    __shared__ float sp[4][32];
    int bid = blockIdx.x;
    int tid = threadIdx.x, lane = tid & 63, wave = tid >> 6;
    int t = bid * 256 + tid;
    int e = t >> 9;
    int rows[8];
    decode_rows(idx3, (size_t)t, rows);
    float4 m[8];
    maxgather(Y3 + (size_t)e * 512 * 32, rows, m);
    const float4* bp = (const float4*)(B3 + (size_t)t * 32);
    float4 r[8];
#pragma unroll
    for (int q = 0; q < 8; q++) {
        float4 bv = bp[q];
        r[q].x = elu_f(bv.x + m[q].x); r[q].y = elu_f(bv.y + m[q].y);
        r[q].z = elu_f(bv.z + m[q].z); r[q].w = elu_f(bv.w + m[q].w);
    }
    for (int off = 1; off < 64; off <<= 1) {
#pragma unroll
        for (int q = 0; q < 8; q++) {
            r[q].x += __shfl_xor(r[q].x, off);
            r[q].y += __shfl_xor(r[q].y, off);
            r[q].z += __shfl_xor(r[q].z, off);
            r[q].w += __shfl_xor(r[q].w, off);
        }
    }
    if (lane == 0) {
#pragma unroll
        for (int q = 0; q < 8; q++) {
            sp[wave][q*4+0] = r[q].x; sp[wave][q*4+1] = r[q].y;
            sp[wave][q*4+2] = r[q].z; sp[wave][q*4+3] = r[q].w;
        }
    }
    __syncthreads();
    if (tid < 32)
        pool[(size_t)bid * 32 + tid] = sp[0][tid] + sp[1][tid] + sp[2][tid] + sp[3][tid];
}

// final: 2 pooled partials per event + MLP + sigmoid + arange
__global__ __launch_bounds__(64) void final_kernel(
    const float* __restrict__ pool,
    const float* __restrict__ W1, const float* __restrict__ b1,
    const float* __restrict__ W2, const float* __restrict__ b2,
    float* __restrict__ outp)
{
    int b = blockIdx.x;
    int lane = threadIdx.x, c = lane & 31;
    __shared__ float sp[32];
    __shared__ float sh1[32];
    if (lane < 32)
        sp[c] = (pool[(size_t)(2*b) * 32 + c] + pool[(size_t)(2*b+1) * 32 + c]) * (1.0f / 512.0f);
    __syncthreads();
    if (lane < 32) {
        float h = b1[c];
#pragma unroll
        for (int d = 0; d < 32; d++) h = fmaf(sp[d], W1[d * 32 + c], h);
        sh1[c] = elu_f(h);
    }
    __syncthreads();
    if (lane == 0) {
        float o = b2[0];
#pragma unroll
        for (int d = 0; d < 32; d++) o = fmaf(sh1[d], W2[d], o);
        o = 1.f / (1.f + __expf(-o));
        outp[b] = o;
        outp[NB + b] = (float)b;
    }
}

extern "C" void kernel_launch(void* const* d_in, const int* in_sizes, int n_in,
                              void* d_out, int out_size, void* d_ws, size_t ws_size,
                              hipStream_t stream) {
    const float* x_sv  = (const float*)d_in[0];
    const float* x_trk = (const float*)d_in[1];
    const float* x_pfc = (const float*)d_in[2];
    const float* sv_W1  = (const float*)d_in[6];
    const float* sv_b1  = (const float*)d_in[7];
    const float* sv_W2  = (const float*)d_in[8];
    const float* sv_b2  = (const float*)d_in[9];
    const float* trk_W1 = (const float*)d_in[10];
    const float* trk_b1 = (const float*)d_in[11];
    const float* trk_W2 = (const float*)d_in[12];
    const float* trk_b2 = (const float*)d_in[13];
    const float* pfc_W1 = (const float*)d_in[14];
    const float* pfc_b1 = (const float*)d_in[15];
    const float* pfc_W2 = (const float*)d_in[16];
    const float* pfc_b2 = (const float*)d_in[17];
    const float* conv_W = (const float*)d_in[18];
    const float* conv_b = (const float*)d_in[19];
    const float* out_W1 = (const float*)d_in[20];
    const float* out_b1 = (const float*)d_in[21];
    const float* out_W2 = (const float*)d_in[22];
    const float* out_b2 = (const float*)d_in[23];

    float* ws = (float*)d_ws;
    const size_t SV_E  = (size_t)NB * 64 * 32;     //   524288
    const size_t TRK_E = (size_t)NB * 512 * 32;    //  4194304
    float* f1      = ws;
    float* f2      = f1 + TRK_E;
    float* trk_enc = f2 + TRK_E;                   // Y3 aliases after knn12
    float* Y1      = trk_enc + TRK_E;
    float* Y2      = Y1 + SV_E;
    unsigned short* svHi  = (unsigned short*)(Y2 + TRK_E);   // SV_E u16
    unsigned short* svLo  = svHi + SV_E;                     // pool aliases
    unsigned short* pfcHi = svLo + SV_E;                     // TRK_E u16
    unsigned short* pfcLo = pfcHi + TRK_E;                   // B3 aliases
    unsigned short* f1Hi  = pfcLo + TRK_E;
    unsigned short* f1Lo  = f1Hi + TRK_E;
    float* nrm_sv  = (float*)(f1Lo + TRK_E);                 // NB*64
    float* nrm_pfc = nrm_sv + (size_t)NB * 64;               // NB*512
    float* nrm_f1  = nrm_pfc + (size_t)NB * 512;             // NB*512
    unsigned short* idx1 = (unsigned short*)(nrm_f1 + (size_t)NB * 512); // NB*512*8
    unsigned short* idx2 = idx1 + (size_t)NB * 512 * 8;
    unsigned short* idx3 = idx2 + (size_t)NB * 512 * 8;
    float* Y3   = trk_enc;          // trk_enc dead after knn12
    float* B3   = (float*)pfcHi;    // pfc hi/lo planes dead after knn12
    float* pool = (float*)svHi;     // sv planes dead after knn12

    encode_all_kernel<<<1088, 256, 0, stream>>>(
        x_sv, x_trk, x_pfc,
        sv_W1, sv_b1, sv_W2, sv_b2,
        trk_W1, trk_b1, trk_W2, trk_b2,
        pfc_W1, pfc_b1, pfc_W2, pfc_b2,
        conv_W, conv_b,
        trk_enc, Y1, Y2, f1, f2,
        svHi, svLo, nrm_sv, pfcHi, pfcLo, nrm_pfc);

    knn12_kernel<<<4096, 256, 0, stream>>>(svHi, svLo, nrm_sv,
                                           pfcHi, pfcLo, nrm_pfc,
                                           trk_enc, idx1, idx2);
    g12_kernel<<<1024, 256, 0, stream>>>(Y1, idx1, f1, Y2, idx2, f2,
                                         f1Hi, f1Lo, nrm_f1);

    yb3_kernel<<<4096, 256, 0, stream>>>(f1, f2, conv_W, conv_b, Y3, B3);
    knn3_kernel<<<2048, 256, 0, stream>>>(f1Hi, f1Lo, nrm_f1, f2, idx3);
    g3_kernel<<<512, 256, 0, stream>>>(Y3, B3, idx3, pool);

    final_kernel<<<NB, 64, 0, stream>>>(pool, out_W1, out_b1, out_W2, out_b2, (float*)d_out);
}

// Round 7
// 316.253 us; speedup vs baseline: 1.6413x; 1.0664x over previous
//
#include <hip/hip_runtime.h>
#include <math.h>

#define NB 256      // events
#define KNN 8

typedef __attribute__((ext_vector_type(8))) short short8;
typedef __attribute__((ext_vector_type(4))) float f32x4;

__device__ __forceinline__ float elu_f(float x) {
    return x > 0.f ? x : __expf(x) - 1.f;
}

// round-to-nearest-even fp32 -> bf16 (returns low 16 bits)
__device__ __forceinline__ unsigned bf16rn(float x) {
    unsigned u = __float_as_uint(x);
    return (u + 0x7FFFu + ((u >> 16) & 1u)) >> 16;
}

// split fp32 -> (hi, lo) bf16 pair
__device__ __forceinline__ void bfsplit(float x, short& h, short& l) {
    unsigned hu = bf16rn(x);
    h = (short)hu;
    l = (short)bf16rn(x - __uint_as_float(hu << 16));
}

// ---- sorting-network primitives on u32 keys -------------------------------
// key = (bits(dv) & ~511) | src_idx, dv >= 0 so raw-bit order == float order.
// Truncation to 512 ulp, tie-break lower-index-wins (validated r1-r6).
__device__ __forceinline__ void cex(unsigned& a, unsigned& b) {
    unsigned lo = min(a, b), hi = max(a, b);
    a = lo; b = hi;
}

// Batcher odd-even mergesort, 8 elements, 19 CE (validated r1).
__device__ __forceinline__ void sort8(unsigned* s) {
    cex(s[0], s[1]); cex(s[2], s[3]); cex(s[4], s[5]); cex(s[6], s[7]);
    cex(s[0], s[2]); cex(s[1], s[3]); cex(s[4], s[6]); cex(s[5], s[7]);
    cex(s[1], s[2]); cex(s[5], s[6]);
    cex(s[0], s[4]); cex(s[1], s[5]); cex(s[2], s[6]); cex(s[3], s[7]);
    cex(s[2], s[4]); cex(s[3], s[5]);
    cex(s[1], s[2]); cex(s[3], s[4]); cex(s[5], s[6]);
}

// v asc top-8, s asc 8 candidates -> v = 8 smallest of union, ascending.
__device__ __forceinline__ void merge8(unsigned* v, const unsigned* s) {
#pragma unroll
    for (int i = 0; i < 8; i++) v[i] = min(v[i], s[7 - i]);
    cex(v[0], v[4]); cex(v[1], v[5]); cex(v[2], v[6]); cex(v[3], v[7]);
    cex(v[0], v[2]); cex(v[1], v[3]); cex(v[4], v[6]); cex(v[5], v[7]);
    cex(v[0], v[1]); cex(v[2], v[3]); cex(v[4], v[5]); cex(v[6], v[7]);
}

// ================= MFMA encoder (+ conv-side linear precomputes) ==========
// (r6-validated) 256 nodes/block, 4 waves; wave owns 64 rows.
template<int FIN, int MODE>
__device__ void encode_mfma_body(const float* __restrict__ x,
    const float* __restrict__ W1, const float* __restrict__ b1,
    const float* __restrict__ W2, const float* __restrict__ b2,
    const float* __restrict__ conv_W, const float* __restrict__ conv_b,
    float* __restrict__ enc, float* __restrict__ e1, float* __restrict__ e2,
    unsigned short* __restrict__ hiP, unsigned short* __restrict__ loP,
    float* __restrict__ nrmP,
    int blk, float* __restrict__ sx)
{
    int tid = threadIdx.x;
    int lane = tid & 63, wv = tid >> 6;
    int c = lane & 15, kg = lane >> 4;
    size_t node0 = (size_t)blk * 256;

    {
        const float* xb = x + node0 * FIN;
        for (int i = tid; i < 8192; i += 256) {
            int n = i >> 5, f = i & 31;
            sx[i] = (f < FIN) ? xb[n * FIN + f] : 0.f;
        }
    }
    __syncthreads();

    int rb = wv * 64;

#pragma unroll
    for (int ph = 0; ph < 3; ph++) {
        short8 Bh0, Bl0, Bh1, Bl1;
#pragma unroll
        for (int e = 0; e < 8; e++) {
            int kk = kg * 8 + e;
            float w0, w1;
            if (ph == 0) {
                w0 = (kk < FIN) ? W1[kk * 32 + c] : 0.f;
                w1 = (kk < FIN) ? W1[kk * 32 + 16 + c] : 0.f;
            } else if (ph == 1) {
                w0 = W2[kk * 32 + c];
                w1 = W2[kk * 32 + 16 + c];
            } else {
                w0 = conv_W[1024 + kk * 32 + c];
                w1 = conv_W[1024 + kk * 32 + 16 + c];
                if (MODE == 1) {
                    w0 = conv_W[kk * 32 + c] - w0;
                    w1 = conv_W[kk * 32 + 16 + c] - w1;
                }
            }
            short h, l;
            bfsplit(w0, h, l); Bh0[e] = h; Bl0[e] = l;
            bfsplit(w1, h, l); Bh1[e] = h; Bl1[e] = l;
        }
        float bias0, bias1;
        if (ph == 0)      { bias0 = b1[c]; bias1 = b1[16 + c]; }
        else if (ph == 1) { bias0 = b2[c]; bias1 = b2[16 + c]; }
        else              { bias0 = (MODE == 1) ? conv_b[c] : 0.f;
                            bias1 = (MODE == 1) ? conv_b[16 + c] : 0.f; }

#pragma unroll
        for (int t = 0; t < 4; t++) {
            int tb = rb + t * 16;
            int arow = tb + c;
            const float* ap = sx + arow * 32 + kg * 8;
            float4 a0 = *(const float4*)(ap);
            float4 a1 = *(const float4*)(ap + 4);
            float av[8] = {a0.x, a0.y, a0.z, a0.w, a1.x, a1.y, a1.z, a1.w};
            short8 Ah, Al;
#pragma unroll
            for (int e = 0; e < 8; e++) {
                short h, l;
                bfsplit(av[e], h, l);
                Ah[e] = h; Al[e] = l;
            }

            if (MODE == 0 && ph == 2) {
                float nr = 0.f;
#pragma unroll
                for (int e = 0; e < 8; e++) nr = fmaf(av[e], av[e], nr);
                nr += __shfl_xor(nr, 16);
                nr += __shfl_xor(nr, 32);
                if (kg == 0) nrmP[node0 + arow] = nr;
                *(short8*)(hiP + (node0 + arow) * 32 + kg * 8) = Ah;
                *(short8*)(loP + (node0 + arow) * 32 + kg * 8) = Al;
            }

            f32x4 acc0 = {bias0, bias0, bias0, bias0};
            f32x4 acc1 = {bias1, bias1, bias1, bias1};
            acc0 = __builtin_amdgcn_mfma_f32_16x16x32_bf16(Al, Bh0, acc0, 0, 0, 0);
            acc0 = __builtin_amdgcn_mfma_f32_16x16x32_bf16(Ah, Bl0, acc0, 0, 0, 0);
            acc0 = __builtin_amdgcn_mfma_f32_16x16x32_bf16(Ah, Bh0, acc0, 0, 0, 0);
            acc1 = __builtin_amdgcn_mfma_f32_16x16x32_bf16(Al, Bh1, acc1, 0, 0, 0);
            acc1 = __builtin_amdgcn_mfma_f32_16x16x32_bf16(Ah, Bl1, acc1, 0, 0, 0);
            acc1 = __builtin_amdgcn_mfma_f32_16x16x32_bf16(Ah, Bh1, acc1, 0, 0, 0);

            int drow = tb + kg * 4;
            if (ph < 2) {
#pragma unroll
                for (int r = 0; r < 4; r++) {
                    float v0 = elu_f(acc0[r]);
                    float v1 = elu_f(acc1[r]);
                    sx[(drow + r) * 32 + c] = v0;
                    sx[(drow + r) * 32 + 16 + c] = v1;
                    if (MODE == 1 && ph == 1) {
                        size_t off = (node0 + drow + r) * 32 + c;
                        enc[off] = v0;
                        enc[off + 16] = v1;
                    }
                }
            } else {
#pragma unroll
                for (int r = 0; r < 4; r++) {
                    size_t off = (node0 + drow + r) * 32 + c;
                    e1[off] = acc0[r];
                    e1[off + 16] = acc1[r];
                    if (MODE == 1) {
                        e2[off] = acc0[r];
                        e2[off + 16] = acc1[r];
                    }
                }
            }
        }
    }
}

// 1088 blocks: sv(64) | trk(512) | pfc(512); 256 nodes/block
__global__ __launch_bounds__(256) void encode_all_kernel(
    const float* __restrict__ x_sv, const float* __restrict__ x_trk, const float* __restrict__ x_pfc,
    const float* __restrict__ sv_W1, const float* __restrict__ sv_b1,
    const float* __restrict__ sv_W2, const float* __restrict__ sv_b2,
    const float* __restrict__ trk_W1, const float* __restrict__ trk_b1,
    const float* __restrict__ trk_W2, const float* __restrict__ trk_b2,
    const float* __restrict__ pfc_W1, const float* __restrict__ pfc_b1,
    const float* __restrict__ pfc_W2, const float* __restrict__ pfc_b2,
    const float* __restrict__ conv_W, const float* __restrict__ conv_b,
    float* __restrict__ trk_enc,
    float* __restrict__ Y1, float* __restrict__ Y2,
    float* __restrict__ f1, float* __restrict__ f2,
    unsigned short* __restrict__ svHi, unsigned short* __restrict__ svLo, float* __restrict__ nrm_sv,
    unsigned short* __restrict__ pfcHi, unsigned short* __restrict__ pfcLo, float* __restrict__ nrm_pfc)
{
    __shared__ float sx[8192];
    int bid = blockIdx.x;
    if (bid < 64)
        encode_mfma_body<14, 0>(x_sv, sv_W1, sv_b1, sv_W2, sv_b2, conv_W, conv_b,
                                nullptr, Y1, nullptr, svHi, svLo, nrm_sv, bid, sx);
    else if (bid < 576)
        encode_mfma_body<30, 1>(x_trk, trk_W1, trk_b1, trk_W2, trk_b2, conv_W, conv_b,
                                trk_enc, f1, f2, nullptr, nullptr, nullptr, bid - 64, sx);
    else
        encode_mfma_body<10, 0>(x_pfc, pfc_W1, pfc_b1, pfc_W2, pfc_b2, conv_W, conv_b,
                                nullptr, Y2, nullptr, pfcHi, pfcLo, nrm_pfc, bid - 576, sx);
}

// ================= kNN via MFMA Gram tiles =================================
// build B fragment (16 dsts) from f32 rows; hi/lo split + full dst norm
__device__ __forceinline__ void knn_build_B(const float* __restrict__ dstF,
                                            int dstbase, int c, int kg,
                                            short8& Bh, short8& Bl, float& nd)
{
    const float* brow = dstF + (size_t)(dstbase + c) * 32 + kg * 8;
    float4 b0 = *(const float4*)(brow);
    float4 b1 = *(const float4*)(brow + 4);
    float bx[8] = {b0.x, b0.y, b0.z, b0.w, b1.x, b1.y, b1.z, b1.w};
    nd = 0.f;
#pragma unroll
    for (int i = 0; i < 8; i++) {
        float xv = bx[i];
        nd = fmaf(xv, xv, nd);
        short h, l;
        bfsplit(xv, h, l);
        Bh[i] = h; Bl[i] = l;
    }
    nd += __shfl_xor(nd, 16);
    nd += __shfl_xor(nd, 32);
}

// scan NT tiles (NT even): batch-8 candidates (2 tiles) -> sort8 + merge8.
template<int NT>
__device__ __forceinline__ void knn_scan(
    const unsigned short* __restrict__ srcHi, const unsigned short* __restrict__ srcLo,
    const float* __restrict__ snrm,
    short8 Bh, short8 Bl, float nd, int c, int kg,
    unsigned* key)
{
    for (int t = 0; t < NT; t += 2) {
        unsigned cand[8];
#pragma unroll
        for (int u = 0; u < 2; u++) {
            int tt = t + u;
            size_t arow = ((size_t)(tt * 16 + c)) * 32 + (size_t)kg * 8;
            short8 Ah = *(const short8*)(srcHi + arow);
            short8 Al = *(const short8*)(srcLo + arow);
            f32x4 acc = {0.f, 0.f, 0.f, 0.f};
            acc = __builtin_amdgcn_mfma_f32_16x16x32_bf16(Al, Bl, acc, 0, 0, 0);
            acc = __builtin_amdgcn_mfma_f32_16x16x32_bf16(Al, Bh, acc, 0, 0, 0);
            acc = __builtin_amdgcn_mfma_f32_16x16x32_bf16(Ah, Bl, acc, 0, 0, 0);
            acc = __builtin_amdgcn_mfma_f32_16x16x32_bf16(Ah, Bh, acc, 0, 0, 0);
            float4 sn = *(const float4*)(snrm + tt * 16 + kg * 4);
            int sb = tt * 16 + kg * 4;
            cand[u*4+0] = (__float_as_uint(fmaf(-2.f, acc[0], sn.x + nd)) & 0xFFFFFE00u) | (unsigned)(sb + 0);
            cand[u*4+1] = (__float_as_uint(fmaf(-2.f, acc[1], sn.y + nd)) & 0xFFFFFE00u) | (unsigned)(sb + 1);
            cand[u*4+2] = (__float_as_uint(fmaf(-2.f, acc[2], sn.z + nd)) & 0xFFFFFE00u) | (unsigned)(sb + 2);
            cand[u*4+3] = (__float_as_uint(fmaf(-2.f, acc[3], sn.w + nd)) & 0xFFFFFE00u) | (unsigned)(sb + 3);
        }
        sort8(cand);
        merge8(key, cand);
    }
}

// cross-lane merge of the 4 src-subsets + packed u16 store (lane<16)
__device__ __forceinline__ void knn_finalize(unsigned* key, int lane,
                                             unsigned short* __restrict__ idx_out,
                                             int dstbase)
{
    unsigned oth[8];
#pragma unroll
    for (int k = 0; k < 8; k++) oth[k] = __shfl_xor(key[k], 16);
    merge8(key, oth);
#pragma unroll
    for (int k = 0; k < 8; k++) oth[k] = __shfl_xor(key[k], 32);
    merge8(key, oth);
    if (lane < 16) {
        uint4 o;
        o.x = (key[0] & 511u) | ((key[1] & 511u) << 16);
        o.y = (key[2] & 511u) | ((key[3] & 511u) << 16);
        o.z = (key[4] & 511u) | ((key[5] & 511u) << 16);
        o.w = (key[6] & 511u) | ((key[7] & 511u) << 16);
        *(uint4*)(idx_out + (size_t)(dstbase + lane) * 8) = o;
    }
}

// knn12: 2048 blocks. Wave builds its 16-dst B fragment ONCE, then scans
// pfc (32 tiles -> idx2) and sv (4 tiles -> idx1).
__global__ __launch_bounds__(256) void knn12_kernel(
    const unsigned short* __restrict__ svHi, const unsigned short* __restrict__ svLo,
    const float* __restrict__ nrm_sv,
    const unsigned short* __restrict__ pfcHi, const unsigned short* __restrict__ pfcLo,
    const float* __restrict__ nrm_pfc,
    const float* __restrict__ trk_enc,
    unsigned short* __restrict__ idx1, unsigned short* __restrict__ idx2)
{
    int bid = blockIdx.x;
    int e = bid & 255, j = bid >> 8;
    int lane = threadIdx.x & 63, wave = threadIdx.x >> 6;
    int c = lane & 15, kg = lane >> 4;
    int dstbase = j * 64 + wave * 16;

    short8 Bh, Bl;
    float nd;
    knn_build_B(trk_enc + (size_t)e * 512 * 32, dstbase, c, kg, Bh, Bl, nd);

    unsigned key[8];
#pragma unroll
    for (int k = 0; k < 8; k++) key[k] = 0xFFFFFFFFu;
    knn_scan<32>(pfcHi + (size_t)e * 512 * 32, pfcLo + (size_t)e * 512 * 32,
                 nrm_pfc + e * 512, Bh, Bl, nd, c, kg, key);
    knn_finalize(key, lane, idx2 + (size_t)e * 512 * 8, dstbase);

#pragma unroll
    for (int k = 0; k < 8; k++) key[k] = 0xFFFFFFFFu;
    knn_scan<4>(svHi + (size_t)e * 64 * 32, svLo + (size_t)e * 64 * 32,
                nrm_sv + e * 64, Bh, Bl, nd, c, kg, key);
    knn_finalize(key, lane, idx1 + (size_t)e * 512 * 8, dstbase);
}

// knn3: 2048 blocks. src=f1 (hi/lo from g12), dst=f2 (f32).
__global__ __launch_bounds__(256) void knn3_kernel(
    const unsigned short* __restrict__ f1Hi, const unsigned short* __restrict__ f1Lo,
    const float* __restrict__ nrm_f1,
    const float* __restrict__ f2,
    unsigned short* __restrict__ idx3)
{
    int bid = blockIdx.x;
    int e = bid & 255, j = bid >> 8;
    int lane = threadIdx.x & 63, wave = threadIdx.x >> 6;
    int c = lane & 15, kg = lane >> 4;
    int dstbase = j * 64 + wave * 16;

    short8 Bh, Bl;
    float nd;
    knn_build_B(f2 + (size_t)e * 512 * 32, dstbase, c, kg, Bh, Bl, nd);

    unsigned key[8];
#pragma unroll
    for (int k = 0; k < 8; k++) key[k] = 0xFFFFFFFFu;
    knn_scan<32>(f1Hi + (size_t)e * 512 * 32, f1Lo + (size_t)e * 512 * 32,
                 nrm_f1 + e * 512, Bh, Bl, nd, c, kg, key);
    knn_finalize(key, lane, idx3 + (size_t)e * 512 * 8, dstbase);
}

// ================= gather helpers ==========================================
__device__ __forceinline__ void maxgather(const float* __restrict__ Ybase,
                                          const int* rows, float4* m)
{
    const float4* Yb = (const float4*)Ybase;
    const float4* r0 = Yb + (size_t)rows[0] * 8;
#pragma unroll
    for (int q = 0; q < 8; q++) m[q] = r0[q];
#pragma unroll
    for (int k = 1; k < 8; k++) {
        const float4* rr = Yb + (size_t)rows[k] * 8;
#pragma unroll
        for (int q = 0; q < 8; q++) {
            float4 v = rr[q];
            m[q].x = fmaxf(m[q].x, v.x); m[q].y = fmaxf(m[q].y, v.y);
            m[q].z = fmaxf(m[q].z, v.z); m[q].w = fmaxf(m[q].w, v.w);
        }
    }
}

__device__ __forceinline__ void decode_rows(const unsigned short* __restrict__ ip,
                                            size_t t, int* rows)
{
    uint4 u = *(const uint4*)(ip + t * 8);
    rows[0] = (int)(u.x & 0xffff); rows[1] = (int)(u.x >> 16);
    rows[2] = (int)(u.y & 0xffff); rows[3] = (int)(u.y >> 16);
    rows[4] = (int)(u.z & 0xffff); rows[5] = (int)(u.z >> 16);
    rows[6] = (int)(u.w & 0xffff); rows[7] = (int)(u.w >> 16);
}

// g12: 1024 blocks. f holds Base (from encoder); in-place f=elu(f+maxY).
// f1 branch also emits f1 hi/lo planes + norms for knn3.
__global__ __launch_bounds__(256) void g12_kernel(
    const float* __restrict__ Y1, const unsigned short* __restrict__ idx1, float* __restrict__ f1,
    const float* __restrict__ Y2, const unsigned short* __restrict__ idx2, float* __restrict__ f2,
    unsigned short* __restrict__ f1Hi, unsigned short* __restrict__ f1Lo,
    float* __restrict__ nrm_f1)
{
    int bid = blockIdx.x;
    int tid = threadIdx.x;
    int rows[8];
    float* fp;
    const float* Yb;
    int t;
    int isf1 = (bid < 512);
    if (isf1) {
        t = bid * 256 + tid;
        decode_rows(idx1, (size_t)t, rows);
        Yb = Y1 + (size_t)(t >> 9) * 64 * 32;
        fp = f1 + (size_t)t * 32;
    } else {
        t = (bid - 512) * 256 + tid;
        decode_rows(idx2, (size_t)t, rows);
        Yb = Y2 + (size_t)(t >> 9) * 512 * 32;
        fp = f2 + (size_t)t * 32;
    }
    float4 m[8];
    maxgather(Yb, rows, m);
    float4* op = (float4*)fp;
    float4 r[8];
#pragma unroll
    for (int q = 0; q < 8; q++) {
        float4 bv = op[q];
        r[q].x = elu_f(bv.x + m[q].x); r[q].y = elu_f(bv.y + m[q].y);
        r[q].z = elu_f(bv.z + m[q].z); r[q].w = elu_f(bv.w + m[q].w);
        op[q] = r[q];
    }
    if (isf1) {
        unsigned hw[16], lw[16];
        float nr = 0.f;
#pragma unroll
        for (int q = 0; q < 8; q++) {
            float4 v = r[q];
            nr = fmaf(v.x, v.x, nr); nr = fmaf(v.y, v.y, nr);
            nr = fmaf(v.z, v.z, nr); nr = fmaf(v.w, v.w, nr);
            unsigned h0 = bf16rn(v.x), h1 = bf16rn(v.y), h2 = bf16rn(v.z), h3 = bf16rn(v.w);
            unsigned l0 = bf16rn(v.x - __uint_as_float(h0 << 16));
            unsigned l1 = bf16rn(v.y - __uint_as_float(h1 << 16));
            unsigned l2 = bf16rn(v.z - __uint_as_float(h2 << 16));
            unsigned l3 = bf16rn(v.w - __uint_as_float(h3 << 16));
            hw[2*q]   = h0 | (h1 << 16); hw[2*q+1] = h2 | (h3 << 16);
            lw[2*q]   = l0 | (l1 << 16); lw[2*q+1] = l2 | (l3 << 16);
        }
        nrm_f1[t] = nr;
        uint4* hp = (uint4*)(f1Hi + (size_t)t * 32);
        uint4* lp = (uint4*)(f1Lo + (size_t)t * 32);
#pragma unroll
        for (int q = 0; q < 4; q++) {
            hp[q] = make_uint4(hw[4*q], hw[4*q+1], hw[4*q+2], hw[4*q+3]);
            lp[q] = make_uint4(lw[4*q], lw[4*q+1], lw[4*q+2], lw[4*q+3]);
        }
    }
}

// yb3 via MFMA: 1024 blocks x 256 rows. bid<512: Y3 = f1@w2h; else B3 =
// f2@wd + bb. Mirrors encoder phase 3 (same 3-MFMA accumulation order).
__global__ __launch_bounds__(256) void yb3_kernel(
    const float* __restrict__ f1, const float* __restrict__ f2,
    const float* __restrict__ conv_W, const float* __restrict__ conv_b,
    float* __restrict__ Y3, float* __restrict__ B3)
{
    int bid = blockIdx.x;
    int mode = (bid >= 512);
    const float* X = mode ? f2 : f1;
    float* O = mode ? B3 : Y3;
    size_t node0 = (size_t)(mode ? bid - 512 : bid) * 256;
    int tid = threadIdx.x, lane = tid & 63, wv = tid >> 6;
    int c = lane & 15, kg = lane >> 4;

    short8 Bh0, Bl0, Bh1, Bl1;
#pragma unroll
    for (int e = 0; e < 8; e++) {
        int kk = kg * 8 + e;
        float w0 = conv_W[1024 + kk * 32 + c];
        float w1 = conv_W[1024 + kk * 32 + 16 + c];
        if (mode) {
            w0 = conv_W[kk * 32 + c] - w0;
            w1 = conv_W[kk * 32 + 16 + c] - w1;
        }
        short h, l;
        bfsplit(w0, h, l); Bh0[e] = h; Bl0[e] = l;
        bfsplit(w1, h, l); Bh1[e] = h; Bl1[e] = l;
    }
    float bias0 = mode ? conv_b[c] : 0.f;
    float bias1 = mode ? conv_b[16 + c] : 0.f;

    int rb = wv * 64;
#pragma unroll
    for (int t = 0; t < 4; t++) {
        int tb = rb + t * 16;
        int arow = tb + c;
        const float* ap = X + (node0 + arow) * 32 + kg * 8;
        float4 a0 = *(const float4*)(ap);
        float4 a1 = *(const float4*)(ap + 4);
        float av[8] = {a0.x, a0.y, a0.z, a0.w, a1.x, a1.y, a1.z, a1.w};
        short8 Ah, Al;
#pragma unroll
        for (int e = 0; e < 8; e++) {
            short h, l;
            bfsplit(av[e], h, l);
            Ah[e] = h; Al[e] = l;
        }
        f32x4 acc0 = {bias0, bias0, bias0, bias0};
        f32x4 acc1 = {bias1, bias1, bias1, bias1};
        acc0 = __builtin_amdgcn_mfma_f32_16x16x32_bf16(Al, Bh0, acc0, 0, 0, 0);
        acc0 = __builtin_amdgcn_mfma_f32_16x16x32_bf16(Ah, Bl0, acc0, 0, 0, 0);
        acc0 = __builtin_amdgcn_mfma_f32_16x16x32_bf16(Ah, Bh0, acc0, 0, 0, 0);
        acc1 = __builtin_amdgcn_mfma_f32_16x16x32_bf16(Al, Bh1, acc1, 0, 0, 0);
        acc1 = __builtin_amdgcn_mfma_f32_16x16x32_bf16(Ah, Bl1, acc1, 0, 0, 0);
        acc1 = __builtin_amdgcn_mfma_f32_16x16x32_bf16(Ah, Bh1, acc1, 0, 0, 0);

        int drow = tb + kg * 4;
#pragma unroll
        for (int r = 0; r < 4; r++) {
            size_t off = (node0 + drow + r) * 32 + c;
            O[off] = acc0[r];
            O[off + 16] = acc1[r];
        }
    }
}

// g3: 512 blocks. f3 rows in registers, reduced straight to pooled partials.
__global__ __launch_bounds__(256) void g3_kernel(
    const float* __restrict__ Y3, const float* __restrict__ B3,
    const unsigned short* __restrict__ idx3,
    float* __restrict__ pool)
{
    __shared__ float sp[4][32];
    int bid = blockIdx.x;
    int tid = threadIdx.x, lane = tid & 63, wave = tid >> 6;
    int t = bid * 256 + tid;
    int e = t >> 9;
    int rows[8];
    decode_rows(idx3, (size_t)t, rows);
    float4 m[8];
    maxgather(Y3 + (size_t)e * 512 * 32, rows, m);
    const float4* bp = (const float4*)(B3 + (size_t)t * 32);
    float4 r[8];
#pragma unroll
    for (int q = 0; q < 8; q++) {
        float4 bv = bp[q];
        r[q].x = elu_f(bv.x + m[q].x); r[q].y = elu_f(bv.y + m[q].y);
        r[q].z = elu_f(bv.z + m[q].z); r[q].w = elu_f(bv.w + m[q].w);
    }
    for (int off = 1; off < 64; off <<= 1) {
#pragma unroll
        for (int q = 0; q < 8; q++) {
            r[q].x += __shfl_xor(r[q].x, off);
            r[q].y += __shfl_xor(r[q].y, off);
            r[q].z += __shfl_xor(r[q].z, off);
            r[q].w += __shfl_xor(r[q].w, off);
        }
    }
    if (lane == 0) {
#pragma unroll
        for (int q = 0; q < 8; q++) {
            sp[wave][q*4+0] = r[q].x; sp[wave][q*4+1] = r[q].y;
            sp[wave][q*4+2] = r[q].z; sp[wave][q*4+3] = r[q].w;
        }
    }
    __syncthreads();
    if (tid < 32)
        pool[(size_t)bid * 32 + tid] = sp[0][tid] + sp[1][tid] + sp[2][tid] + sp[3][tid];
}

// final: 2 pooled partials per event + MLP + sigmoid + arange
__global__ __launch_bounds__(64) void final_kernel(
    const float* __restrict__ pool,
    const float* __restrict__ W1, const float* __restrict__ b1,
    const float* __restrict__ W2, const float* __restrict__ b2,
    float* __restrict__ outp)
{
    int b = blockIdx.x;
    int lane = threadIdx.x, c = lane & 31;
    __shared__ float sp[32];
    __shared__ float sh1[32];
    if (lane < 32)
        sp[c] = (pool[(size_t)(2*b) * 32 + c] + pool[(size_t)(2*b+1) * 32 + c]) * (1.0f / 512.0f);
    __syncthreads();
    if (lane < 32) {
        float h = b1[c];
#pragma unroll
        for (int d = 0; d < 32; d++) h = fmaf(sp[d], W1[d * 32 + c], h);
        sh1[c] = elu_f(h);
    }
    __syncthreads();
    if (lane == 0) {
        float o = b2[0];
#pragma unroll
        for (int d = 0; d < 32; d++) o = fmaf(sh1[d], W2[d], o);
        o = 1.f / (1.f + __expf(-o));
        outp[b] = o;
        outp[NB + b] = (float)b;
    }
}

extern "C" void kernel_launch(void* const* d_in, const int* in_sizes, int n_in,
                              void* d_out, int out_size, void* d_ws, size_t ws_size,
                              hipStream_t stream) {
    const float* x_sv  = (const float*)d_in[0];
    const float* x_trk = (const float*)d_in[1];
    const float* x_pfc = (const float*)d_in[2];
    const float* sv_W1  = (const float*)d_in[6];
    const float* sv_b1  = (const float*)d_in[7];
    const float* sv_W2  = (const float*)d_in[8];
    const float* sv_b2  = (const float*)d_in[9];
    const float* trk_W1 = (const float*)d_in[10];
    const float* trk_b1 = (const float*)d_in[11];
    const float* trk_W2 = (const float*)d_in[12];
    const float* trk_b2 = (const float*)d_in[13];
    const float* pfc_W1 = (const float*)d_in[14];
    const float* pfc_b1 = (const float*)d_in[15];
    const float* pfc_W2 = (const float*)d_in[16];
    const float* pfc_b2 = (const float*)d_in[17];
    const float* conv_W = (const float*)d_in[18];
    const float* conv_b = (const float*)d_in[19];
    const float* out_W1 = (const float*)d_in[20];
    const float* out_b1 = (const float*)d_in[21];
    const float* out_W2 = (const float*)d_in[22];
    const float* out_b2 = (const float*)d_in[23];

    float* ws = (float*)d_ws;
    const size_t SV_E  = (size_t)NB * 64 * 32;     //   524288
    const size_t TRK_E = (size_t)NB * 512 * 32;    //  4194304
    float* f1      = ws;
    float* f2      = f1 + TRK_E;
    float* trk_enc = f2 + TRK_E;                   // Y3 aliases after knn12
    float* Y1      = trk_enc + TRK_E;
    float* Y2      = Y1 + SV_E;
    unsigned short* svHi  = (unsigned short*)(Y2 + TRK_E);   // SV_E u16
    unsigned short* svLo  = svHi + SV_E;                     // pool aliases
    unsigned short* pfcHi = svLo + SV_E;                     // TRK_E u16
    unsigned short* pfcLo = pfcHi + TRK_E;                   // B3 aliases
    unsigned short* f1Hi  = pfcLo + TRK_E;
    unsigned short* f1Lo  = f1Hi + TRK_E;
    float* nrm_sv  = (float*)(f1Lo + TRK_E);                 // NB*64
    float* nrm_pfc = nrm_sv + (size_t)NB * 64;               // NB*512
    float* nrm_f1  = nrm_pfc + (size_t)NB * 512;             // NB*512
    unsigned short* idx1 = (unsigned short*)(nrm_f1 + (size_t)NB * 512); // NB*512*8
    unsigned short* idx2 = idx1 + (size_t)NB * 512 * 8;
    unsigned short* idx3 = idx2 + (size_t)NB * 512 * 8;
    float* Y3   = trk_enc;          // trk_enc dead after knn12
    float* B3   = (float*)pfcHi;    // pfc hi/lo planes dead after knn12
    float* pool = (float*)svHi;     // sv planes dead after knn12

    encode_all_kernel<<<1088, 256, 0, stream>>>(
        x_sv, x_trk, x_pfc,
        sv_W1, sv_b1, sv_W2, sv_b2,
        trk_W1, trk_b1, trk_W2, trk_b2,
        pfc_W1, pfc_b1, pfc_W2, pfc_b2,
        conv_W, conv_b,
        trk_enc, Y1, Y2, f1, f2,
        svHi, svLo, nrm_sv, pfcHi, pfcLo, nrm_pfc);

    knn12_kernel<<<2048, 256, 0, stream>>>(svHi, svLo, nrm_sv,
                                           pfcHi, pfcLo, nrm_pfc,
                                           trk_enc, idx1, idx2);
    g12_kernel<<<1024, 256, 0, stream>>>(Y1, idx1, f1, Y2, idx2, f2,
                                         f1Hi, f1Lo, nrm_f1);

    yb3_kernel<<<1024, 256, 0, stream>>>(f1, f2, conv_W, conv_b, Y3, B3);
    knn3_kernel<<<2048, 256, 0, stream>>>(f1Hi, f1Lo, nrm_f1, f2, idx3);
    g3_kernel<<<512, 256, 0, stream>>>(Y3, B3, idx3, pool);

    final_kernel<<<NB, 64, 0, stream>>>(pool, out_W1, out_b1, out_W2, out_b2, (float*)d_out);
}

// Round 8
// 303.890 us; speedup vs baseline: 1.7081x; 1.0407x over previous
//
#include <hip/hip_runtime.h>
#include <math.h>

#define NB 256      // events
#define KNN 8

typedef __attribute__((ext_vector_type(8))) short short8;
typedef __attribute__((ext_vector_type(4))) float f32x4;

__device__ __forceinline__ float elu_f(float x) {
    return x > 0.f ? x : __expf(x) - 1.f;
}

// round-to-nearest-even fp32 -> bf16 (returns low 16 bits)
__device__ __forceinline__ unsigned bf16rn(float x) {
    unsigned u = __float_as_uint(x);
    return (u + 0x7FFFu + ((u >> 16) & 1u)) >> 16;
}

// split fp32 -> (hi, lo) bf16 pair
__device__ __forceinline__ void bfsplit(float x, short& h, short& l) {
    unsigned hu = bf16rn(x);
    h = (short)hu;
    l = (short)bf16rn(x - __uint_as_float(hu << 16));
}

// ---- sorting-network primitives on u32 keys -------------------------------
// key = (bits(dv) & ~511) | src_idx, dv >= 0 so raw-bit order == float order.
// Truncation to 512 ulp, tie-break lower-index-wins (validated r1-r7).
__device__ __forceinline__ void cex(unsigned& a, unsigned& b) {
    unsigned lo = min(a, b), hi = max(a, b);
    a = lo; b = hi;
}

// Batcher odd-even mergesort, 8 elements, 19 CE (validated r1).
__device__ __forceinline__ void sort8(unsigned* s) {
    cex(s[0], s[1]); cex(s[2], s[3]); cex(s[4], s[5]); cex(s[6], s[7]);
    cex(s[0], s[2]); cex(s[1], s[3]); cex(s[4], s[6]); cex(s[5], s[7]);
    cex(s[1], s[2]); cex(s[5], s[6]);
    cex(s[0], s[4]); cex(s[1], s[5]); cex(s[2], s[6]); cex(s[3], s[7]);
    cex(s[2], s[4]); cex(s[3], s[5]);
    cex(s[1], s[2]); cex(s[3], s[4]); cex(s[5], s[6]);
}

// v asc top-8, s asc 8 candidates -> v = 8 smallest of union, ascending.
__device__ __forceinline__ void merge8(unsigned* v, const unsigned* s) {
#pragma unroll
    for (int i = 0; i < 8; i++) v[i] = min(v[i], s[7 - i]);
    cex(v[0], v[4]); cex(v[1], v[5]); cex(v[2], v[6]); cex(v[3], v[7]);
    cex(v[0], v[2]); cex(v[1], v[3]); cex(v[4], v[6]); cex(v[5], v[7]);
    cex(v[0], v[1]); cex(v[2], v[3]); cex(v[4], v[5]); cex(v[6], v[7]);
}

// ================= MFMA encoder (+ conv-side linear precomputes) ==========
// (r6-validated) 256 nodes/block, 4 waves; wave owns 64 rows.
// MODE 1 no longer writes e2: the f1/f2 bases are identical; the fused
// knn12 kernel writes f2 from the f1 base.
template<int FIN, int MODE>
__device__ void encode_mfma_body(const float* __restrict__ x,
    const float* __restrict__ W1, const float* __restrict__ b1,
    const float* __restrict__ W2, const float* __restrict__ b2,
    const float* __restrict__ conv_W, const float* __restrict__ conv_b,
    float* __restrict__ enc, float* __restrict__ e1,
    unsigned short* __restrict__ hiP, unsigned short* __restrict__ loP,
    float* __restrict__ nrmP,
    int blk, float* __restrict__ sx)
{
    int tid = threadIdx.x;
    int lane = tid & 63, wv = tid >> 6;
    int c = lane & 15, kg = lane >> 4;
    size_t node0 = (size_t)blk * 256;

    {
        const float* xb = x + node0 * FIN;
        for (int i = tid; i < 8192; i += 256) {
            int n = i >> 5, f = i & 31;
            sx[i] = (f < FIN) ? xb[n * FIN + f] : 0.f;
        }
    }
    __syncthreads();

    int rb = wv * 64;

#pragma unroll
    for (int ph = 0; ph < 3; ph++) {
        short8 Bh0, Bl0, Bh1, Bl1;
#pragma unroll
        for (int e = 0; e < 8; e++) {
            int kk = kg * 8 + e;
            float w0, w1;
            if (ph == 0) {
                w0 = (kk < FIN) ? W1[kk * 32 + c] : 0.f;
                w1 = (kk < FIN) ? W1[kk * 32 + 16 + c] : 0.f;
            } else if (ph == 1) {
                w0 = W2[kk * 32 + c];
                w1 = W2[kk * 32 + 16 + c];
            } else {
                w0 = conv_W[1024 + kk * 32 + c];
                w1 = conv_W[1024 + kk * 32 + 16 + c];
                if (MODE == 1) {
                    w0 = conv_W[kk * 32 + c] - w0;
                    w1 = conv_W[kk * 32 + 16 + c] - w1;
                }
            }
            short h, l;
            bfsplit(w0, h, l); Bh0[e] = h; Bl0[e] = l;
            bfsplit(w1, h, l); Bh1[e] = h; Bl1[e] = l;
        }
        float bias0, bias1;
        if (ph == 0)      { bias0 = b1[c]; bias1 = b1[16 + c]; }
        else if (ph == 1) { bias0 = b2[c]; bias1 = b2[16 + c]; }
        else              { bias0 = (MODE == 1) ? conv_b[c] : 0.f;
                            bias1 = (MODE == 1) ? conv_b[16 + c] : 0.f; }

#pragma unroll
        for (int t = 0; t < 4; t++) {
            int tb = rb + t * 16;
            int arow = tb + c;
            const float* ap = sx + arow * 32 + kg * 8;
            float4 a0 = *(const float4*)(ap);
            float4 a1 = *(const float4*)(ap + 4);
            float av[8] = {a0.x, a0.y, a0.z, a0.w, a1.x, a1.y, a1.z, a1.w};
            short8 Ah, Al;
#pragma unroll
            for (int e = 0; e < 8; e++) {
                short h, l;
                bfsplit(av[e], h, l);
                Ah[e] = h; Al[e] = l;
            }

            if (MODE == 0 && ph == 2) {
                float nr = 0.f;
#pragma unroll
                for (int e = 0; e < 8; e++) nr = fmaf(av[e], av[e], nr);
                nr += __shfl_xor(nr, 16);
                nr += __shfl_xor(nr, 32);
                if (kg == 0) nrmP[node0 + arow] = nr;
                *(short8*)(hiP + (node0 + arow) * 32 + kg * 8) = Ah;
                *(short8*)(loP + (node0 + arow) * 32 + kg * 8) = Al;
            }

            f32x4 acc0 = {bias0, bias0, bias0, bias0};
            f32x4 acc1 = {bias1, bias1, bias1, bias1};
            acc0 = __builtin_amdgcn_mfma_f32_16x16x32_bf16(Al, Bh0, acc0, 0, 0, 0);
            acc0 = __builtin_amdgcn_mfma_f32_16x16x32_bf16(Ah, Bl0, acc0, 0, 0, 0);
            acc0 = __builtin_amdgcn_mfma_f32_16x16x32_bf16(Ah, Bh0, acc0, 0, 0, 0);
            acc1 = __builtin_amdgcn_mfma_f32_16x16x32_bf16(Al, Bh1, acc1, 0, 0, 0);
            acc1 = __builtin_amdgcn_mfma_f32_16x16x32_bf16(Ah, Bl1, acc1, 0, 0, 0);
            acc1 = __builtin_amdgcn_mfma_f32_16x16x32_bf16(Ah, Bh1, acc1, 0, 0, 0);

            int drow = tb + kg * 4;
            if (ph < 2) {
#pragma unroll
                for (int r = 0; r < 4; r++) {
                    float v0 = elu_f(acc0[r]);
                    float v1 = elu_f(acc1[r]);
                    sx[(drow + r) * 32 + c] = v0;
                    sx[(drow + r) * 32 + 16 + c] = v1;
                    if (MODE == 1 && ph == 1) {
                        size_t off = (node0 + drow + r) * 32 + c;
                        enc[off] = v0;
                        enc[off + 16] = v1;
                    }
                }
            } else {
#pragma unroll
                for (int r = 0; r < 4; r++) {
                    size_t off = (node0 + drow + r) * 32 + c;
                    e1[off] = acc0[r];
                    e1[off + 16] = acc1[r];
                }
            }
        }
    }
}

// 1088 blocks: sv(64) | trk(512) | pfc(512); 256 nodes/block
__global__ __launch_bounds__(256) void encode_all_kernel(
    const float* __restrict__ x_sv, const float* __restrict__ x_trk, const float* __restrict__ x_pfc,
    const float* __restrict__ sv_W1, const float* __restrict__ sv_b1,
    const float* __restrict__ sv_W2, const float* __restrict__ sv_b2,
    const float* __restrict__ trk_W1, const float* __restrict__ trk_b1,
    const float* __restrict__ trk_W2, const float* __restrict__ trk_b2,
    const float* __restrict__ pfc_W1, const float* __restrict__ pfc_b1,
    const float* __restrict__ pfc_W2, const float* __restrict__ pfc_b2,
    const float* __restrict__ conv_W, const float* __restrict__ conv_b,
    float* __restrict__ trk_enc,
    float* __restrict__ Y1, float* __restrict__ Y2,
    float* __restrict__ f1,
    unsigned short* __restrict__ svHi, unsigned short* __restrict__ svLo, float* __restrict__ nrm_sv,
    unsigned short* __restrict__ pfcHi, unsigned short* __restrict__ pfcLo, float* __restrict__ nrm_pfc)
{
    __shared__ float sx[8192];
    int bid = blockIdx.x;
    if (bid < 64)
        encode_mfma_body<14, 0>(x_sv, sv_W1, sv_b1, sv_W2, sv_b2, conv_W, conv_b,
                                nullptr, Y1, svHi, svLo, nrm_sv, bid, sx);
    else if (bid < 576)
        encode_mfma_body<30, 1>(x_trk, trk_W1, trk_b1, trk_W2, trk_b2, conv_W, conv_b,
                                trk_enc, f1, nullptr, nullptr, nullptr, bid - 64, sx);
    else
        encode_mfma_body<10, 0>(x_pfc, pfc_W1, pfc_b1, pfc_W2, pfc_b2, conv_W, conv_b,
                                nullptr, Y2, pfcHi, pfcLo, nrm_pfc, bid - 576, sx);
}

// ================= kNN via MFMA Gram tiles =================================
// build B fragment (16 dsts) from f32 rows; hi/lo split + full dst norm
__device__ __forceinline__ void knn_build_B(const float* __restrict__ dstF,
                                            int dstbase, int c, int kg,
                                            short8& Bh, short8& Bl, float& nd)
{
    const float* brow = dstF + (size_t)(dstbase + c) * 32 + kg * 8;
    float4 b0 = *(const float4*)(brow);
    float4 b1 = *(const float4*)(brow + 4);
    float bx[8] = {b0.x, b0.y, b0.z, b0.w, b1.x, b1.y, b1.z, b1.w};
    nd = 0.f;
#pragma unroll
    for (int i = 0; i < 8; i++) {
        float xv = bx[i];
        nd = fmaf(xv, xv, nd);
        short h, l;
        bfsplit(xv, h, l);
        Bh[i] = h; Bl[i] = l;
    }
    nd += __shfl_xor(nd, 16);
    nd += __shfl_xor(nd, 32);
}

// scan NT tiles (NT even): batch-8 candidates (2 tiles) -> sort8 + merge8.
template<int NT>
__device__ __forceinline__ void knn_scan(
    const unsigned short* __restrict__ srcHi, const unsigned short* __restrict__ srcLo,
    const float* __restrict__ snrm,
    short8 Bh, short8 Bl, float nd, int c, int kg,
    unsigned* key)
{
    for (int t = 0; t < NT; t += 2) {
        unsigned cand[8];
#pragma unroll
        for (int u = 0; u < 2; u++) {
            int tt = t + u;
            size_t arow = ((size_t)(tt * 16 + c)) * 32 + (size_t)kg * 8;
            short8 Ah = *(const short8*)(srcHi + arow);
            short8 Al = *(const short8*)(srcLo + arow);
            f32x4 acc = {0.f, 0.f, 0.f, 0.f};
            acc = __builtin_amdgcn_mfma_f32_16x16x32_bf16(Al, Bl, acc, 0, 0, 0);
            acc = __builtin_amdgcn_mfma_f32_16x16x32_bf16(Al, Bh, acc, 0, 0, 0);
            acc = __builtin_amdgcn_mfma_f32_16x16x32_bf16(Ah, Bl, acc, 0, 0, 0);
            acc = __builtin_amdgcn_mfma_f32_16x16x32_bf16(Ah, Bh, acc, 0, 0, 0);
            float4 sn = *(const float4*)(snrm + tt * 16 + kg * 4);
            int sb = tt * 16 + kg * 4;
            cand[u*4+0] = (__float_as_uint(fmaf(-2.f, acc[0], sn.x + nd)) & 0xFFFFFE00u) | (unsigned)(sb + 0);
            cand[u*4+1] = (__float_as_uint(fmaf(-2.f, acc[1], sn.y + nd)) & 0xFFFFFE00u) | (unsigned)(sb + 1);
            cand[u*4+2] = (__float_as_uint(fmaf(-2.f, acc[2], sn.z + nd)) & 0xFFFFFE00u) | (unsigned)(sb + 2);
            cand[u*4+3] = (__float_as_uint(fmaf(-2.f, acc[3], sn.w + nd)) & 0xFFFFFE00u) | (unsigned)(sb + 3);
        }
        sort8(cand);
        merge8(key, cand);
    }
}

// cross-lane merge of the 4 src-subsets. Symmetric merges: afterwards ALL
// four lanes (c, c+16, c+32, c+48) hold the identical final sorted top-8
// for dst column c (keys unique -> deterministic).
__device__ __forceinline__ void knn_merge_lanes(unsigned* key)
{
    unsigned oth[8];
#pragma unroll
    for (int k = 0; k < 8; k++) oth[k] = __shfl_xor(key[k], 16);
    merge8(key, oth);
#pragma unroll
    for (int k = 0; k < 8; k++) oth[k] = __shfl_xor(key[k], 32);
    merge8(key, oth);
}

// per-lane gather of this lane's 8-float segment of the 8 neighbor rows
__device__ __forceinline__ void gather_max8(const float* __restrict__ Yb,
                                            const unsigned* key, int kg, float* m)
{
    const float* r0 = Yb + (size_t)(key[0] & 511u) * 32 + kg * 8;
    float4 a = *(const float4*)(r0);
    float4 b = *(const float4*)(r0 + 4);
    m[0] = a.x; m[1] = a.y; m[2] = a.z; m[3] = a.w;
    m[4] = b.x; m[5] = b.y; m[6] = b.z; m[7] = b.w;
#pragma unroll
    for (int k = 1; k < 8; k++) {
        const float* rr = Yb + (size_t)(key[k] & 511u) * 32 + kg * 8;
        float4 va = *(const float4*)(rr);
        float4 vb = *(const float4*)(rr + 4);
        m[0] = fmaxf(m[0], va.x); m[1] = fmaxf(m[1], va.y);
        m[2] = fmaxf(m[2], va.z); m[3] = fmaxf(m[3], va.w);
        m[4] = fmaxf(m[4], vb.x); m[5] = fmaxf(m[5], vb.y);
        m[6] = fmaxf(m[6], vb.z); m[7] = fmaxf(m[7], vb.w);
    }
}

// knn12 + g12 fused: 2048 blocks. Wave owns 16 dsts; builds B once, scans
// pfc (32 tiles) and sv (4 tiles), then gathers Y2/Y1 and writes
// f2 = elu(base+maxY2), f1 = elu(base+maxY1) + f1 hi/lo planes + norms.
// f1/f2 values bit-identical to the unfused path (base read once; identical).
__global__ __launch_bounds__(256) void knn12_kernel(
    const unsigned short* __restrict__ svHi, const unsigned short* __restrict__ svLo,
    const float* __restrict__ nrm_sv,
    const unsigned short* __restrict__ pfcHi, const unsigned short* __restrict__ pfcLo,
    const float* __restrict__ nrm_pfc,
    const float* __restrict__ trk_enc,
    const float* __restrict__ Y1, const float* __restrict__ Y2,
    float* __restrict__ f1, float* __restrict__ f2,
    unsigned short* __restrict__ f1Hi, unsigned short* __restrict__ f1Lo,
    float* __restrict__ nrm_f1)
{
    int bid = blockIdx.x;
    int e = bid & 255, j = bid >> 8;
    int lane = threadIdx.x & 63, wave = threadIdx.x >> 6;
    int c = lane & 15, kg = lane >> 4;
    int dstbase = j * 64 + wave * 16;
    size_t trow = (size_t)e * 512 + dstbase + c;

    short8 Bh, Bl;
    float nd;
    knn_build_B(trk_enc + (size_t)e * 512 * 32, dstbase, c, kg, Bh, Bl, nd);

    unsigned key2[8];
#pragma unroll
    for (int k = 0; k < 8; k++) key2[k] = 0xFFFFFFFFu;
    knn_scan<32>(pfcHi + (size_t)e * 512 * 32, pfcLo + (size_t)e * 512 * 32,
                 nrm_pfc + e * 512, Bh, Bl, nd, c, kg, key2);
    knn_merge_lanes(key2);

    unsigned key1[8];
#pragma unroll
    for (int k = 0; k < 8; k++) key1[k] = 0xFFFFFFFFu;
    knn_scan<4>(svHi + (size_t)e * 64 * 32, svLo + (size_t)e * 64 * 32,
                nrm_sv + e * 64, Bh, Bl, nd, c, kg, key1);
    knn_merge_lanes(key1);

    // base (f1 base == f2 base, written once by encoder)
    const float* bp = f1 + trow * 32 + kg * 8;
    float4 bb0 = *(const float4*)(bp);
    float4 bb1 = *(const float4*)(bp + 4);
    float base[8] = {bb0.x, bb0.y, bb0.z, bb0.w, bb1.x, bb1.y, bb1.z, bb1.w};

    float m[8];
    // f2 = elu(base + max Y2[rows2])
    gather_max8(Y2 + (size_t)e * 512 * 32, key2, kg, m);
    {
        float4 o0, o1;
        o0.x = elu_f(base[0] + m[0]); o0.y = elu_f(base[1] + m[1]);
        o0.z = elu_f(base[2] + m[2]); o0.w = elu_f(base[3] + m[3]);
        o1.x = elu_f(base[4] + m[4]); o1.y = elu_f(base[5] + m[5]);
        o1.z = elu_f(base[6] + m[6]); o1.w = elu_f(base[7] + m[7]);
        float4* op = (float4*)(f2 + trow * 32 + kg * 8);
        op[0] = o0; op[1] = o1;
    }
    // f1 = elu(base + max Y1[rows1]) + planes + norm
    gather_max8(Y1 + (size_t)e * 64 * 32, key1, kg, m);
    {
        float v[8];
        float nr = 0.f;
        short8 Hh, Hl;
#pragma unroll
        for (int i = 0; i < 8; i++) {
            v[i] = elu_f(base[i] + m[i]);
            nr = fmaf(v[i], v[i], nr);
            short h, l;
            bfsplit(v[i], h, l);
            Hh[i] = h; Hl[i] = l;
        }
        nr += __shfl_xor(nr, 16);
        nr += __shfl_xor(nr, 32);
        if (kg == 0) nrm_f1[trow] = nr;
        float4* op = (float4*)(f1 + trow * 32 + kg * 8);
        op[0] = (float4){v[0], v[1], v[2], v[3]};
        op[1] = (float4){v[4], v[5], v[6], v[7]};
        *(short8*)(f1Hi + trow * 32 + kg * 8) = Hh;
        *(short8*)(f1Lo + trow * 32 + kg * 8) = Hl;
    }
}

// knn3 + g3 fused: 2048 blocks. src=f1 planes, dst=f2. After selection,
// gather Y3 + B3 base, elu, and reduce straight to per-(event,j) pooled
// partials (8 partials/event; final_kernel sums them deterministically).
__global__ __launch_bounds__(256) void knn3_kernel(
    const unsigned short* __restrict__ f1Hi, const unsigned short* __restrict__ f1Lo,
    const float* __restrict__ nrm_f1,
    const float* __restrict__ f2,
    const float* __restrict__ Y3, const float* __restrict__ B3,
    float* __restrict__ pool)
{
    __shared__ float sp[4][32];
    int bid = blockIdx.x;
    int e = bid & 255, j = bid >> 8;
    int tid = threadIdx.x;
    int lane = tid & 63, wave = tid >> 6;
    int c = lane & 15, kg = lane >> 4;
    int dstbase = j * 64 + wave * 16;
    size_t trow = (size_t)e * 512 + dstbase + c;

    short8 Bh, Bl;
    float nd;
    knn_build_B(f2 + (size_t)e * 512 * 32, dstbase, c, kg, Bh, Bl, nd);

    unsigned key[8];
#pragma unroll
    for (int k = 0; k < 8; k++) key[k] = 0xFFFFFFFFu;
    knn_scan<32>(f1Hi + (size_t)e * 512 * 32, f1Lo + (size_t)e * 512 * 32,
                 nrm_f1 + e * 512, Bh, Bl, nd, c, kg, key);
    knn_merge_lanes(key);

    float m[8];
    gather_max8(Y3 + (size_t)e * 512 * 32, key, kg, m);

    const float* bp = B3 + trow * 32 + kg * 8;
    float4 bb0 = *(const float4*)(bp);
    float4 bb1 = *(const float4*)(bp + 4);
    float base[8] = {bb0.x, bb0.y, bb0.z, bb0.w, bb1.x, bb1.y, bb1.z, bb1.w};

    float r[8];
#pragma unroll
    for (int i = 0; i < 8; i++) r[i] = elu_f(base[i] + m[i]);

    // sum over the wave's 16 dsts (lanes differing in c-bits, same kg)
#pragma unroll
    for (int off = 1; off < 16; off <<= 1) {
#pragma unroll
        for (int i = 0; i < 8; i++) r[i] += __shfl_xor(r[i], off);
    }
    if (c == 0) {
#pragma unroll
        for (int i = 0; i < 8; i++) sp[wave][kg * 8 + i] = r[i];
    }
    __syncthreads();
    if (tid < 32)
        pool[((size_t)e * 8 + j) * 32 + tid] =
            sp[0][tid] + sp[1][tid] + sp[2][tid] + sp[3][tid];
}

// yb3 via MFMA: 1024 blocks x 256 rows. bid<512: Y3 = f1@w2h; else B3 =
// f2@wd + bb. (r7-validated)
__global__ __launch_bounds__(256) void yb3_kernel(
    const float* __restrict__ f1, const float* __restrict__ f2,
    const float* __restrict__ conv_W, const float* __restrict__ conv_b,
    float* __restrict__ Y3, float* __restrict__ B3)
{
    int bid = blockIdx.x;
    int mode = (bid >= 512);
    const float* X = mode ? f2 : f1;
    float* O = mode ? B3 : Y3;
    size_t node0 = (size_t)(mode ? bid - 512 : bid) * 256;
    int tid = threadIdx.x, lane = tid & 63, wv = tid >> 6;
    int c = lane & 15, kg = lane >> 4;

    short8 Bh0, Bl0, Bh1, Bl1;
#pragma unroll
    for (int e = 0; e < 8; e++) {
        int kk = kg * 8 + e;
        float w0 = conv_W[1024 + kk * 32 + c];
        float w1 = conv_W[1024 + kk * 32 + 16 + c];
        if (mode) {
            w0 = conv_W[kk * 32 + c] - w0;
            w1 = conv_W[kk * 32 + 16 + c] - w1;
        }
        short h, l;
        bfsplit(w0, h, l); Bh0[e] = h; Bl0[e] = l;
        bfsplit(w1, h, l); Bh1[e] = h; Bl1[e] = l;
    }
    float bias0 = mode ? conv_b[c] : 0.f;
    float bias1 = mode ? conv_b[16 + c] : 0.f;

    int rb = wv * 64;
#pragma unroll
    for (int t = 0; t < 4; t++) {
        int tb = rb + t * 16;
        int arow = tb + c;
        const float* ap = X + (node0 + arow) * 32 + kg * 8;
        float4 a0 = *(const float4*)(ap);
        float4 a1 = *(const float4*)(ap + 4);
        float av[8] = {a0.x, a0.y, a0.z, a0.w, a1.x, a1.y, a1.z, a1.w};
        short8 Ah, Al;
#pragma unroll
        for (int e = 0; e < 8; e++) {
            short h, l;
            bfsplit(av[e], h, l);
            Ah[e] = h; Al[e] = l;
        }
        f32x4 acc0 = {bias0, bias0, bias0, bias0};
        f32x4 acc1 = {bias1, bias1, bias1, bias1};
        acc0 = __builtin_amdgcn_mfma_f32_16x16x32_bf16(Al, Bh0, acc0, 0, 0, 0);
        acc0 = __builtin_amdgcn_mfma_f32_16x16x32_bf16(Ah, Bl0, acc0, 0, 0, 0);
        acc0 = __builtin_amdgcn_mfma_f32_16x16x32_bf16(Ah, Bh0, acc0, 0, 0, 0);
        acc1 = __builtin_amdgcn_mfma_f32_16x16x32_bf16(Al, Bh1, acc1, 0, 0, 0);
        acc1 = __builtin_amdgcn_mfma_f32_16x16x32_bf16(Ah, Bl1, acc1, 0, 0, 0);
        acc1 = __builtin_amdgcn_mfma_f32_16x16x32_bf16(Ah, Bh1, acc1, 0, 0, 0);

        int drow = tb + kg * 4;
#pragma unroll
        for (int r = 0; r < 4; r++) {
            size_t off = (node0 + drow + r) * 32 + c;
            O[off] = acc0[r];
            O[off + 16] = acc1[r];
        }
    }
}

// final: 8 pooled partials per event + MLP + sigmoid + arange
__global__ __launch_bounds__(64) void final_kernel(
    const float* __restrict__ pool,
    const float* __restrict__ W1, const float* __restrict__ b1,
    const float* __restrict__ W2, const float* __restrict__ b2,
    float* __restrict__ outp)
{
    int b = blockIdx.x;
    int lane = threadIdx.x, c = lane & 31;
    __shared__ float sp[32];
    __shared__ float sh1[32];
    if (lane < 32) {
        float s = 0.f;
#pragma unroll
        for (int jj = 0; jj < 8; jj++)
            s += pool[((size_t)b * 8 + jj) * 32 + c];
        sp[c] = s * (1.0f / 512.0f);
    }
    __syncthreads();
    if (lane < 32) {
        float h = b1[c];
#pragma unroll
        for (int d = 0; d < 32; d++) h = fmaf(sp[d], W1[d * 32 + c], h);
        sh1[c] = elu_f(h);
    }
    __syncthreads();
    if (lane == 0) {
        float o = b2[0];
#pragma unroll
        for (int d = 0; d < 32; d++) o = fmaf(sh1[d], W2[d], o);
        o = 1.f / (1.f + __expf(-o));
        outp[b] = o;
        outp[NB + b] = (float)b;
    }
}

extern "C" void kernel_launch(void* const* d_in, const int* in_sizes, int n_in,
                              void* d_out, int out_size, void* d_ws, size_t ws_size,
                              hipStream_t stream) {
    const float* x_sv  = (const float*)d_in[0];
    const float* x_trk = (const float*)d_in[1];
    const float* x_pfc = (const float*)d_in[2];
    const float* sv_W1  = (const float*)d_in[6];
    const float* sv_b1  = (const float*)d_in[7];
    const float* sv_W2  = (const float*)d_in[8];
    const float* sv_b2  = (const float*)d_in[9];
    const float* trk_W1 = (const float*)d_in[10];
    const float* trk_b1 = (const float*)d_in[11];
    const float* trk_W2 = (const float*)d_in[12];
    const float* trk_b2 = (const float*)d_in[13];
    const float* pfc_W1 = (const float*)d_in[14];
    const float* pfc_b1 = (const float*)d_in[15];
    const float* pfc_W2 = (const float*)d_in[16];
    const float* pfc_b2 = (const float*)d_in[17];
    const float* conv_W = (const float*)d_in[18];
    const float* conv_b = (const float*)d_in[19];
    const float* out_W1 = (const float*)d_in[20];
    const float* out_b1 = (const float*)d_in[21];
    const float* out_W2 = (const float*)d_in[22];
    const float* out_b2 = (const float*)d_in[23];

    float* ws = (float*)d_ws;
    const size_t SV_E  = (size_t)NB * 64 * 32;     //   524288
    const size_t TRK_E = (size_t)NB * 512 * 32;    //  4194304
    float* f1      = ws;
    float* f2      = f1 + TRK_E;
    float* trk_enc = f2 + TRK_E;                   // Y3 aliases after knn12
    float* Y1      = trk_enc + TRK_E;
    float* Y2      = Y1 + SV_E;
    unsigned short* svHi  = (unsigned short*)(Y2 + TRK_E);   // SV_E u16
    unsigned short* svLo  = svHi + SV_E;                     // pool aliases
    unsigned short* pfcHi = svLo + SV_E;                     // TRK_E u16
    unsigned short* pfcLo = pfcHi + TRK_E;                   // B3 aliases
    unsigned short* f1Hi  = pfcLo + TRK_E;
    unsigned short* f1Lo  = f1Hi + TRK_E;
    float* nrm_sv  = (float*)(f1Lo + TRK_E);                 // NB*64
    float* nrm_pfc = nrm_sv + (size_t)NB * 64;               // NB*512
    float* nrm_f1  = nrm_pfc + (size_t)NB * 512;             // NB*512
    float* Y3   = trk_enc;          // trk_enc dead after knn12
    float* B3   = (float*)pfcHi;    // pfc hi/lo planes dead after knn12
    float* pool = (float*)svHi;     // sv planes dead after knn12; NB*8*32 f32

    encode_all_kernel<<<1088, 256, 0, stream>>>(
        x_sv, x_trk, x_pfc,
        sv_W1, sv_b1, sv_W2, sv_b2,
        trk_W1, trk_b1, trk_W2, trk_b2,
        pfc_W1, pfc_b1, pfc_W2, pfc_b2,
        conv_W, conv_b,
        trk_enc, Y1, Y2, f1,
        svHi, svLo, nrm_sv, pfcHi, pfcLo, nrm_pfc);

    knn12_kernel<<<2048, 256, 0, stream>>>(svHi, svLo, nrm_sv,
                                           pfcHi, pfcLo, nrm_pfc,
                                           trk_enc, Y1, Y2,
                                           f1, f2, f1Hi, f1Lo, nrm_f1);

    yb3_kernel<<<1024, 256, 0, stream>>>(f1, f2, conv_W, conv_b, Y3, B3);
    knn3_kernel<<<2048, 256, 0, stream>>>(f1Hi, f1Lo, nrm_f1, f2, Y3, B3, pool);

    final_kernel<<<NB, 64, 0, stream>>>(pool, out_W1, out_b1, out_W2, out_b2, (float*)d_out);
}

// Round 10
// 295.805 us; speedup vs baseline: 1.7548x; 1.0273x over previous
//
#include <hip/hip_runtime.h>
#include <math.h>

#define NB 256      // events
#define KNN 8

typedef __attribute__((ext_vector_type(8))) short short8;
typedef __attribute__((ext_vector_type(4))) float f32x4;

__device__ __forceinline__ float elu_f(float x) {
    return x > 0.f ? x : __expf(x) - 1.f;
}

// round-to-nearest-even fp32 -> bf16 (returns low 16 bits)
__device__ __forceinline__ unsigned bf16rn(float x) {
    unsigned u = __float_as_uint(x);
    return (u + 0x7FFFu + ((u >> 16) & 1u)) >> 16;
}

// split fp32 -> (hi, lo) bf16 pair
__device__ __forceinline__ void bfsplit(float x, short& h, short& l) {
    unsigned hu = bf16rn(x);
    h = (short)hu;
    l = (short)bf16rn(x - __uint_as_float(hu << 16));
}

// ---- sorting-network primitives on u32 keys (validated r1-r8) -------------
__device__ __forceinline__ void cex(unsigned& a, unsigned& b) {
    unsigned lo = min(a, b), hi = max(a, b);
    a = lo; b = hi;
}

__device__ __forceinline__ void sort8(unsigned* s) {
    cex(s[0], s[1]); cex(s[2], s[3]); cex(s[4], s[5]); cex(s[6], s[7]);
    cex(s[0], s[2]); cex(s[1], s[3]); cex(s[4], s[6]); cex(s[5], s[7]);
    cex(s[1], s[2]); cex(s[5], s[6]);
    cex(s[0], s[4]); cex(s[1], s[5]); cex(s[2], s[6]); cex(s[3], s[7]);
    cex(s[2], s[4]); cex(s[3], s[5]);
    cex(s[1], s[2]); cex(s[3], s[4]); cex(s[5], s[6]);
}

__device__ __forceinline__ void merge8(unsigned* v, const unsigned* s) {
#pragma unroll
    for (int i = 0; i < 8; i++) v[i] = min(v[i], s[7 - i]);
    cex(v[0], v[4]); cex(v[1], v[5]); cex(v[2], v[6]); cex(v[3], v[7]);
    cex(v[0], v[2]); cex(v[1], v[3]); cex(v[4], v[6]); cex(v[5], v[7]);
    cex(v[0], v[1]); cex(v[2], v[3]); cex(v[4], v[5]); cex(v[6], v[7]);
}

// ================= MFMA encoder (r6-validated) =============================
template<int FIN, int MODE>
__device__ void encode_mfma_body(const float* __restrict__ x,
    const float* __restrict__ W1, const float* __restrict__ b1,
    const float* __restrict__ W2, const float* __restrict__ b2,
    const float* __restrict__ conv_W, const float* __restrict__ conv_b,
    float* __restrict__ enc, float* __restrict__ e1,
    unsigned short* __restrict__ hiP, unsigned short* __restrict__ loP,
    float* __restrict__ nrmP,
    int blk, float* __restrict__ sx)
{
    int tid = threadIdx.x;
    int lane = tid & 63, wv = tid >> 6;
    int c = lane & 15, kg = lane >> 4;
    size_t node0 = (size_t)blk * 256;

    {
        const float* xb = x + node0 * FIN;
        for (int i = tid; i < 8192; i += 256) {
            int n = i >> 5, f = i & 31;
            sx[i] = (f < FIN) ? xb[n * FIN + f] : 0.f;
        }
    }
    __syncthreads();

    int rb = wv * 64;

#pragma unroll
    for (int ph = 0; ph < 3; ph++) {
        short8 Bh0, Bl0, Bh1, Bl1;
#pragma unroll
        for (int e = 0; e < 8; e++) {
            int kk = kg * 8 + e;
            float w0, w1;
            if (ph == 0) {
                w0 = (kk < FIN) ? W1[kk * 32 + c] : 0.f;
                w1 = (kk < FIN) ? W1[kk * 32 + 16 + c] : 0.f;
            } else if (ph == 1) {
                w0 = W2[kk * 32 + c];
                w1 = W2[kk * 32 + 16 + c];
            } else {
                w0 = conv_W[1024 + kk * 32 + c];
                w1 = conv_W[1024 + kk * 32 + 16 + c];
                if (MODE == 1) {
                    w0 = conv_W[kk * 32 + c] - w0;
                    w1 = conv_W[kk * 32 + 16 + c] - w1;
                }
            }
            short h, l;
            bfsplit(w0, h, l); Bh0[e] = h; Bl0[e] = l;
            bfsplit(w1, h, l); Bh1[e] = h; Bl1[e] = l;
        }
        float bias0, bias1;
        if (ph == 0)      { bias0 = b1[c]; bias1 = b1[16 + c]; }
        else if (ph == 1) { bias0 = b2[c]; bias1 = b2[16 + c]; }
        else              { bias0 = (MODE == 1) ? conv_b[c] : 0.f;
                            bias1 = (MODE == 1) ? conv_b[16 + c] : 0.f; }

#pragma unroll
        for (int t = 0; t < 4; t++) {
            int tb = rb + t * 16;
            int arow = tb + c;
            const float* ap = sx + arow * 32 + kg * 8;
            float4 a0 = *(const float4*)(ap);
            float4 a1 = *(const float4*)(ap + 4);
            float av[8] = {a0.x, a0.y, a0.z, a0.w, a1.x, a1.y, a1.z, a1.w};
            short8 Ah, Al;
#pragma unroll
            for (int e = 0; e < 8; e++) {
                short h, l;
                bfsplit(av[e], h, l);
                Ah[e] = h; Al[e] = l;
            }

            if (MODE == 0 && ph == 2) {
                float nr = 0.f;
#pragma unroll
                for (int e = 0; e < 8; e++) nr = fmaf(av[e], av[e], nr);
                nr += __shfl_xor(nr, 16);
                nr += __shfl_xor(nr, 32);
                if (kg == 0) nrmP[node0 + arow] = nr;
                *(short8*)(hiP + (node0 + arow) * 32 + kg * 8) = Ah;
                *(short8*)(loP + (node0 + arow) * 32 + kg * 8) = Al;
            }

            f32x4 acc0 = {bias0, bias0, bias0, bias0};
            f32x4 acc1 = {bias1, bias1, bias1, bias1};
            acc0 = __builtin_amdgcn_mfma_f32_16x16x32_bf16(Al, Bh0, acc0, 0, 0, 0);
            acc0 = __builtin_amdgcn_mfma_f32_16x16x32_bf16(Ah, Bl0, acc0, 0, 0, 0);
            acc0 = __builtin_amdgcn_mfma_f32_16x16x32_bf16(Ah, Bh0, acc0, 0, 0, 0);
            acc1 = __builtin_amdgcn_mfma_f32_16x16x32_bf16(Al, Bh1, acc1, 0, 0, 0);
            acc1 = __builtin_amdgcn_mfma_f32_16x16x32_bf16(Ah, Bl1, acc1, 0, 0, 0);
            acc1 = __builtin_amdgcn_mfma_f32_16x16x32_bf16(Ah, Bh1, acc1, 0, 0, 0);

            int drow = tb + kg * 4;
            if (ph < 2) {
#pragma unroll
                for (int r = 0; r < 4; r++) {
                    float v0 = elu_f(acc0[r]);
                    float v1 = elu_f(acc1[r]);
                    sx[(drow + r) * 32 + c] = v0;
                    sx[(drow + r) * 32 + 16 + c] = v1;
                    if (MODE == 1 && ph == 1) {
                        size_t off = (node0 + drow + r) * 32 + c;
                        enc[off] = v0;
                        enc[off + 16] = v1;
                    }
                }
            } else {
#pragma unroll
                for (int r = 0; r < 4; r++) {
                    size_t off = (node0 + drow + r) * 32 + c;
                    e1[off] = acc0[r];
                    e1[off + 16] = acc1[r];
                }
            }
        }
    }
}

// 1088 blocks: sv(64) | trk(512) | pfc(512); 256 nodes/block
__global__ __launch_bounds__(256) void encode_all_kernel(
    const float* __restrict__ x_sv, const float* __restrict__ x_trk, const float* __restrict__ x_pfc,
    const float* __restrict__ sv_W1, const float* __restrict__ sv_b1,
    const float* __restrict__ sv_W2, const float* __restrict__ sv_b2,
    const float* __restrict__ trk_W1, const float* __restrict__ trk_b1,
    const float* __restrict__ trk_W2, const float* __restrict__ trk_b2,
    const float* __restrict__ pfc_W1, const float* __restrict__ pfc_b1,
    const float* __restrict__ pfc_W2, const float* __restrict__ pfc_b2,
    const float* __restrict__ conv_W, const float* __restrict__ conv_b,
    float* __restrict__ trk_enc,
    float* __restrict__ Y1, float* __restrict__ Y2,
    float* __restrict__ f1base,
    unsigned short* __restrict__ svHi, unsigned short* __restrict__ svLo, float* __restrict__ nrm_sv,
    unsigned short* __restrict__ pfcHi, unsigned short* __restrict__ pfcLo, float* __restrict__ nrm_pfc)
{
    __shared__ float sx[8192];
    int bid = blockIdx.x;
    if (bid < 64)
        encode_mfma_body<14, 0>(x_sv, sv_W1, sv_b1, sv_W2, sv_b2, conv_W, conv_b,
                                nullptr, Y1, svHi, svLo, nrm_sv, bid, sx);
    else if (bid < 576)
        encode_mfma_body<30, 1>(x_trk, trk_W1, trk_b1, trk_W2, trk_b2, conv_W, conv_b,
                                trk_enc, f1base, nullptr, nullptr, nullptr, bid - 64, sx);
    else
        encode_mfma_body<10, 0>(x_pfc, pfc_W1, pfc_b1, pfc_W2, pfc_b2, conv_W, conv_b,
                                nullptr, Y2, pfcHi, pfcLo, nrm_pfc, bid - 576, sx);
}

// ================= kNN via MFMA Gram tiles (r4/r7/r8-validated) ============
__device__ __forceinline__ void knn_build_B(const float* __restrict__ dstF,
                                            int dstbase, int c, int kg,
                                            short8& Bh, short8& Bl, float& nd)
{
    const float* brow = dstF + (size_t)(dstbase + c) * 32 + kg * 8;
    float4 b0 = *(const float4*)(brow);
    float4 b1 = *(const float4*)(brow + 4);
    float bx[8] = {b0.x, b0.y, b0.z, b0.w, b1.x, b1.y, b1.z, b1.w};
    nd = 0.f;
#pragma unroll
    for (int i = 0; i < 8; i++) {
        float xv = bx[i];
        nd = fmaf(xv, xv, nd);
        short h, l;
        bfsplit(xv, h, l);
        Bh[i] = h; Bl[i] = l;
    }
    nd += __shfl_xor(nd, 16);
    nd += __shfl_xor(nd, 32);
}

template<int NT>
__device__ __forceinline__ void knn_scan(
    const unsigned short* __restrict__ srcHi, const unsigned short* __restrict__ srcLo,
    const float* __restrict__ snrm,
    short8 Bh, short8 Bl, float nd, int c, int kg,
    unsigned* key)
{
    for (int t = 0; t < NT; t += 2) {
        unsigned cand[8];
#pragma unroll
        for (int u = 0; u < 2; u++) {
            int tt = t + u;
            size_t arow = ((size_t)(tt * 16 + c)) * 32 + (size_t)kg * 8;
            short8 Ah = *(const short8*)(srcHi + arow);
            short8 Al = *(const short8*)(srcLo + arow);
            f32x4 acc = {0.f, 0.f, 0.f, 0.f};
            acc = __builtin_amdgcn_mfma_f32_16x16x32_bf16(Al, Bl, acc, 0, 0, 0);
            acc = __builtin_amdgcn_mfma_f32_16x16x32_bf16(Al, Bh, acc, 0, 0, 0);
            acc = __builtin_amdgcn_mfma_f32_16x16x32_bf16(Ah, Bl, acc, 0, 0, 0);
            acc = __builtin_amdgcn_mfma_f32_16x16x32_bf16(Ah, Bh, acc, 0, 0, 0);
            float4 sn = *(const float4*)(snrm + tt * 16 + kg * 4);
            int sb = tt * 16 + kg * 4;
            cand[u*4+0] = (__float_as_uint(fmaf(-2.f, acc[0], sn.x + nd)) & 0xFFFFFE00u) | (unsigned)(sb + 0);
            cand[u*4+1] = (__float_as_uint(fmaf(-2.f, acc[1], sn.y + nd)) & 0xFFFFFE00u) | (unsigned)(sb + 1);
            cand[u*4+2] = (__float_as_uint(fmaf(-2.f, acc[2], sn.z + nd)) & 0xFFFFFE00u) | (unsigned)(sb + 2);
            cand[u*4+3] = (__float_as_uint(fmaf(-2.f, acc[3], sn.w + nd)) & 0xFFFFFE00u) | (unsigned)(sb + 3);
        }
        sort8(cand);
        merge8(key, cand);
    }
}

// after symmetric merges all 4 lanes of a dst column hold the identical
// final sorted top-8 (keys unique -> deterministic).
__device__ __forceinline__ void knn_merge_lanes(unsigned* key)
{
    unsigned oth[8];
#pragma unroll
    for (int k = 0; k < 8; k++) oth[k] = __shfl_xor(key[k], 16);
    merge8(key, oth);
#pragma unroll
    for (int k = 0; k < 8; k++) oth[k] = __shfl_xor(key[k], 32);
    merge8(key, oth);
}

__device__ __forceinline__ void gather_max8(const float* __restrict__ Yb,
                                            const unsigned* key, int kg, float* m)
{
    const float* r0 = Yb + (size_t)(key[0] & 511u) * 32 + kg * 8;
    float4 a = *(const float4*)(r0);
    float4 b = *(const float4*)(r0 + 4);
    m[0] = a.x; m[1] = a.y; m[2] = a.z; m[3] = a.w;
    m[4] = b.x; m[5] = b.y; m[6] = b.z; m[7] = b.w;
#pragma unroll
    for (int k = 1; k < 8; k++) {
        const float* rr = Yb + (size_t)(key[k] & 511u) * 32 + kg * 8;
        float4 va = *(const float4*)(rr);
        float4 vb = *(const float4*)(rr + 4);
        m[0] = fmaxf(m[0], va.x); m[1] = fmaxf(m[1], va.y);
        m[2] = fmaxf(m[2], va.z); m[3] = fmaxf(m[3], va.w);
        m[4] = fmaxf(m[4], vb.x); m[5] = fmaxf(m[5], vb.y);
        m[6] = fmaxf(m[6], vb.z); m[7] = fmaxf(m[7], vb.w);
    }
}

// knn12 + g12 + yb3 fused: 2048 blocks. Y3 aliases trk_enc and B3 aliases
// f1base: each wave reads ONLY its own 16 rows of both (knn_build_B and the
// base read), strictly before overwriting those same rows -> in-wave program
// order guarantees correctness; no cross-wave row sharing within the launch.
__global__ __launch_bounds__(256) void knn12_kernel(
    const unsigned short* __restrict__ svHi, const unsigned short* __restrict__ svLo,
    const float* __restrict__ nrm_sv,
    const unsigned short* __restrict__ pfcHi, const unsigned short* __restrict__ pfcLo,
    const float* __restrict__ nrm_pfc,
    const float* __restrict__ trk_enc,
    const float* __restrict__ Y1, const float* __restrict__ Y2,
    const float* __restrict__ f1base, float* __restrict__ f2,
    unsigned short* __restrict__ f1Hi, unsigned short* __restrict__ f1Lo,
    float* __restrict__ nrm_f1,
    float* __restrict__ Y3, float* __restrict__ B3,
    const float* __restrict__ conv_W, const float* __restrict__ conv_b)
{
    int bid = blockIdx.x;
    int e = bid & 255, j = bid >> 8;
    int tid = threadIdx.x;
    int lane = tid & 63, wave = tid >> 6;
    int c = lane & 15, kg = lane >> 4;
    int dstbase = j * 64 + wave * 16;
    size_t trow = (size_t)e * 512 + dstbase + c;

    // conv weight fragments for the fused Y3/B3 MFMAs (r7 yb3 order)
    short8 WYh0, WYl0, WYh1, WYl1, WDh0, WDl0, WDh1, WDl1;
#pragma unroll
    for (int ee = 0; ee < 8; ee++) {
        int kk = kg * 8 + ee;
        float y0 = conv_W[1024 + kk * 32 + c];
        float y1 = conv_W[1024 + kk * 32 + 16 + c];
        float d0 = conv_W[kk * 32 + c] - y0;
        float d1 = conv_W[kk * 32 + 16 + c] - y1;
        short h, l;
        bfsplit(y0, h, l); WYh0[ee] = h; WYl0[ee] = l;
        bfsplit(y1, h, l); WYh1[ee] = h; WYl1[ee] = l;
        bfsplit(d0, h, l); WDh0[ee] = h; WDl0[ee] = l;
        bfsplit(d1, h, l); WDh1[ee] = h; WDl1[ee] = l;
    }
    float bd0 = conv_b[c], bd1 = conv_b[16 + c];

    short8 Bh, Bl;
    float nd;
    knn_build_B(trk_enc + (size_t)e * 512 * 32, dstbase, c, kg, Bh, Bl, nd);

    unsigned key2[8];
#pragma unroll
    for (int k = 0; k < 8; k++) key2[k] = 0xFFFFFFFFu;
    knn_scan<32>(pfcHi + (size_t)e * 512 * 32, pfcLo + (size_t)e * 512 * 32,
                 nrm_pfc + e * 512, Bh, Bl, nd, c, kg, key2);
    knn_merge_lanes(key2);

    unsigned key1[8];
#pragma unroll
    for (int k = 0; k < 8; k++) key1[k] = 0xFFFFFFFFu;
    knn_scan<4>(svHi + (size_t)e * 64 * 32, svLo + (size_t)e * 64 * 32,
                nrm_sv + e * 64, Bh, Bl, nd, c, kg, key1);
    knn_merge_lanes(key1);

    // base (read BEFORE B3 overwrites these rows)
    const float* bp = f1base + trow * 32 + kg * 8;
    float4 bb0 = *(const float4*)(bp);
    float4 bb1 = *(const float4*)(bp + 4);
    float base[8] = {bb0.x, bb0.y, bb0.z, bb0.w, bb1.x, bb1.y, bb1.z, bb1.w};

    float m[8];
    // f2 = elu(base + max Y2[rows2]); keep split for B3
    gather_max8(Y2 + (size_t)e * 512 * 32, key2, kg, m);
    float v2[8];
    short8 Fh, Fl;
#pragma unroll
    for (int i = 0; i < 8; i++) {
        v2[i] = elu_f(base[i] + m[i]);
        short h, l;
        bfsplit(v2[i], h, l);
        Fh[i] = h; Fl[i] = l;
    }
    {
        float4* op = (float4*)(f2 + trow * 32 + kg * 8);
        op[0] = (float4){v2[0], v2[1], v2[2], v2[3]};
        op[1] = (float4){v2[4], v2[5], v2[6], v2[7]};
    }

    // f1 = elu(base + max Y1[rows1]) -> planes + norm (kept in regs)
    gather_max8(Y1 + (size_t)e * 64 * 32, key1, kg, m);
    float v1[8];
    float nr = 0.f;
    short8 Hh, Hl;
#pragma unroll
    for (int i = 0; i < 8; i++) {
        v1[i] = elu_f(base[i] + m[i]);
        nr = fmaf(v1[i], v1[i], nr);
        short h, l;
        bfsplit(v1[i], h, l);
        Hh[i] = h; Hl[i] = l;
    }
    nr += __shfl_xor(nr, 16);
    nr += __shfl_xor(nr, 32);
    if (kg == 0) nrm_f1[trow] = nr;
    *(short8*)(f1Hi + trow * 32 + kg * 8) = Hh;
    *(short8*)(f1Lo + trow * 32 + kg * 8) = Hl;

    // Y3 = f1 @ w2h (bias 0) for this wave's 16 dst rows (r7 yb3 order)
    f32x4 a0 = {0.f, 0.f, 0.f, 0.f}, a1 = {0.f, 0.f, 0.f, 0.f};
    a0 = __builtin_amdgcn_mfma_f32_16x16x32_bf16(Hl, WYh0, a0, 0, 0, 0);
    a0 = __builtin_amdgcn_mfma_f32_16x16x32_bf16(Hh, WYl0, a0, 0, 0, 0);
    a0 = __builtin_amdgcn_mfma_f32_16x16x32_bf16(Hh, WYh0, a0, 0, 0, 0);
    a1 = __builtin_amdgcn_mfma_f32_16x16x32_bf16(Hl, WYh1, a1, 0, 0, 0);
    a1 = __builtin_amdgcn_mfma_f32_16x16x32_bf16(Hh, WYl1, a1, 0, 0, 0);
    a1 = __builtin_amdgcn_mfma_f32_16x16x32_bf16(Hh, WYh1, a1, 0, 0, 0);
    // B3 = f2 @ wd + conv_b
    f32x4 q0 = {bd0, bd0, bd0, bd0}, q1 = {bd1, bd1, bd1, bd1};
    q0 = __builtin_amdgcn_mfma_f32_16x16x32_bf16(Fl, WDh0, q0, 0, 0, 0);
    q0 = __builtin_amdgcn_mfma_f32_16x16x32_bf16(Fh, WDl0, q0, 0, 0, 0);
    q0 = __builtin_amdgcn_mfma_f32_16x16x32_bf16(Fh, WDh0, q0, 0, 0, 0);
    q1 = __builtin_amdgcn_mfma_f32_16x16x32_bf16(Fl, WDh1, q1, 0, 0, 0);
    q1 = __builtin_amdgcn_mfma_f32_16x16x32_bf16(Fh, WDl1, q1, 0, 0, 0);
    q1 = __builtin_amdgcn_mfma_f32_16x16x32_bf16(Fh, WDh1, q1, 0, 0, 0);

    int drow = dstbase + kg * 4;
#pragma unroll
    for (int r = 0; r < 4; r++) {
        size_t off = ((size_t)e * 512 + drow + r) * 32 + c;
        Y3[off] = a0[r];  Y3[off + 16] = a1[r];
        B3[off] = q0[r];  B3[off + 16] = q1[r];
    }
}

// knn3 + g3 fused (r8-validated): 2048 blocks
__global__ __launch_bounds__(256) void knn3_kernel(
    const unsigned short* __restrict__ f1Hi, const unsigned short* __restrict__ f1Lo,
    const float* __restrict__ nrm_f1,
    const float* __restrict__ f2,
    const float* __restrict__ Y3, const float* __restrict__ B3,
    float* __restrict__ pool)
{
    __shared__ float sp[4][32];
    int bid = blockIdx.x;
    int e = bid & 255, j = bid >> 8;
    int tid = threadIdx.x;
    int lane = tid & 63, wave = tid >> 6;
    int c = lane & 15, kg = lane >> 4;
    int dstbase = j * 64 + wave * 16;
    size_t trow = (size_t)e * 512 + dstbase + c;

    short8 Bh, Bl;
    float nd;
    knn_build_B(f2 + (size_t)e * 512 * 32, dstbase, c, kg, Bh, Bl, nd);

    unsigned key[8];
#pragma unroll
    for (int k = 0; k < 8; k++) key[k] = 0xFFFFFFFFu;
    knn_scan<32>(f1Hi + (size_t)e * 512 * 32, f1Lo + (size_t)e * 512 * 32,
                 nrm_f1 + e * 512, Bh, Bl, nd, c, kg, key);
    knn_merge_lanes(key);

    float m[8];
    gather_max8(Y3 + (size_t)e * 512 * 32, key, kg, m);

    const float* bp = B3 + trow * 32 + kg * 8;
    float4 bb0 = *(const float4*)(bp);
    float4 bb1 = *(const float4*)(bp + 4);
    float base[8] = {bb0.x, bb0.y, bb0.z, bb0.w, bb1.x, bb1.y, bb1.z, bb1.w};

    float r[8];
#pragma unroll
    for (int i = 0; i < 8; i++) r[i] = elu_f(base[i] + m[i]);

#pragma unroll
    for (int off = 1; off < 16; off <<= 1) {
#pragma unroll
        for (int i = 0; i < 8; i++) r[i] += __shfl_xor(r[i], off);
    }
    if (c == 0) {
#pragma unroll
        for (int i = 0; i < 8; i++) sp[wave][kg * 8 + i] = r[i];
    }
    __syncthreads();
    if (tid < 32)
        pool[((size_t)e * 8 + j) * 32 + tid] =
            sp[0][tid] + sp[1][tid] + sp[2][tid] + sp[3][tid];
}

// final: 8 pooled partials per event + MLP + sigmoid + arange
__global__ __launch_bounds__(64) void final_kernel(
    const float* __restrict__ pool,
    const float* __restrict__ W1, const float* __restrict__ b1,
    const float* __restrict__ W2, const float* __restrict__ b2,
    float* __restrict__ outp)
{
    int b = blockIdx.x;
    int lane = threadIdx.x, c = lane & 31;
    __shared__ float sp[32];
    __shared__ float sh1[32];
    if (lane < 32) {
        float s = 0.f;
#pragma unroll
        for (int jj = 0; jj < 8; jj++)
            s += pool[((size_t)b * 8 + jj) * 32 + c];
        sp[c] = s * (1.0f / 512.0f);
    }
    __syncthreads();
    if (lane < 32) {
        float h = b1[c];
#pragma unroll
        for (int d = 0; d < 32; d++) h = fmaf(sp[d], W1[d * 32 + c], h);
        sh1[c] = elu_f(h);
    }
    __syncthreads();
    if (lane == 0) {
        float o = b2[0];
#pragma unroll
        for (int d = 0; d < 32; d++) o = fmaf(sh1[d], W2[d], o);
        o = 1.f / (1.f + __expf(-o));
        outp[b] = o;
        outp[NB + b] = (float)b;
    }
}

extern "C" void kernel_launch(void* const* d_in, const int* in_sizes, int n_in,
                              void* d_out, int out_size, void* d_ws, size_t ws_size,
                              hipStream_t stream) {
    const float* x_sv  = (const float*)d_in[0];
    const float* x_trk = (const float*)d_in[1];
    const float* x_pfc = (const float*)d_in[2];
    const float* sv_W1  = (const float*)d_in[6];
    const float* sv_b1  = (const float*)d_in[7];
    const float* sv_W2  = (const float*)d_in[8];
    const float* sv_b2  = (const float*)d_in[9];
    const float* trk_W1 = (const float*)d_in[10];
    const float* trk_b1 = (const float*)d_in[11];
    const float* trk_W2 = (const float*)d_in[12];
    const float* trk_b2 = (const float*)d_in[13];
    const float* pfc_W1 = (const float*)d_in[14];
    const float* pfc_b1 = (const float*)d_in[15];
    const float* pfc_W2 = (const float*)d_in[16];
    const float* pfc_b2 = (const float*)d_in[17];
    const float* conv_W = (const float*)d_in[18];
    const float* conv_b = (const float*)d_in[19];
    const float* out_W1 = (const float*)d_in[20];
    const float* out_b1 = (const float*)d_in[21];
    const float* out_W2 = (const float*)d_in[22];
    const float* out_b2 = (const float*)d_in[23];

    float* ws = (float*)d_ws;
    const size_t SV_E  = (size_t)NB * 64 * 32;     //   524288
    const size_t TRK_E = (size_t)NB * 512 * 32;    //  4194304
    float* f1base  = ws;                           // B3 aliases (in knn12)
    float* f2      = f1base + TRK_E;
    float* trk_enc = f2 + TRK_E;                   // Y3 aliases (in knn12)
    float* Y1      = trk_enc + TRK_E;
    float* Y2      = Y1 + SV_E;
    unsigned short* svHi  = (unsigned short*)(Y2 + TRK_E);   // SV_E u16
    unsigned short* svLo  = svHi + SV_E;                     // pool aliases
    unsigned short* pfcHi = svLo + SV_E;                     // TRK_E u16
    unsigned short* pfcLo = pfcHi + TRK_E;
    unsigned short* f1Hi  = pfcLo + TRK_E;
    unsigned short* f1Lo  = f1Hi + TRK_E;
    float* nrm_sv  = (float*)(f1Lo + TRK_E);                 // NB*64
    float* nrm_pfc = nrm_sv + (size_t)NB * 64;               // NB*512
    float* nrm_f1  = nrm_pfc + (size_t)NB * 512;             // NB*512
    float* Y3   = trk_enc;          // each wave reads-then-writes own rows
    float* B3   = f1base;           // same argument
    float* pool = (float*)svHi;     // sv planes dead after knn12; NB*8*32 f32

    encode_all_kernel<<<1088, 256, 0, stream>>>(
        x_sv, x_trk, x_pfc,
        sv_W1, sv_b1, sv_W2, sv_b2,
        trk_W1, trk_b1, trk_W2, trk_b2,
        pfc_W1, pfc_b1, pfc_W2, pfc_b2,
        conv_W, conv_b,
        trk_enc, Y1, Y2, f1base,
        svHi, svLo, nrm_sv, pfcHi, pfcLo, nrm_pfc);

    knn12_kernel<<<2048, 256, 0, stream>>>(svHi, svLo, nrm_sv,
                                           pfcHi, pfcLo, nrm_pfc,
                                           trk_enc, Y1, Y2,
                                           f1base, f2, f1Hi, f1Lo, nrm_f1,
                                           Y3, B3, conv_W, conv_b);

    knn3_kernel<<<2048, 256, 0, stream>>>(f1Hi, f1Lo, nrm_f1, f2, Y3, B3, pool);

    final_kernel<<<NB, 64, 0, stream>>>(pool, out_W1, out_b1, out_W2, out_b2, (float*)d_out);
}